// Round 1
// baseline (888.088 us; speedup 1.0000x reference)
//
#include <hip/hip_runtime.h>
#include <hip/hip_cooperative_groups.h>
#include <hip/hip_bf16.h>
#include <math.h>

namespace cg = cooperative_groups;

#define BATCH 8
#define HH 1024
#define WW 1024

#define NBLK 512
#define NTHR 131072   // NBLK * 256

__device__ __forceinline__ int reflect1024(int i) {
    i = i < 0 ? -i : i;
    return i > 1023 ? 2046 - i : i;
}

// ---------------------------------------------------------------------------
// Mega-kernel argument block (passed by value; pointers stable across replays)
// ---------------------------------------------------------------------------
struct MegaArgs {
    const float *lqs, *evs;
    const float *sw0, *sb0, *sw1, *sb1, *sw2, *sb2, *sw3, *sb3;
    const float *lw1, *lb1, *lw2;
    const float *cw0, *cb0, *cw1, *cb1;
    const float *fw1, *fb1, *fw2, *fb2, *fw3, *fb3;
    const float *fuw, *fub;
    float *o0, *o1, *o2, *o3, *xl1, *xl2, *xg0, *xin, *bg;
};

// ---------------------------------------------------------------------------
// Stage 0: conv0 — concat(nearest(lqs,256)[3], evs[15]) -> (8,18,3,3) s2 p1
// + bias + relu -> [B,8,128,128].  1 output px per thread, 8 oc.
// items = 8 * 128*128 = 131072 (exactly the grid).
// ---------------------------------------------------------------------------
__device__ __forceinline__ void stage_conv0(int idx, const MegaArgs& A) {
    int px = idx & 16383;
    int b = idx >> 14;
    int ox = px & 127, oy = px >> 7;
    int iy0 = 2 * oy - 1, ix0 = 2 * ox - 1;

    float acc[8];
#pragma unroll
    for (int o = 0; o < 8; ++o) acc[o] = A.sb0[o];

#pragma unroll
    for (int ic = 0; ic < 3; ++ic) {
        const float* ipc = A.lqs + ((size_t)(b * 3 + ic) << 20);
#pragma unroll
        for (int ky = 0; ky < 3; ++ky) {
            int iy = iy0 + ky;
            if ((unsigned)iy >= 256u) continue;
            const float* row = ipc + (size_t)iy * 4 * WW;  // nearest: src row 4*iy
#pragma unroll
            for (int kx = 0; kx < 3; ++kx) {
                int ix = ix0 + kx;
                if ((unsigned)ix >= 256u) continue;
                float v = row[ix * 4];                      // nearest: src col 4*ix
                const float* wp = A.sw0 + ic * 9 + ky * 3 + kx;
#pragma unroll
                for (int o = 0; o < 8; ++o) acc[o] = fmaf(wp[o * 162], v, acc[o]);
            }
        }
    }
    for (int ic = 0; ic < 15; ++ic) {
        const float* ipc = A.evs + ((size_t)(b * 15 + ic) << 16);
#pragma unroll
        for (int ky = 0; ky < 3; ++ky) {
            int iy = iy0 + ky;
            if ((unsigned)iy >= 256u) continue;
            const float* row = ipc + iy * 256;
#pragma unroll
            for (int kx = 0; kx < 3; ++kx) {
                int ix = ix0 + kx;
                if ((unsigned)ix >= 256u) continue;
                float v = row[ix];
                const float* wp = A.sw0 + (ic + 3) * 9 + ky * 3 + kx;
#pragma unroll
                for (int o = 0; o < 8; ++o) acc[o] = fmaf(wp[o * 162], v, acc[o]);
            }
        }
    }
#pragma unroll
    for (int o = 0; o < 8; ++o)
        A.o0[((size_t)(b * 8 + o) << 14) + px] = fmaxf(acc[o], 0.0f);
}

// ---------------------------------------------------------------------------
// Generic 3x3 conv stage (pad=1). One item = (b, oc-group, output px).
// Same math as the previously-verified convN_k body.
// ---------------------------------------------------------------------------
template <int IC, int OC, int OCT, int IH, int IW, int STRIDE, bool RELU, bool HASB>
__device__ __forceinline__ void stage_conv(int r, const float* __restrict__ in,
                                           const float* __restrict__ w,
                                           const float* __restrict__ bias,
                                           float* __restrict__ out) {
    constexpr int OH = (IH + 2 - 3) / STRIDE + 1;
    constexpr int OW = (IW + 2 - 3) / STRIDE + 1;
    constexpr int POS = OH * OW;
    constexpr int G = OC / OCT;
    int px = r % POS;
    int g = (r / POS) % G;
    int b = r / (POS * G);
    int ox = px % OW, oy = px / OW;
    int iy0 = oy * STRIDE - 1, ix0 = ox * STRIDE - 1;

    float acc[OCT];
#pragma unroll
    for (int o = 0; o < OCT; ++o) acc[o] = HASB ? bias[g * OCT + o] : 0.0f;

    const float* ip = in + (size_t)b * IC * IH * IW;
    for (int ic = 0; ic < IC; ++ic) {
        const float* ipc = ip + ic * IH * IW;
        float x[9];
#pragma unroll
        for (int ky = 0; ky < 3; ++ky) {
            int iy = iy0 + ky;
#pragma unroll
            for (int kx = 0; kx < 3; ++kx) {
                int ix = ix0 + kx;
                bool ok = ((unsigned)iy < (unsigned)IH) && ((unsigned)ix < (unsigned)IW);
                x[ky * 3 + kx] = ok ? ipc[iy * IW + ix] : 0.0f;
            }
        }
#pragma unroll
        for (int o = 0; o < OCT; ++o) {
            const float* wp = w + ((g * OCT + o) * IC + ic) * 9;
#pragma unroll
            for (int k = 0; k < 9; ++k) acc[o] = fmaf(wp[k], x[k], acc[o]);
        }
    }
#pragma unroll
    for (int o = 0; o < OCT; ++o) {
        float v = acc[o];
        if (RELU) v = fmaxf(v, 0.0f);
        out[(size_t)(b * OC + g * OCT + o) * POS + px] = v;
    }
}

// ---------------------------------------------------------------------------
// Cooperative mega-kernel: conv0 -> conv1 -> conv2 -> conv3 ->
//   {lw1 | cw0} -> {lw2 | cw1(+cb1,relu)} -> fc1/fc2/fc3 + fuse -> bg
// 512 blocks x 256 threads, grid.sync() between stages.
// ---------------------------------------------------------------------------
__global__ __launch_bounds__(256, 2) void mega_k(MegaArgs A) {
    cg::grid_group grid = cg::this_grid();
    int idx = blockIdx.x * 256 + threadIdx.x;  // 0..131071

    // S0: conv0 (18->8 @256 s2) -> o0 [8,8,128,128]
    stage_conv0(idx, A);
    grid.sync();

    // S1: conv1 (8->16 @128 s2) -> o1.  items = 8*4*4096 = 131072 (OCT=4)
    stage_conv<8, 16, 4, 128, 128, 2, true, true>(idx, A.o0, A.sw1, A.sb1, A.o1);
    grid.sync();

    // S2: conv2 (16->32 @64 s2) -> o2.  items = 8*16*1024 = 131072 (OCT=2)
    stage_conv<16, 32, 2, 64, 64, 2, true, true>(idx, A.o1, A.sw2, A.sb2, A.o2);
    grid.sync();

    // S3: conv3 (32->64 @32 s2) -> o3.  items = 8*64*256 = 131072 (OCT=1)
    stage_conv<32, 64, 1, 32, 32, 2, true, true>(idx, A.o2, A.sw3, A.sb3, A.o3);
    grid.sync();

    // S4: lw1 (64->64 @16 s1, relu) all threads; cw0 (64->64 @16 s2, relu)
    //     on the first 32768 threads (items = 8*64*64).
    stage_conv<64, 64, 1, 16, 16, 1, true, true>(idx, A.o3, A.lw1, A.lb1, A.xl1);
    if (idx < 32768)
        stage_conv<64, 64, 1, 16, 16, 2, true, true>(idx, A.o3, A.cw0, A.cb0, A.xg0);
    grid.sync();

    // S5: lw2 (64->64 @16 s1, no bias/relu) all; cw1 (64->64 @8 s2, +cb1, relu)
    //     on the first 8192 threads (items = 8*64*16) -> xin = fc input
    stage_conv<64, 64, 1, 16, 16, 1, false, false>(idx, A.xl1, A.lw2, nullptr, A.xl2);
    if (idx < 8192)
        stage_conv<64, 64, 1, 8, 8, 2, true, true>(idx, A.xg0, A.cw1, A.cb1, A.xin);
    grid.sync();

    // S6: fc1 -> fc2 -> fc3 -> fuse, block b handles batch b (blocks 0..7)
    __shared__ __align__(16) float sX[1024];
    __shared__ __align__(16) float sH1[256];
    __shared__ __align__(16) float sH2[128];
    __shared__ float sXG[64];
    if (blockIdx.x < 8) {
        int b = blockIdx.x, t = threadIdx.x;
#pragma unroll
        for (int j = 0; j < 4; ++j) sX[t + 256 * j] = A.xin[b * 1024 + t + 256 * j];
        __syncthreads();
        {
            // fc1: h1[r] = relu(fw1[r,:].xin + fb1[r]),  r = t (256 rows)
            const float4* w4 = (const float4*)(A.fw1 + (size_t)t * 1024);
            const float4* x4 = (const float4*)sX;
            float a[4] = {0.f, 0.f, 0.f, 0.f};
#pragma unroll 4
            for (int j = 0; j < 256; ++j) {
                float4 wv = w4[j], xv = x4[j];
                a[j & 3] = fmaf(wv.x, xv.x, fmaf(wv.y, xv.y,
                           fmaf(wv.z, xv.z, fmaf(wv.w, xv.w, a[j & 3]))));
            }
            sH1[t] = fmaxf(a[0] + a[1] + a[2] + a[3] + A.fb1[t], 0.0f);
        }
        __syncthreads();
        if (t < 128) {
            // fc2: 128 rows x 256
            const float4* w4 = (const float4*)(A.fw2 + (size_t)t * 256);
            const float4* x4 = (const float4*)sH1;
            float a[4] = {0.f, 0.f, 0.f, 0.f};
#pragma unroll 4
            for (int j = 0; j < 64; ++j) {
                float4 wv = w4[j], xv = x4[j];
                a[j & 3] = fmaf(wv.x, xv.x, fmaf(wv.y, xv.y,
                           fmaf(wv.z, xv.z, fmaf(wv.w, xv.w, a[j & 3]))));
            }
            sH2[t] = fmaxf(a[0] + a[1] + a[2] + a[3] + A.fb2[t], 0.0f);
        }
        __syncthreads();
        if (t < 64) {
            // fc3: 64 rows x 128 (linear)
            const float4* w4 = (const float4*)(A.fw3 + (size_t)t * 128);
            const float4* x4 = (const float4*)sH2;
            float a[4] = {0.f, 0.f, 0.f, 0.f};
#pragma unroll 4
            for (int j = 0; j < 32; ++j) {
                float4 wv = w4[j], xv = x4[j];
                a[j & 3] = fmaf(wv.x, xv.x, fmaf(wv.y, xv.y,
                           fmaf(wv.z, xv.z, fmaf(wv.w, xv.w, a[j & 3]))));
            }
            sXG[t] = a[0] + a[1] + a[2] + a[3] + A.fb3[t];
        }
        __syncthreads();
        // fuse: bg[b,d,px] = fub[d] + sum_c fuw[d,c] * relu(xg[c] + xl2[b,c,px])
        {
            int px = t;
            float accd[8];
#pragma unroll
            for (int d = 0; d < 8; ++d) accd[d] = A.fub[d];
            for (int c = 0; c < 64; ++c) {
                float f = fmaxf(sXG[c] + A.xl2[(size_t)(b * 64 + c) * 256 + px], 0.0f);
#pragma unroll
                for (int d = 0; d < 8; ++d) accd[d] = fmaf(A.fuw[d * 64 + c], f, accd[d]);
            }
#pragma unroll
            for (int d = 0; d < 8; ++d) A.bg[(b * 8 + d) * 256 + px] = accd[d];
        }
    }
}

// ---------------------------------------------------------------------------
// guide+slice (unchanged, verified): vertical-first separable blur, sliding
// register windows, per-px guide MLP + trilinear grid slice.
// ---------------------------------------------------------------------------
__global__ __launch_bounds__(256) void guide_slice_k(const float* __restrict__ lqs,
                                                     const float* __restrict__ bgp,
                                                     const float* __restrict__ gw1,
                                                     const float* __restrict__ gb1,
                                                     const float* __restrict__ gw2,
                                                     const float* __restrict__ gb2,
                                                     float* __restrict__ out) {
    constexpr int TW = 64, TH = 32;
    __shared__ float sBH[3][TH][81];
    __shared__ float sBG[2048];
    __shared__ float sW1[48], sB1[16], sW2[16], sB2v[1];

    int t = threadIdx.x;
    int bx = blockIdx.x & 15;
    int by = (blockIdx.x >> 4) & 31;
    int b = blockIdx.x >> 9;
    int x0 = bx * TW, y0 = by * TH;

    float gv[17];
    {
        float gs = 0.0f;
#pragma unroll
        for (int i = 0; i < 17; ++i) {
            float d = (float)i - 8.0f;
            gv[i] = expf(-(d * d) * 0.125f);
            gs += gv[i];
        }
        float inv = 1.0f / gs;
#pragma unroll
        for (int i = 0; i < 17; ++i) gv[i] *= inv;
    }

    for (int i = t; i < 2048; i += 256) sBG[i] = bgp[b * 2048 + i];
    if (t < 48) sW1[t] = gw1[t];
    if (t < 16) { sB1[t] = gb1[t]; sW2[t] = gw2[t]; }
    if (t == 0) sB2v[0] = gb2[0];

    if (t < 240) {
        int c = t / 80, xo = t % 80;
        int gx = reflect1024(x0 + xo - 8);
        const float* colp = lqs + (size_t)(b * 3 + c) * HH * WW + gx;
        float win[17];
#pragma unroll
        for (int i = 0; i < 16; ++i)
            win[i] = colp[(size_t)reflect1024(y0 - 8 + i) * WW];
#pragma unroll
        for (int j = 0; j < TH; ++j) {
            win[(16 + j) % 17] = colp[(size_t)reflect1024(y0 + 8 + j) * WW];
            float acc = 0.0f;
#pragma unroll
            for (int i = 0; i < 17; ++i) acc = fmaf(gv[i], win[(j + i) % 17], acc);
            sBH[c][j][xo] = acc;
        }
    }
    __syncthreads();

    int yy = t >> 3, xs = (t & 7) * 8;
    int Y = y0 + yy;
    float fy = fminf(fmaxf((Y + 0.5f) * (1.0f / 64.0f) + 3.5f, 0.0f), 15.0f);
    float yf = floorf(fy);
    int yi = (int)yf;
    float ay = fy - yf;
    int yi1 = min(yi + 1, 15);

    float bcv[3][8];
#pragma unroll
    for (int c = 0; c < 3; ++c) {
        float win[17];
#pragma unroll
        for (int i = 0; i < 16; ++i) win[i] = sBH[c][yy][xs + i];
#pragma unroll
        for (int j = 0; j < 8; ++j) {
            win[(16 + j) % 17] = sBH[c][yy][xs + 16 + j];
            float acc = 0.0f;
#pragma unroll
            for (int i = 0; i < 17; ++i) acc = fmaf(gv[i], win[(j + i) % 17], acc);
            bcv[c][j] = acc;
        }
    }

    float val[8];
#pragma unroll
    for (int j = 0; j < 8; ++j) {
        float b0 = bcv[0][j], b1 = bcv[1][j], b2 = bcv[2][j];
        float s = sB2v[0];
#pragma unroll
        for (int c = 0; c < 16; ++c) {
            float g1 = fmaf(sW1[c * 3 + 0], b0,
                       fmaf(sW1[c * 3 + 1], b1,
                       fmaf(sW1[c * 3 + 2], b2, sB1[c])));
            s = fmaf(sW2[c], fmaxf(g1, 0.0f), s);
        }
        float sig = 1.0f / (1.0f + expf(-s));
        float guide = sig * 2.0f - 0.5f;

        int X = x0 + xs + j;
        float fx = fminf(fmaxf((X + 0.5f) * (1.0f / 64.0f) + 3.5f, 0.0f), 15.0f);
        float fz = fminf(fmaxf(fmaf(guide, 4.0f, 3.5f), 0.0f), 7.0f);
        float xf = floorf(fx), zf = floorf(fz);
        int xi = (int)xf, zi = (int)zf;
        float ax = fx - xf, az = fz - zf;
        int xi1 = min(xi + 1, 15), zi1 = min(zi + 1, 7);

        const float* g0 = sBG + zi * 256;
        const float* g1p = sBG + zi1 * 256;
        int i00 = yi * 16 + xi, i01 = yi * 16 + xi1;
        int i10 = yi1 * 16 + xi, i11 = yi1 * 16 + xi1;
        float c00 = g0[i00] + az * (g1p[i00] - g0[i00]);
        float c01 = g0[i01] + az * (g1p[i01] - g0[i01]);
        float c10 = g0[i10] + az * (g1p[i10] - g0[i10]);
        float c11 = g0[i11] + az * (g1p[i11] - g0[i11]);
        float c0 = c00 + ay * (c10 - c00);
        float c1 = c01 + ay * (c11 - c01);
        val[j] = c0 + ax * (c1 - c0);
    }
    float4* op = (float4*)(out + (size_t)b * HH * WW + (size_t)Y * WW + x0 + xs);
    op[0] = make_float4(val[0], val[1], val[2], val[3]);
    op[1] = make_float4(val[4], val[5], val[6], val[7]);
}

// ---------------------------------------------------------------------------
extern "C" void kernel_launch(void* const* d_in, const int* in_sizes, int n_in,
                              void* d_out, int out_size, void* d_ws, size_t ws_size,
                              hipStream_t stream) {
    const float* lqs = (const float*)d_in[0];
    const float* evs = (const float*)d_in[1];
    const float* gw1 = (const float*)d_in[2];
    const float* gb1 = (const float*)d_in[3];
    const float* gw2 = (const float*)d_in[4];
    const float* gb2 = (const float*)d_in[5];
    const float* sw0 = (const float*)d_in[6];
    const float* sb0 = (const float*)d_in[7];
    const float* sw1 = (const float*)d_in[8];
    const float* sb1 = (const float*)d_in[9];
    const float* sw2 = (const float*)d_in[10];
    const float* sb2 = (const float*)d_in[11];
    const float* sw3 = (const float*)d_in[12];
    const float* sb3 = (const float*)d_in[13];
    const float* cw0 = (const float*)d_in[14];
    const float* cb0 = (const float*)d_in[15];
    const float* cw1 = (const float*)d_in[16];
    const float* cb1 = (const float*)d_in[17];
    const float* fw1 = (const float*)d_in[18];
    const float* fb1 = (const float*)d_in[19];
    const float* fw2 = (const float*)d_in[20];
    const float* fb2 = (const float*)d_in[21];
    const float* fw3 = (const float*)d_in[22];
    const float* fb3 = (const float*)d_in[23];
    const float* lw1 = (const float*)d_in[24];
    const float* lb1 = (const float*)d_in[25];
    const float* lw2 = (const float*)d_in[26];
    const float* fuw = (const float*)d_in[27];
    const float* fub = (const float*)d_in[28];
    float* out = (float*)d_out;

    float* ws = (float*)d_ws;
    float* o0  = ws;               // [8,8,128,128]  1048576
    float* o1  = o0 + 1048576;     // [8,16,64,64]    524288
    float* o2  = o1 + 524288;      // [8,32,32,32]    262144
    float* o3  = o2 + 262144;      // [8,64,16,16]    131072
    float* xl1 = o3 + 131072;      // [8,64,16,16]    131072
    float* xl2 = xl1 + 131072;     // [8,64,16,16]    131072
    float* xg0 = xl2 + 131072;     // [8,64,8,8]       32768
    float* xin = xg0 + 32768;      // [8,64,4,4]        8192  (post cb1+relu)
    float* bg  = xin + 8192;       // [8,8,16,16]      16384
    // total ~2.17M floats = 8.7 MB

    MegaArgs A;
    A.lqs = lqs; A.evs = evs;
    A.sw0 = sw0; A.sb0 = sb0; A.sw1 = sw1; A.sb1 = sb1;
    A.sw2 = sw2; A.sb2 = sb2; A.sw3 = sw3; A.sb3 = sb3;
    A.lw1 = lw1; A.lb1 = lb1; A.lw2 = lw2;
    A.cw0 = cw0; A.cb0 = cb0; A.cw1 = cw1; A.cb1 = cb1;
    A.fw1 = fw1; A.fb1 = fb1; A.fw2 = fw2; A.fb2 = fb2;
    A.fw3 = fw3; A.fb3 = fb3; A.fuw = fuw; A.fub = fub;
    A.o0 = o0; A.o1 = o1; A.o2 = o2; A.o3 = o3;
    A.xl1 = xl1; A.xl2 = xl2; A.xg0 = xg0; A.xin = xin; A.bg = bg;

    void* params[] = {(void*)&A};
    hipLaunchCooperativeKernel(mega_k, dim3(NBLK), dim3(256), params, 0, stream);
    guide_slice_k<<<BATCH * 32 * 16, 256, 0, stream>>>(lqs, bg, gw1, gb1, gw2, gb2, out);
}

// Round 2
// 632.625 us; speedup vs baseline: 1.4038x; 1.4038x over previous
//
#include <hip/hip_runtime.h>
#include <hip/hip_bf16.h>
#include <math.h>

#define BATCH 8
#define HH 1024
#define WW 1024

__device__ __forceinline__ int reflect1024(int i) {
    i = i < 0 ? -i : i;
    return i > 1023 ? 2046 - i : i;
}

// ---------------------------------------------------------------------------
// Generic 3x3 conv item (pad=1), OCT=1. One item = (b, oc, output px).
// Same per-output FMA order as the verified convN_k/stage_conv bodies.
// ---------------------------------------------------------------------------
template <int IC, int OC, int IH, int IW, int STRIDE, bool RELU, bool HASB>
__device__ __forceinline__ void conv_item(int r, const float* __restrict__ in,
                                          const float* __restrict__ w,
                                          const float* __restrict__ bias,
                                          float* __restrict__ out) {
    constexpr int OH = (IH + 2 - 3) / STRIDE + 1;
    constexpr int OW = (IW + 2 - 3) / STRIDE + 1;
    constexpr int POS = OH * OW;
    int px = r % POS;
    int oc = (r / POS) % OC;
    int b = r / (POS * OC);
    int ox = px % OW, oy = px / OW;
    int iy0 = oy * STRIDE - 1, ix0 = ox * STRIDE - 1;

    float acc = HASB ? bias[oc] : 0.0f;
    const float* ip = in + (size_t)b * IC * IH * IW;
    for (int ic = 0; ic < IC; ++ic) {
        const float* ipc = ip + ic * IH * IW;
        float x[9];
#pragma unroll
        for (int ky = 0; ky < 3; ++ky) {
            int iy = iy0 + ky;
#pragma unroll
            for (int kx = 0; kx < 3; ++kx) {
                int ix = ix0 + kx;
                bool ok = ((unsigned)iy < (unsigned)IH) && ((unsigned)ix < (unsigned)IW);
                x[ky * 3 + kx] = ok ? ipc[iy * IW + ix] : 0.0f;
            }
        }
        const float* wp = w + (oc * IC + ic) * 9;
#pragma unroll
        for (int k = 0; k < 9; ++k) acc = fmaf(wp[k], x[k], acc);
    }
    float v = RELU ? fmaxf(acc, 0.0f) : acc;
    out[(size_t)(b * OC + oc) * POS + px] = v;
}

// ---------------------------------------------------------------------------
// conv01_k: fused conv0 (18->8 @256 s2) + conv1 (8->16 @128 s2) -> o1
// [8,16,64,64].  512 blocks = b(8) x ty(8) x tx(8); o1 tile 8x8 per block.
// o0 tile (8ch x 17x17, incl. halo + zero-pad) computed into LDS.
// ---------------------------------------------------------------------------
__global__ __launch_bounds__(256) void conv01_k(const float* __restrict__ lqs,
                                                const float* __restrict__ evs,
                                                const float* __restrict__ sw0,
                                                const float* __restrict__ sb0,
                                                const float* __restrict__ sw1,
                                                const float* __restrict__ sb1,
                                                float* __restrict__ o1) {
    __shared__ float s0[8 * 289];  // [ic][yy*17+xx]
    int t = threadIdx.x;
    int blk = blockIdx.x;
    int tx = blk & 7, ty = (blk >> 3) & 7, b = blk >> 6;
    int oy0 = ty << 3, ox0 = tx << 3;            // o1 tile origin (64x64 grid)
    int iy0s = 2 * oy0 - 1, ix0s = 2 * ox0 - 1;  // o0 region origin (17x17)

    for (int p = t; p < 289; p += 256) {
        int yy = p / 17, xx = p - yy * 17;
        int iy = iy0s + yy, ix = ix0s + xx;      // o0 coords in [0,128)
        if ((unsigned)iy < 128u && (unsigned)ix < 128u) {
            float acc[8];
#pragma unroll
            for (int o = 0; o < 8; ++o) acc[o] = sb0[o];
#pragma unroll
            for (int ic = 0; ic < 3; ++ic) {
                const float* ipc = lqs + ((size_t)(b * 3 + ic) << 20);
#pragma unroll
                for (int ky = 0; ky < 3; ++ky) {
                    int r = 2 * iy - 1 + ky;
                    if ((unsigned)r >= 256u) continue;
                    const float* row = ipc + ((size_t)r << 12);  // nearest: row 4*r
#pragma unroll
                    for (int kx = 0; kx < 3; ++kx) {
                        int c = 2 * ix - 1 + kx;
                        if ((unsigned)c >= 256u) continue;
                        float v = row[c << 2];                    // nearest: col 4*c
                        const float* wp = sw0 + ic * 9 + ky * 3 + kx;
#pragma unroll
                        for (int o = 0; o < 8; ++o) acc[o] = fmaf(wp[o * 162], v, acc[o]);
                    }
                }
            }
            for (int ic = 0; ic < 15; ++ic) {
                const float* ipc = evs + ((size_t)(b * 15 + ic) << 16);
#pragma unroll
                for (int ky = 0; ky < 3; ++ky) {
                    int r = 2 * iy - 1 + ky;
                    if ((unsigned)r >= 256u) continue;
                    const float* row = ipc + (r << 8);
#pragma unroll
                    for (int kx = 0; kx < 3; ++kx) {
                        int c = 2 * ix - 1 + kx;
                        if ((unsigned)c >= 256u) continue;
                        float v = row[c];
                        const float* wp = sw0 + (ic + 3) * 9 + ky * 3 + kx;
#pragma unroll
                        for (int o = 0; o < 8; ++o) acc[o] = fmaf(wp[o * 162], v, acc[o]);
                    }
                }
            }
#pragma unroll
            for (int o = 0; o < 8; ++o) s0[o * 289 + p] = fmaxf(acc[o], 0.0f);
        } else {
#pragma unroll
            for (int o = 0; o < 8; ++o) s0[o * 289 + p] = 0.0f;
        }
    }
    __syncthreads();

    // conv1: thread t -> px = t&63 (8x8), oc group = t>>6 (4 oc each)
    int px = t & 63, ocg = t >> 6;
    int lpy = px >> 3, lpx = px & 7;
    float a1[4];
#pragma unroll
    for (int o = 0; o < 4; ++o) a1[o] = sb1[ocg * 4 + o];
#pragma unroll
    for (int ic = 0; ic < 8; ++ic) {
        const float* sp = s0 + ic * 289 + (2 * lpy) * 17 + 2 * lpx;
        float x[9];
#pragma unroll
        for (int ky = 0; ky < 3; ++ky)
#pragma unroll
            for (int kx = 0; kx < 3; ++kx) x[ky * 3 + kx] = sp[ky * 17 + kx];
#pragma unroll
        for (int o = 0; o < 4; ++o) {
            const float* wp = sw1 + ((ocg * 4 + o) * 8 + ic) * 9;
#pragma unroll
            for (int k = 0; k < 9; ++k) a1[o] = fmaf(wp[k], x[k], a1[o]);
        }
    }
    int oy = oy0 + lpy, ox = ox0 + lpx;
#pragma unroll
    for (int o = 0; o < 4; ++o)
        o1[((size_t)(b * 16 + ocg * 4 + o) << 12) + (oy << 6) + ox] = fmaxf(a1[o], 0.0f);
}

// ---------------------------------------------------------------------------
// conv23_k: fused conv2 (16->32 @64 s2) + conv3 (32->64 @32 s2) -> o3
// [8,64,16,16].  128 blocks = b(8) x ty(4) x tx(4); o3 tile 4x4 per block.
// o2 region (32ch x 9x9, incl. halo + zero-pad) in LDS.
// ---------------------------------------------------------------------------
__global__ __launch_bounds__(256) void conv23_k(const float* __restrict__ o1,
                                                const float* __restrict__ sw2,
                                                const float* __restrict__ sb2,
                                                const float* __restrict__ sw3,
                                                const float* __restrict__ sb3,
                                                float* __restrict__ o3) {
    __shared__ float s2[32 * 81];  // [ic][yy*9+xx]
    int t = threadIdx.x;
    int blk = blockIdx.x;
    int tx = blk & 3, ty = (blk >> 2) & 3, b = blk >> 4;
    int oy0 = ty << 2, ox0 = tx << 2;            // o3 tile origin (16x16 grid)
    int iy0s = 2 * oy0 - 1, ix0s = 2 * ox0 - 1;  // o2 region origin (9x9)

    // o2 region: 81 px x 4 oc-groups (8 oc) = 324 items
    for (int it = t; it < 324; it += 256) {
        int ocg = it / 81, p = it - ocg * 81;
        int yy = p / 9, xx = p - yy * 9;
        int iy = iy0s + yy, ix = ix0s + xx;      // o2 coords in [0,32)
        if ((unsigned)iy < 32u && (unsigned)ix < 32u) {
            float acc[8];
#pragma unroll
            for (int o = 0; o < 8; ++o) acc[o] = sb2[ocg * 8 + o];
            const float* ip = o1 + ((size_t)b << 16);
            int ry0 = 2 * iy - 1, rx0 = 2 * ix - 1;
            for (int ic = 0; ic < 16; ++ic) {
                const float* ipc = ip + (ic << 12);
                float x[9];
#pragma unroll
                for (int ky = 0; ky < 3; ++ky) {
                    int r = ry0 + ky;
#pragma unroll
                    for (int kx = 0; kx < 3; ++kx) {
                        int c = rx0 + kx;
                        bool ok = ((unsigned)r < 64u) && ((unsigned)c < 64u);
                        x[ky * 3 + kx] = ok ? ipc[(r << 6) + c] : 0.0f;
                    }
                }
#pragma unroll
                for (int o = 0; o < 8; ++o) {
                    const float* wp = sw2 + ((ocg * 8 + o) * 16 + ic) * 9;
#pragma unroll
                    for (int k = 0; k < 9; ++k) acc[o] = fmaf(wp[k], x[k], acc[o]);
                }
            }
#pragma unroll
            for (int o = 0; o < 8; ++o) s2[(ocg * 8 + o) * 81 + p] = fmaxf(acc[o], 0.0f);
        } else {
#pragma unroll
            for (int o = 0; o < 8; ++o) s2[(ocg * 8 + o) * 81 + p] = 0.0f;
        }
    }
    __syncthreads();

    // conv3: thread t -> oc = t>>2, column lx = t&3; 4 rows per thread
    int oc = t >> 2, lx = t & 3;
    float a3[4];
#pragma unroll
    for (int j = 0; j < 4; ++j) a3[j] = sb3[oc];
    for (int ic = 0; ic < 32; ++ic) {
        const float* wp = sw3 + (oc * 32 + ic) * 9;
        float w[9];
#pragma unroll
        for (int k = 0; k < 9; ++k) w[k] = wp[k];
        const float* sp = s2 + ic * 81 + 2 * lx;
#pragma unroll
        for (int j = 0; j < 4; ++j)
#pragma unroll
            for (int ky = 0; ky < 3; ++ky)
#pragma unroll
                for (int kx = 0; kx < 3; ++kx)
                    a3[j] = fmaf(w[ky * 3 + kx], sp[(2 * j + ky) * 9 + kx], a3[j]);
    }
#pragma unroll
    for (int j = 0; j < 4; ++j) {
        int gy = oy0 + j, gx = ox0 + lx;
        o3[((size_t)(b * 64 + oc) << 8) + (gy << 4) + gx] = fmaxf(a3[j], 0.0f);
    }
}

// ---------------------------------------------------------------------------
// lw1cw0_k: lw1 (64->64 @16 s1, relu) on blocks 0..511; cw0 (64->64 @16 s2,
// relu) on blocks 512..639. Both read o3.
// ---------------------------------------------------------------------------
__global__ __launch_bounds__(256) void lw1cw0_k(const float* __restrict__ o3,
                                                const float* __restrict__ lw1,
                                                const float* __restrict__ lb1,
                                                const float* __restrict__ cw0,
                                                const float* __restrict__ cb0,
                                                float* __restrict__ xl1,
                                                float* __restrict__ xg0) {
    int blk = blockIdx.x;
    if (blk < 512) {
        conv_item<64, 64, 16, 16, 1, true, true>(blk * 256 + threadIdx.x, o3, lw1, lb1, xl1);
    } else {
        conv_item<64, 64, 16, 16, 2, true, true>((blk - 512) * 256 + threadIdx.x, o3, cw0, cb0, xg0);
    }
}

// ---------------------------------------------------------------------------
// lw2cw1fc_k: lw2 (64->64 @16 s1, no bias/relu) on blocks 0..511 -> xl2;
// blocks 512..519 (one per batch): cw1 (+cb1+relu) -> LDS, then fc1/fc2/fc3
// -> xgv[b,64].
// ---------------------------------------------------------------------------
__global__ __launch_bounds__(256) void lw2cw1fc_k(const float* __restrict__ xl1,
                                                  const float* __restrict__ lw2,
                                                  const float* __restrict__ xg0,
                                                  const float* __restrict__ cw1,
                                                  const float* __restrict__ cb1,
                                                  const float* __restrict__ fw1,
                                                  const float* __restrict__ fb1,
                                                  const float* __restrict__ fw2,
                                                  const float* __restrict__ fb2,
                                                  const float* __restrict__ fw3,
                                                  const float* __restrict__ fb3,
                                                  float* __restrict__ xl2,
                                                  float* __restrict__ xgv) {
    int blk = blockIdx.x, t = threadIdx.x;
    if (blk < 512) {
        conv_item<64, 64, 16, 16, 1, false, false>(blk * 256 + t, xl1, lw2, nullptr, xl2);
        return;
    }
    int b = blk - 512;
    __shared__ __align__(16) float sX[1024];
    __shared__ __align__(16) float sH1[256];
    __shared__ __align__(16) float sH2[128];

    // cw1: item = oc*16 + px (matches xg1 flatten order oc*POS+px)
#pragma unroll
    for (int j = 0; j < 4; ++j) {
        int item = t + (j << 8);
        int oc = item >> 4, px = item & 15;
        int oy = px >> 2, ox = px & 3;
        int iy0 = 2 * oy - 1, ix0 = 2 * ox - 1;
        float acc = cb1[oc];
        const float* ip = xg0 + ((size_t)b << 12);
        for (int ic = 0; ic < 64; ++ic) {
            const float* ipc = ip + (ic << 6);
            const float* wp = cw1 + (oc * 64 + ic) * 9;
#pragma unroll
            for (int ky = 0; ky < 3; ++ky) {
                int r = iy0 + ky;
#pragma unroll
                for (int kx = 0; kx < 3; ++kx) {
                    int c = ix0 + kx;
                    bool ok = ((unsigned)r < 8u) && ((unsigned)c < 8u);
                    float x = ok ? ipc[(r << 3) + c] : 0.0f;
                    acc = fmaf(wp[ky * 3 + kx], x, acc);
                }
            }
        }
        sX[item] = fmaxf(acc, 0.0f);
    }
    __syncthreads();
    {
        // fc1: h1[r] = relu(fw1[r,:].sX + fb1[r]),  r = t (256 rows)
        const float4* w4 = (const float4*)(fw1 + (size_t)t * 1024);
        const float4* x4 = (const float4*)sX;
        float a[4] = {0.f, 0.f, 0.f, 0.f};
#pragma unroll 4
        for (int j = 0; j < 256; ++j) {
            float4 wv = w4[j], xv = x4[j];
            a[j & 3] = fmaf(wv.x, xv.x, fmaf(wv.y, xv.y,
                       fmaf(wv.z, xv.z, fmaf(wv.w, xv.w, a[j & 3]))));
        }
        sH1[t] = fmaxf(a[0] + a[1] + a[2] + a[3] + fb1[t], 0.0f);
    }
    __syncthreads();
    if (t < 128) {
        const float4* w4 = (const float4*)(fw2 + (size_t)t * 256);
        const float4* x4 = (const float4*)sH1;
        float a[4] = {0.f, 0.f, 0.f, 0.f};
#pragma unroll 4
        for (int j = 0; j < 64; ++j) {
            float4 wv = w4[j], xv = x4[j];
            a[j & 3] = fmaf(wv.x, xv.x, fmaf(wv.y, xv.y,
                       fmaf(wv.z, xv.z, fmaf(wv.w, xv.w, a[j & 3]))));
        }
        sH2[t] = fmaxf(a[0] + a[1] + a[2] + a[3] + fb2[t], 0.0f);
    }
    __syncthreads();
    if (t < 64) {
        const float4* w4 = (const float4*)(fw3 + (size_t)t * 128);
        const float4* x4 = (const float4*)sH2;
        float a[4] = {0.f, 0.f, 0.f, 0.f};
#pragma unroll 4
        for (int j = 0; j < 32; ++j) {
            float4 wv = w4[j], xv = x4[j];
            a[j & 3] = fmaf(wv.x, xv.x, fmaf(wv.y, xv.y,
                       fmaf(wv.z, xv.z, fmaf(wv.w, xv.w, a[j & 3]))));
        }
        xgv[b * 64 + t] = a[0] + a[1] + a[2] + a[3] + fb3[t];
    }
}

// ---------------------------------------------------------------------------
// guide+slice with fuse_k folded in as prologue: each block computes bg[b]
// (identical arithmetic to the verified fuse_k) into sBG, then the verified
// blur + guide MLP + trilinear slice.
// ---------------------------------------------------------------------------
__global__ __launch_bounds__(256) void guide_slice_k(const float* __restrict__ lqs,
                                                     const float* __restrict__ xl2,
                                                     const float* __restrict__ xgv,
                                                     const float* __restrict__ fuw,
                                                     const float* __restrict__ fub,
                                                     const float* __restrict__ gw1,
                                                     const float* __restrict__ gb1,
                                                     const float* __restrict__ gw2,
                                                     const float* __restrict__ gb2,
                                                     float* __restrict__ out) {
    constexpr int TW = 64, TH = 32;
    __shared__ float sBH[3][TH][81];
    __shared__ float sBG[2048];
    __shared__ float sW1[48], sB1[16], sW2[16], sB2v[1];
    __shared__ float sXG[64];

    int t = threadIdx.x;
    int bx = blockIdx.x & 15;
    int by = (blockIdx.x >> 4) & 31;
    int b = blockIdx.x >> 9;
    int x0 = bx * TW, y0 = by * TH;

    float gv[17];
    {
        float gs = 0.0f;
#pragma unroll
        for (int i = 0; i < 17; ++i) {
            float d = (float)i - 8.0f;
            gv[i] = expf(-(d * d) * 0.125f);
            gs += gv[i];
        }
        float inv = 1.0f / gs;
#pragma unroll
        for (int i = 0; i < 17; ++i) gv[i] *= inv;
    }

    if (t < 64) sXG[t] = xgv[b * 64 + t];
    if (t < 48) sW1[t] = gw1[t];
    if (t < 16) { sB1[t] = gb1[t]; sW2[t] = gw2[t]; }
    if (t == 0) sB2v[0] = gb2[0];
    __syncthreads();

    // fuse (== fuse_k): bg[b,d,px] = fub[d] + sum_c fuw[d,c]*relu(xg[c]+xl2[b,c,px])
    {
        float accd[8];
#pragma unroll
        for (int d = 0; d < 8; ++d) accd[d] = fub[d];
        const float* xp = xl2 + ((size_t)b << 14) + t;
        for (int c = 0; c < 64; ++c) {
            float f = fmaxf(sXG[c] + xp[c << 8], 0.0f);
#pragma unroll
            for (int d = 0; d < 8; ++d) accd[d] = fmaf(fuw[(d << 6) + c], f, accd[d]);
        }
#pragma unroll
        for (int d = 0; d < 8; ++d) sBG[(d << 8) + t] = accd[d];
    }

    if (t < 240) {
        int c = t / 80, xo = t % 80;
        int gx = reflect1024(x0 + xo - 8);
        const float* colp = lqs + (size_t)(b * 3 + c) * HH * WW + gx;
        float win[17];
#pragma unroll
        for (int i = 0; i < 16; ++i)
            win[i] = colp[(size_t)reflect1024(y0 - 8 + i) * WW];
#pragma unroll
        for (int j = 0; j < TH; ++j) {
            win[(16 + j) % 17] = colp[(size_t)reflect1024(y0 + 8 + j) * WW];
            float acc = 0.0f;
#pragma unroll
            for (int i = 0; i < 17; ++i) acc = fmaf(gv[i], win[(j + i) % 17], acc);
            sBH[c][j][xo] = acc;
        }
    }
    __syncthreads();

    int yy = t >> 3, xs = (t & 7) * 8;
    int Y = y0 + yy;
    float fy = fminf(fmaxf((Y + 0.5f) * (1.0f / 64.0f) + 3.5f, 0.0f), 15.0f);
    float yf = floorf(fy);
    int yi = (int)yf;
    float ay = fy - yf;
    int yi1 = min(yi + 1, 15);

    float bcv[3][8];
#pragma unroll
    for (int c = 0; c < 3; ++c) {
        float win[17];
#pragma unroll
        for (int i = 0; i < 16; ++i) win[i] = sBH[c][yy][xs + i];
#pragma unroll
        for (int j = 0; j < 8; ++j) {
            win[(16 + j) % 17] = sBH[c][yy][xs + 16 + j];
            float acc = 0.0f;
#pragma unroll
            for (int i = 0; i < 17; ++i) acc = fmaf(gv[i], win[(j + i) % 17], acc);
            bcv[c][j] = acc;
        }
    }

    float val[8];
#pragma unroll
    for (int j = 0; j < 8; ++j) {
        float b0 = bcv[0][j], b1 = bcv[1][j], b2 = bcv[2][j];
        float s = sB2v[0];
#pragma unroll
        for (int c = 0; c < 16; ++c) {
            float g1 = fmaf(sW1[c * 3 + 0], b0,
                       fmaf(sW1[c * 3 + 1], b1,
                       fmaf(sW1[c * 3 + 2], b2, sB1[c])));
            s = fmaf(sW2[c], fmaxf(g1, 0.0f), s);
        }
        float sig = 1.0f / (1.0f + expf(-s));
        float guide = sig * 2.0f - 0.5f;

        int X = x0 + xs + j;
        float fx = fminf(fmaxf((X + 0.5f) * (1.0f / 64.0f) + 3.5f, 0.0f), 15.0f);
        float fz = fminf(fmaxf(fmaf(guide, 4.0f, 3.5f), 0.0f), 7.0f);
        float xf = floorf(fx), zf = floorf(fz);
        int xi = (int)xf, zi = (int)zf;
        float ax = fx - xf, az = fz - zf;
        int xi1 = min(xi + 1, 15), zi1 = min(zi + 1, 7);

        const float* g0 = sBG + zi * 256;
        const float* g1p = sBG + zi1 * 256;
        int i00 = yi * 16 + xi, i01 = yi * 16 + xi1;
        int i10 = yi1 * 16 + xi, i11 = yi1 * 16 + xi1;
        float c00 = g0[i00] + az * (g1p[i00] - g0[i00]);
        float c01 = g0[i01] + az * (g1p[i01] - g0[i01]);
        float c10 = g0[i10] + az * (g1p[i10] - g0[i10]);
        float c11 = g0[i11] + az * (g1p[i11] - g0[i11]);
        float c0 = c00 + ay * (c10 - c00);
        float c1 = c01 + ay * (c11 - c01);
        val[j] = c0 + ax * (c1 - c0);
    }
    float4* op = (float4*)(out + (size_t)b * HH * WW + (size_t)Y * WW + x0 + xs);
    op[0] = make_float4(val[0], val[1], val[2], val[3]);
    op[1] = make_float4(val[4], val[5], val[6], val[7]);
}

// ---------------------------------------------------------------------------
extern "C" void kernel_launch(void* const* d_in, const int* in_sizes, int n_in,
                              void* d_out, int out_size, void* d_ws, size_t ws_size,
                              hipStream_t stream) {
    const float* lqs = (const float*)d_in[0];
    const float* evs = (const float*)d_in[1];
    const float* gw1 = (const float*)d_in[2];
    const float* gb1 = (const float*)d_in[3];
    const float* gw2 = (const float*)d_in[4];
    const float* gb2 = (const float*)d_in[5];
    const float* sw0 = (const float*)d_in[6];
    const float* sb0 = (const float*)d_in[7];
    const float* sw1 = (const float*)d_in[8];
    const float* sb1 = (const float*)d_in[9];
    const float* sw2 = (const float*)d_in[10];
    const float* sb2 = (const float*)d_in[11];
    const float* sw3 = (const float*)d_in[12];
    const float* sb3 = (const float*)d_in[13];
    const float* cw0 = (const float*)d_in[14];
    const float* cb0 = (const float*)d_in[15];
    const float* cw1 = (const float*)d_in[16];
    const float* cb1 = (const float*)d_in[17];
    const float* fw1 = (const float*)d_in[18];
    const float* fb1 = (const float*)d_in[19];
    const float* fw2 = (const float*)d_in[20];
    const float* fb2 = (const float*)d_in[21];
    const float* fw3 = (const float*)d_in[22];
    const float* fb3 = (const float*)d_in[23];
    const float* lw1 = (const float*)d_in[24];
    const float* lb1 = (const float*)d_in[25];
    const float* lw2 = (const float*)d_in[26];
    const float* fuw = (const float*)d_in[27];
    const float* fub = (const float*)d_in[28];
    float* out = (float*)d_out;

    float* ws = (float*)d_ws;
    float* o1  = ws;               // [8,16,64,64]   524288
    float* o3  = o1 + 524288;      // [8,64,16,16]   131072
    float* xl1 = o3 + 131072;      // [8,64,16,16]   131072
    float* xl2 = xl1 + 131072;     // [8,64,16,16]   131072
    float* xg0 = xl2 + 131072;     // [8,64,8,8]      32768
    float* xgv = xg0 + 32768;      // [8,64]            512
    // total ~0.95M floats = 3.8 MB

    conv01_k<<<512, 256, 0, stream>>>(lqs, evs, sw0, sb0, sw1, sb1, o1);
    conv23_k<<<128, 256, 0, stream>>>(o1, sw2, sb2, sw3, sb3, o3);
    lw1cw0_k<<<640, 256, 0, stream>>>(o3, lw1, lb1, cw0, cb0, xl1, xg0);
    lw2cw1fc_k<<<520, 256, 0, stream>>>(xl1, lw2, xg0, cw1, cb1,
                                        fw1, fb1, fw2, fb2, fw3, fb3, xl2, xgv);
    guide_slice_k<<<BATCH * 32 * 16, 256, 0, stream>>>(lqs, xl2, xgv, fuw, fub,
                                                       gw1, gb1, gw2, gb2, out);
}

// Round 3
// 573.077 us; speedup vs baseline: 1.5497x; 1.1039x over previous
//
#include <hip/hip_runtime.h>
#include <hip/hip_bf16.h>
#include <math.h>

#define BATCH 8
#define HH 1024
#define WW 1024

__device__ __forceinline__ int reflect1024(int i) {
    i = i < 0 ? -i : i;
    return i > 1023 ? 2046 - i : i;
}

// ---------------------------------------------------------------------------
// Generic 3x3 conv item (pad=1). One item = (b, oc, output px).
// Same per-output FMA order as the verified convN_k/stage_conv bodies.
// ---------------------------------------------------------------------------
template <int IC, int OC, int IH, int IW, int STRIDE, bool RELU, bool HASB>
__device__ __forceinline__ void conv_item(int r, const float* __restrict__ in,
                                          const float* __restrict__ w,
                                          const float* __restrict__ bias,
                                          float* __restrict__ out) {
    constexpr int OH = (IH + 2 - 3) / STRIDE + 1;
    constexpr int OW = (IW + 2 - 3) / STRIDE + 1;
    constexpr int POS = OH * OW;
    int px = r % POS;
    int oc = (r / POS) % OC;
    int b = r / (POS * OC);
    int ox = px % OW, oy = px / OW;
    int iy0 = oy * STRIDE - 1, ix0 = ox * STRIDE - 1;

    float acc = HASB ? bias[oc] : 0.0f;
    const float* ip = in + (size_t)b * IC * IH * IW;
    for (int ic = 0; ic < IC; ++ic) {
        const float* ipc = ip + ic * IH * IW;
        float x[9];
#pragma unroll
        for (int ky = 0; ky < 3; ++ky) {
            int iy = iy0 + ky;
#pragma unroll
            for (int kx = 0; kx < 3; ++kx) {
                int ix = ix0 + kx;
                bool ok = ((unsigned)iy < (unsigned)IH) && ((unsigned)ix < (unsigned)IW);
                x[ky * 3 + kx] = ok ? ipc[iy * IW + ix] : 0.0f;
            }
        }
        const float* wp = w + (oc * IC + ic) * 9;
#pragma unroll
        for (int k = 0; k < 9; ++k) acc = fmaf(wp[k], x[k], acc);
    }
    float v = RELU ? fmaxf(acc, 0.0f) : acc;
    out[(size_t)(b * OC + oc) * POS + px] = v;
}

// ---------------------------------------------------------------------------
// conv01_k: fused conv0 (18->8 @256 s2) + conv1 (8->16 @128 s2) -> o1
// [8,16,64,64].  512 blocks = b(8) x ty(8) x tx(8); o1 tile 8x8 per block.
// o0 tile (8ch x 17x17, incl. halo + zero-pad) computed into LDS.
// ---------------------------------------------------------------------------
__global__ __launch_bounds__(256) void conv01_k(const float* __restrict__ lqs,
                                                const float* __restrict__ evs,
                                                const float* __restrict__ sw0,
                                                const float* __restrict__ sb0,
                                                const float* __restrict__ sw1,
                                                const float* __restrict__ sb1,
                                                float* __restrict__ o1) {
    __shared__ float s0[8 * 289];  // [ic][yy*17+xx]
    int t = threadIdx.x;
    int blk = blockIdx.x;
    int tx = blk & 7, ty = (blk >> 3) & 7, b = blk >> 6;
    int oy0 = ty << 3, ox0 = tx << 3;            // o1 tile origin (64x64 grid)
    int iy0s = 2 * oy0 - 1, ix0s = 2 * ox0 - 1;  // o0 region origin (17x17)

    for (int p = t; p < 289; p += 256) {
        int yy = p / 17, xx = p - yy * 17;
        int iy = iy0s + yy, ix = ix0s + xx;      // o0 coords in [0,128)
        if ((unsigned)iy < 128u && (unsigned)ix < 128u) {
            float acc[8];
#pragma unroll
            for (int o = 0; o < 8; ++o) acc[o] = sb0[o];
#pragma unroll
            for (int ic = 0; ic < 3; ++ic) {
                const float* ipc = lqs + ((size_t)(b * 3 + ic) << 20);
#pragma unroll
                for (int ky = 0; ky < 3; ++ky) {
                    int r = 2 * iy - 1 + ky;
                    if ((unsigned)r >= 256u) continue;
                    const float* row = ipc + ((size_t)r << 12);  // nearest: row 4*r
#pragma unroll
                    for (int kx = 0; kx < 3; ++kx) {
                        int c = 2 * ix - 1 + kx;
                        if ((unsigned)c >= 256u) continue;
                        float v = row[c << 2];                    // nearest: col 4*c
                        const float* wp = sw0 + ic * 9 + ky * 3 + kx;
#pragma unroll
                        for (int o = 0; o < 8; ++o) acc[o] = fmaf(wp[o * 162], v, acc[o]);
                    }
                }
            }
            for (int ic = 0; ic < 15; ++ic) {
                const float* ipc = evs + ((size_t)(b * 15 + ic) << 16);
#pragma unroll
                for (int ky = 0; ky < 3; ++ky) {
                    int r = 2 * iy - 1 + ky;
                    if ((unsigned)r >= 256u) continue;
                    const float* row = ipc + (r << 8);
#pragma unroll
                    for (int kx = 0; kx < 3; ++kx) {
                        int c = 2 * ix - 1 + kx;
                        if ((unsigned)c >= 256u) continue;
                        float v = row[c];
                        const float* wp = sw0 + (ic + 3) * 9 + ky * 3 + kx;
#pragma unroll
                        for (int o = 0; o < 8; ++o) acc[o] = fmaf(wp[o * 162], v, acc[o]);
                    }
                }
            }
#pragma unroll
            for (int o = 0; o < 8; ++o) s0[o * 289 + p] = fmaxf(acc[o], 0.0f);
        } else {
#pragma unroll
            for (int o = 0; o < 8; ++o) s0[o * 289 + p] = 0.0f;
        }
    }
    __syncthreads();

    // conv1: thread t -> px = t&63 (8x8), oc group = t>>6 (4 oc each)
    int px = t & 63, ocg = t >> 6;
    int lpy = px >> 3, lpx = px & 7;
    float a1[4];
#pragma unroll
    for (int o = 0; o < 4; ++o) a1[o] = sb1[ocg * 4 + o];
#pragma unroll
    for (int ic = 0; ic < 8; ++ic) {
        const float* sp = s0 + ic * 289 + (2 * lpy) * 17 + 2 * lpx;
        float x[9];
#pragma unroll
        for (int ky = 0; ky < 3; ++ky)
#pragma unroll
            for (int kx = 0; kx < 3; ++kx) x[ky * 3 + kx] = sp[ky * 17 + kx];
#pragma unroll
        for (int o = 0; o < 4; ++o) {
            const float* wp = sw1 + ((ocg * 4 + o) * 8 + ic) * 9;
#pragma unroll
            for (int k = 0; k < 9; ++k) a1[o] = fmaf(wp[k], x[k], a1[o]);
        }
    }
    int oy = oy0 + lpy, ox = ox0 + lpx;
#pragma unroll
    for (int o = 0; o < 4; ++o)
        o1[((size_t)(b * 16 + ocg * 4 + o) << 12) + (oy << 6) + ox] = fmaxf(a1[o], 0.0f);
}

// ---------------------------------------------------------------------------
// conv23_k: fused conv2 (16->32 @64 s2) + conv3 (32->64 @32 s2) -> o3
// [8,64,16,16].  512 blocks = b(8) x ty(8) x tx(8); o3 tile 2x2 per block.
// o2 region (32ch x 5x5, incl. halo + zero-pad) in LDS.
// ---------------------------------------------------------------------------
__global__ __launch_bounds__(256) void conv23_k(const float* __restrict__ o1,
                                                const float* __restrict__ sw2,
                                                const float* __restrict__ sb2,
                                                const float* __restrict__ sw3,
                                                const float* __restrict__ sb3,
                                                float* __restrict__ o3) {
    __shared__ float s2[32 * 25];  // [ic][yy*5+xx]
    int t = threadIdx.x;
    int blk = blockIdx.x;
    int tx = blk & 7, ty = (blk >> 3) & 7, b = blk >> 6;
    int oy0 = ty << 1, ox0 = tx << 1;            // o3 tile origin (16x16 grid)
    int iy0s = 2 * oy0 - 1, ix0s = 2 * ox0 - 1;  // o2 region origin (5x5)

    // o2 region: 25 px x 4 oc-groups (8 oc each) = 100 items
    if (t < 100) {
        int ocg = t / 25, p = t - ocg * 25;
        int yy = p / 5, xx = p - yy * 5;
        int iy = iy0s + yy, ix = ix0s + xx;      // o2 coords in [0,32)
        if ((unsigned)iy < 32u && (unsigned)ix < 32u) {
            float acc[8];
#pragma unroll
            for (int o = 0; o < 8; ++o) acc[o] = sb2[ocg * 8 + o];
            const float* ip = o1 + ((size_t)b << 16);
            int ry0 = 2 * iy - 1, rx0 = 2 * ix - 1;
            for (int ic = 0; ic < 16; ++ic) {
                const float* ipc = ip + (ic << 12);
                float x[9];
#pragma unroll
                for (int ky = 0; ky < 3; ++ky) {
                    int r = ry0 + ky;
#pragma unroll
                    for (int kx = 0; kx < 3; ++kx) {
                        int c = rx0 + kx;
                        bool ok = ((unsigned)r < 64u) && ((unsigned)c < 64u);
                        x[ky * 3 + kx] = ok ? ipc[(r << 6) + c] : 0.0f;
                    }
                }
#pragma unroll
                for (int o = 0; o < 8; ++o) {
                    const float* wp = sw2 + ((ocg * 8 + o) * 16 + ic) * 9;
#pragma unroll
                    for (int k = 0; k < 9; ++k) acc[o] = fmaf(wp[k], x[k], acc[o]);
                }
            }
#pragma unroll
            for (int o = 0; o < 8; ++o) s2[(ocg * 8 + o) * 25 + p] = fmaxf(acc[o], 0.0f);
        } else {
#pragma unroll
            for (int o = 0; o < 8; ++o) s2[(ocg * 8 + o) * 25 + p] = 0.0f;
        }
    }
    __syncthreads();

    // conv3: thread t -> oc = t>>2, p2 = t&3 (2x2), 1 output each
    int oc = t >> 2, p2 = t & 3;
    int py = p2 >> 1, pxx = p2 & 1;
    float a3 = sb3[oc];
    for (int ic = 0; ic < 32; ++ic) {
        const float* wp = sw3 + (oc * 32 + ic) * 9;
        const float* sp = s2 + ic * 25 + (2 * py) * 5 + 2 * pxx;
#pragma unroll
        for (int ky = 0; ky < 3; ++ky)
#pragma unroll
            for (int kx = 0; kx < 3; ++kx)
                a3 = fmaf(wp[ky * 3 + kx], sp[ky * 5 + kx], a3);
    }
    o3[((size_t)(b * 64 + oc) << 8) + ((oy0 + py) << 4) + (ox0 + pxx)] = fmaxf(a3, 0.0f);
}

// ---------------------------------------------------------------------------
// lw1cw0_k: lw1 (64->64 @16 s1, relu) on blocks 0..511; cw0 (64->64 @16 s2,
// relu) on blocks 512..639. Both read o3.
// ---------------------------------------------------------------------------
__global__ __launch_bounds__(256) void lw1cw0_k(const float* __restrict__ o3,
                                                const float* __restrict__ lw1,
                                                const float* __restrict__ lb1,
                                                const float* __restrict__ cw0,
                                                const float* __restrict__ cb0,
                                                float* __restrict__ xl1,
                                                float* __restrict__ xg0) {
    int blk = blockIdx.x;
    if (blk < 512) {
        conv_item<64, 64, 16, 16, 1, true, true>(blk * 256 + threadIdx.x, o3, lw1, lb1, xl1);
    } else {
        conv_item<64, 64, 16, 16, 2, true, true>((blk - 512) * 256 + threadIdx.x, o3, cw0, cb0, xg0);
    }
}

// ---------------------------------------------------------------------------
// lw2cw1fc1_k: lw2 (64->64 @16 s1, no bias/relu) on blocks 0..511 -> xl2;
// blocks 512..575 (8 per batch): LDS-stage xg0[b], redundantly compute cw1
// (+cb1+relu) -> sX, then fc1 for this block's 32 rows -> h1[b,256].
// fc1 math identical to the round-0-verified fc1_k (same chunking+butterfly).
// ---------------------------------------------------------------------------
__global__ __launch_bounds__(256) void lw2cw1fc1_k(const float* __restrict__ xl1,
                                                   const float* __restrict__ lw2,
                                                   const float* __restrict__ xg0,
                                                   const float* __restrict__ cw1,
                                                   const float* __restrict__ cb1,
                                                   const float* __restrict__ fw1,
                                                   const float* __restrict__ fb1,
                                                   float* __restrict__ xl2,
                                                   float* __restrict__ h1) {
    int blk = blockIdx.x, t = threadIdx.x;
    if (blk < 512) {
        conv_item<64, 64, 16, 16, 1, false, false>(blk * 256 + t, xl1, lw2, nullptr, xl2);
        return;
    }
    int rg2 = blk - 512;           // 0..63
    int b = rg2 >> 3, rg = rg2 & 7;
    __shared__ __align__(16) float sG[4096];   // xg0[b] : [64][8][8]
    __shared__ __align__(16) float sX[1024];   // cw1 out (flat oc*16+px)

#pragma unroll
    for (int j = 0; j < 16; ++j) sG[t + (j << 8)] = xg0[((size_t)b << 12) + t + (j << 8)];
    __syncthreads();

    // cw1: 4 items/thread, item = oc*16 + px (matches xg1 flatten order)
#pragma unroll
    for (int j = 0; j < 4; ++j) {
        int item = t + (j << 8);
        int oc = item >> 4, px = item & 15;
        int oy = px >> 2, ox = px & 3;
        int iy0 = 2 * oy - 1, ix0 = 2 * ox - 1;
        float acc = cb1[oc];
        for (int ic = 0; ic < 64; ++ic) {
            const float* ipc = sG + (ic << 6);
            const float* wp = cw1 + (oc * 64 + ic) * 9;
#pragma unroll
            for (int ky = 0; ky < 3; ++ky) {
                int r = iy0 + ky;
#pragma unroll
                for (int kx = 0; kx < 3; ++kx) {
                    int c = ix0 + kx;
                    bool ok = ((unsigned)r < 8u) && ((unsigned)c < 8u);
                    float x = ok ? ipc[(r << 3) + c] : 0.0f;
                    acc = fmaf(wp[ky * 3 + kx], x, acc);
                }
            }
        }
        sX[item] = fmaxf(acc, 0.0f);
    }
    __syncthreads();

    // fc1: this block's rows = rg*32 .. rg*32+31; wave-per-row, 8 rows/wave
    int wave = t >> 6, lane = t & 63;
    const float4* x4 = (const float4*)sX;
#pragma unroll
    for (int k = 0; k < 8; ++k) {
        int r = (rg << 5) + (wave << 3) + k;
        const float4* w4 = (const float4*)(fw1 + (size_t)r * 1024);
        float acc = 0.0f;
#pragma unroll
        for (int jj = 0; jj < 4; ++jj) {
            float4 wv = w4[lane + 64 * jj];
            float4 xv = x4[lane + 64 * jj];
            acc = fmaf(wv.x, xv.x, acc);
            acc = fmaf(wv.y, xv.y, acc);
            acc = fmaf(wv.z, xv.z, acc);
            acc = fmaf(wv.w, xv.w, acc);
        }
#pragma unroll
        for (int m = 32; m; m >>= 1) acc += __shfl_xor(acc, m, 64);
        if (lane == 0) h1[b * 256 + r] = fmaxf(acc + fb1[r], 0.0f);
    }
}

// ---------------------------------------------------------------------------
// guide+slice with fc2+fc3+fuse folded in as prologue (redundant per block,
// identical arithmetic to the verified fc2/fc3/fuse paths). sH1/sH2 overlay
// the sBG region (sBG only written after fc3 completes) to keep LDS at 39936.
// ---------------------------------------------------------------------------
__global__ __launch_bounds__(256) void guide_slice_k(const float* __restrict__ lqs,
                                                     const float* __restrict__ xl2,
                                                     const float* __restrict__ h1g,
                                                     const float* __restrict__ fw2,
                                                     const float* __restrict__ fb2,
                                                     const float* __restrict__ fw3,
                                                     const float* __restrict__ fb3,
                                                     const float* __restrict__ fuw,
                                                     const float* __restrict__ fub,
                                                     const float* __restrict__ gw1,
                                                     const float* __restrict__ gb1,
                                                     const float* __restrict__ gw2,
                                                     const float* __restrict__ gb2,
                                                     float* __restrict__ out) {
    constexpr int TW = 64, TH = 32;
    __shared__ float sBH[3][TH][81];
    __shared__ __align__(16) float sBG[2048];
    __shared__ float sW1[48], sB1[16], sW2[16], sB2v[1];
    __shared__ float sXG[64];
    float* sH1 = sBG;          // overlay: live only before fuse writes sBG
    float* sH2 = sBG + 256;

    int t = threadIdx.x;
    int bx = blockIdx.x & 15;
    int by = (blockIdx.x >> 4) & 31;
    int b = blockIdx.x >> 9;
    int x0 = bx * TW, y0 = by * TH;

    float gv[17];
    {
        float gs = 0.0f;
#pragma unroll
        for (int i = 0; i < 17; ++i) {
            float d = (float)i - 8.0f;
            gv[i] = expf(-(d * d) * 0.125f);
            gs += gv[i];
        }
        float inv = 1.0f / gs;
#pragma unroll
        for (int i = 0; i < 17; ++i) gv[i] *= inv;
    }

    sH1[t] = h1g[b * 256 + t];
    if (t < 48) sW1[t] = gw1[t];
    if (t < 16) { sB1[t] = gb1[t]; sW2[t] = gw2[t]; }
    if (t == 0) sB2v[0] = gb2[0];
    __syncthreads();

    // fc2: h2[r] = relu(fw2[r,:].h1 + fb2[r])
    if (t < 128) {
        const float4* w4 = (const float4*)(fw2 + (size_t)t * 256);
        const float4* x4 = (const float4*)sH1;
        float a[4] = {0.f, 0.f, 0.f, 0.f};
#pragma unroll 4
        for (int j = 0; j < 64; ++j) {
            float4 wv = w4[j], xv = x4[j];
            a[j & 3] = fmaf(wv.x, xv.x, fmaf(wv.y, xv.y,
                       fmaf(wv.z, xv.z, fmaf(wv.w, xv.w, a[j & 3]))));
        }
        sH2[t] = fmaxf(a[0] + a[1] + a[2] + a[3] + fb2[t], 0.0f);
    }
    __syncthreads();
    // fc3: xg[r] = fw3[r,:].h2 + fb3[r]
    if (t < 64) {
        const float4* w4 = (const float4*)(fw3 + (size_t)t * 128);
        const float4* x4 = (const float4*)sH2;
        float a[4] = {0.f, 0.f, 0.f, 0.f};
#pragma unroll 4
        for (int j = 0; j < 32; ++j) {
            float4 wv = w4[j], xv = x4[j];
            a[j & 3] = fmaf(wv.x, xv.x, fmaf(wv.y, xv.y,
                       fmaf(wv.z, xv.z, fmaf(wv.w, xv.w, a[j & 3]))));
        }
        sXG[t] = a[0] + a[1] + a[2] + a[3] + fb3[t];
    }
    __syncthreads();

    // fuse: bg[b,d,px] = fub[d] + sum_c fuw[d,c]*relu(xg[c]+xl2[b,c,px])
    {
        float accd[8];
#pragma unroll
        for (int d = 0; d < 8; ++d) accd[d] = fub[d];
        const float* xp = xl2 + ((size_t)b << 14) + t;
        for (int c = 0; c < 64; ++c) {
            float f = fmaxf(sXG[c] + xp[c << 8], 0.0f);
#pragma unroll
            for (int d = 0; d < 8; ++d) accd[d] = fmaf(fuw[(d << 6) + c], f, accd[d]);
        }
#pragma unroll
        for (int d = 0; d < 8; ++d) sBG[(d << 8) + t] = accd[d];
    }

    if (t < 240) {
        int c = t / 80, xo = t % 80;
        int gx = reflect1024(x0 + xo - 8);
        const float* colp = lqs + (size_t)(b * 3 + c) * HH * WW + gx;
        float win[17];
#pragma unroll
        for (int i = 0; i < 16; ++i)
            win[i] = colp[(size_t)reflect1024(y0 - 8 + i) * WW];
#pragma unroll
        for (int j = 0; j < TH; ++j) {
            win[(16 + j) % 17] = colp[(size_t)reflect1024(y0 + 8 + j) * WW];
            float acc = 0.0f;
#pragma unroll
            for (int i = 0; i < 17; ++i) acc = fmaf(gv[i], win[(j + i) % 17], acc);
            sBH[c][j][xo] = acc;
        }
    }
    __syncthreads();

    int yy = t >> 3, xs = (t & 7) * 8;
    int Y = y0 + yy;
    float fy = fminf(fmaxf((Y + 0.5f) * (1.0f / 64.0f) + 3.5f, 0.0f), 15.0f);
    float yf = floorf(fy);
    int yi = (int)yf;
    float ay = fy - yf;
    int yi1 = min(yi + 1, 15);

    float bcv[3][8];
#pragma unroll
    for (int c = 0; c < 3; ++c) {
        float win[17];
#pragma unroll
        for (int i = 0; i < 16; ++i) win[i] = sBH[c][yy][xs + i];
#pragma unroll
        for (int j = 0; j < 8; ++j) {
            win[(16 + j) % 17] = sBH[c][yy][xs + 16 + j];
            float acc = 0.0f;
#pragma unroll
            for (int i = 0; i < 17; ++i) acc = fmaf(gv[i], win[(j + i) % 17], acc);
            bcv[c][j] = acc;
        }
    }

    float val[8];
#pragma unroll
    for (int j = 0; j < 8; ++j) {
        float b0 = bcv[0][j], b1 = bcv[1][j], b2 = bcv[2][j];
        float s = sB2v[0];
#pragma unroll
        for (int c = 0; c < 16; ++c) {
            float g1 = fmaf(sW1[c * 3 + 0], b0,
                       fmaf(sW1[c * 3 + 1], b1,
                       fmaf(sW1[c * 3 + 2], b2, sB1[c])));
            s = fmaf(sW2[c], fmaxf(g1, 0.0f), s);
        }
        float sig = 1.0f / (1.0f + expf(-s));
        float guide = sig * 2.0f - 0.5f;

        int X = x0 + xs + j;
        float fx = fminf(fmaxf((X + 0.5f) * (1.0f / 64.0f) + 3.5f, 0.0f), 15.0f);
        float fz = fminf(fmaxf(fmaf(guide, 4.0f, 3.5f), 0.0f), 7.0f);
        float xf = floorf(fx), zf = floorf(fz);
        int xi = (int)xf, zi = (int)zf;
        float ax = fx - xf, az = fz - zf;
        int xi1 = min(xi + 1, 15), zi1 = min(zi + 1, 7);

        const float* g0 = sBG + zi * 256;
        const float* g1p = sBG + zi1 * 256;
        int i00 = yi * 16 + xi, i01 = yi * 16 + xi1;
        int i10 = yi1 * 16 + xi, i11 = yi1 * 16 + xi1;
        float c00 = g0[i00] + az * (g1p[i00] - g0[i00]);
        float c01 = g0[i01] + az * (g1p[i01] - g0[i01]);
        float c10 = g0[i10] + az * (g1p[i10] - g0[i10]);
        float c11 = g0[i11] + az * (g1p[i11] - g0[i11]);
        float c0 = c00 + ay * (c10 - c00);
        float c1 = c01 + ay * (c11 - c01);
        val[j] = c0 + ax * (c1 - c0);
    }
    float4* op = (float4*)(out + (size_t)b * HH * WW + (size_t)Y * WW + x0 + xs);
    op[0] = make_float4(val[0], val[1], val[2], val[3]);
    op[1] = make_float4(val[4], val[5], val[6], val[7]);
}

// ---------------------------------------------------------------------------
extern "C" void kernel_launch(void* const* d_in, const int* in_sizes, int n_in,
                              void* d_out, int out_size, void* d_ws, size_t ws_size,
                              hipStream_t stream) {
    const float* lqs = (const float*)d_in[0];
    const float* evs = (const float*)d_in[1];
    const float* gw1 = (const float*)d_in[2];
    const float* gb1 = (const float*)d_in[3];
    const float* gw2 = (const float*)d_in[4];
    const float* gb2 = (const float*)d_in[5];
    const float* sw0 = (const float*)d_in[6];
    const float* sb0 = (const float*)d_in[7];
    const float* sw1 = (const float*)d_in[8];
    const float* sb1 = (const float*)d_in[9];
    const float* sw2 = (const float*)d_in[10];
    const float* sb2 = (const float*)d_in[11];
    const float* sw3 = (const float*)d_in[12];
    const float* sb3 = (const float*)d_in[13];
    const float* cw0 = (const float*)d_in[14];
    const float* cb0 = (const float*)d_in[15];
    const float* cw1 = (const float*)d_in[16];
    const float* cb1 = (const float*)d_in[17];
    const float* fw1 = (const float*)d_in[18];
    const float* fb1 = (const float*)d_in[19];
    const float* fw2 = (const float*)d_in[20];
    const float* fb2 = (const float*)d_in[21];
    const float* fw3 = (const float*)d_in[22];
    const float* fb3 = (const float*)d_in[23];
    const float* lw1 = (const float*)d_in[24];
    const float* lb1 = (const float*)d_in[25];
    const float* lw2 = (const float*)d_in[26];
    const float* fuw = (const float*)d_in[27];
    const float* fub = (const float*)d_in[28];
    float* out = (float*)d_out;

    float* ws = (float*)d_ws;
    float* o1  = ws;               // [8,16,64,64]   524288
    float* o3  = o1 + 524288;      // [8,64,16,16]   131072
    float* xl1 = o3 + 131072;      // [8,64,16,16]   131072
    float* xl2 = xl1 + 131072;     // [8,64,16,16]   131072
    float* xg0 = xl2 + 131072;     // [8,64,8,8]      32768
    float* h1  = xg0 + 32768;      // [8,256]          2048
    // total ~0.95M floats = 3.8 MB

    conv01_k<<<512, 256, 0, stream>>>(lqs, evs, sw0, sb0, sw1, sb1, o1);
    conv23_k<<<512, 256, 0, stream>>>(o1, sw2, sb2, sw3, sb3, o3);
    lw1cw0_k<<<640, 256, 0, stream>>>(o3, lw1, lb1, cw0, cb0, xl1, xg0);
    lw2cw1fc1_k<<<576, 256, 0, stream>>>(xl1, lw2, xg0, cw1, cb1, fw1, fb1, xl2, h1);
    guide_slice_k<<<BATCH * 32 * 16, 256, 0, stream>>>(lqs, xl2, h1, fw2, fb2, fw3, fb3,
                                                       fuw, fub, gw1, gb1, gw2, gb2, out);
}

// Round 6
// 497.046 us; speedup vs baseline: 1.7867x; 1.1530x over previous
//
#include <hip/hip_runtime.h>
#include <hip/hip_bf16.h>
#include <math.h>

#define BATCH 8
#define HH 1024
#define WW 1024

__device__ __forceinline__ int reflect1024(int i) {
    i = i < 0 ? -i : i;
    return i > 1023 ? 2046 - i : i;
}

// ---------------------------------------------------------------------------
// Generic 3x3 conv item (pad=1). One item = (b, oc, output px).
// Same per-output FMA order as the verified convN_k/stage_conv bodies.
// ---------------------------------------------------------------------------
template <int IC, int OC, int IH, int IW, int STRIDE, bool RELU, bool HASB>
__device__ __forceinline__ void conv_item(int r, const float* __restrict__ in,
                                          const float* __restrict__ w,
                                          const float* __restrict__ bias,
                                          float* __restrict__ out) {
    constexpr int OH = (IH + 2 - 3) / STRIDE + 1;
    constexpr int OW = (IW + 2 - 3) / STRIDE + 1;
    constexpr int POS = OH * OW;
    int px = r % POS;
    int oc = (r / POS) % OC;
    int b = r / (POS * OC);
    int ox = px % OW, oy = px / OW;
    int iy0 = oy * STRIDE - 1, ix0 = ox * STRIDE - 1;

    float acc = HASB ? bias[oc] : 0.0f;
    const float* ip = in + (size_t)b * IC * IH * IW;
    for (int ic = 0; ic < IC; ++ic) {
        const float* ipc = ip + ic * IH * IW;
        float x[9];
#pragma unroll
        for (int ky = 0; ky < 3; ++ky) {
            int iy = iy0 + ky;
#pragma unroll
            for (int kx = 0; kx < 3; ++kx) {
                int ix = ix0 + kx;
                bool ok = ((unsigned)iy < (unsigned)IH) && ((unsigned)ix < (unsigned)IW);
                x[ky * 3 + kx] = ok ? ipc[iy * IW + ix] : 0.0f;
            }
        }
        const float* wp = w + (oc * IC + ic) * 9;
#pragma unroll
        for (int k = 0; k < 9; ++k) acc = fmaf(wp[k], x[k], acc);
    }
    float v = RELU ? fmaxf(acc, 0.0f) : acc;
    out[(size_t)(b * OC + oc) * POS + px] = v;
}

// ---------------------------------------------------------------------------
// conv01_k: fused conv0 (18->8 @256 s2) + conv1 (8->16 @128 s2) -> o1
// [8,16,64,64].  512 blocks = b(8) x ty(8) x tx(8); o1 tile 8x8 per block.
// o0 tile (8ch x 17x17, incl. halo + zero-pad) computed into LDS.
// ---------------------------------------------------------------------------
__global__ __launch_bounds__(256) void conv01_k(const float* __restrict__ lqs,
                                                const float* __restrict__ evs,
                                                const float* __restrict__ sw0,
                                                const float* __restrict__ sb0,
                                                const float* __restrict__ sw1,
                                                const float* __restrict__ sb1,
                                                float* __restrict__ o1) {
    __shared__ float s0[8 * 289];  // [ic][yy*17+xx]
    int t = threadIdx.x;
    int blk = blockIdx.x;
    int tx = blk & 7, ty = (blk >> 3) & 7, b = blk >> 6;
    int oy0 = ty << 3, ox0 = tx << 3;            // o1 tile origin (64x64 grid)
    int iy0s = 2 * oy0 - 1, ix0s = 2 * ox0 - 1;  // o0 region origin (17x17)

    for (int p = t; p < 289; p += 256) {
        int yy = p / 17, xx = p - yy * 17;
        int iy = iy0s + yy, ix = ix0s + xx;      // o0 coords in [0,128)
        if ((unsigned)iy < 128u && (unsigned)ix < 128u) {
            float acc[8];
#pragma unroll
            for (int o = 0; o < 8; ++o) acc[o] = sb0[o];
#pragma unroll
            for (int ic = 0; ic < 3; ++ic) {
                const float* ipc = lqs + ((size_t)(b * 3 + ic) << 20);
#pragma unroll
                for (int ky = 0; ky < 3; ++ky) {
                    int r = 2 * iy - 1 + ky;
                    if ((unsigned)r >= 256u) continue;
                    const float* row = ipc + ((size_t)r << 12);  // nearest: row 4*r
#pragma unroll
                    for (int kx = 0; kx < 3; ++kx) {
                        int c = 2 * ix - 1 + kx;
                        if ((unsigned)c >= 256u) continue;
                        float v = row[c << 2];                    // nearest: col 4*c
                        const float* wp = sw0 + ic * 9 + ky * 3 + kx;
#pragma unroll
                        for (int o = 0; o < 8; ++o) acc[o] = fmaf(wp[o * 162], v, acc[o]);
                    }
                }
            }
            for (int ic = 0; ic < 15; ++ic) {
                const float* ipc = evs + ((size_t)(b * 15 + ic) << 16);
#pragma unroll
                for (int ky = 0; ky < 3; ++ky) {
                    int r = 2 * iy - 1 + ky;
                    if ((unsigned)r >= 256u) continue;
                    const float* row = ipc + (r << 8);
#pragma unroll
                    for (int kx = 0; kx < 3; ++kx) {
                        int c = 2 * ix - 1 + kx;
                        if ((unsigned)c >= 256u) continue;
                        float v = row[c];
                        const float* wp = sw0 + (ic + 3) * 9 + ky * 3 + kx;
#pragma unroll
                        for (int o = 0; o < 8; ++o) acc[o] = fmaf(wp[o * 162], v, acc[o]);
                    }
                }
            }
#pragma unroll
            for (int o = 0; o < 8; ++o) s0[o * 289 + p] = fmaxf(acc[o], 0.0f);
        } else {
#pragma unroll
            for (int o = 0; o < 8; ++o) s0[o * 289 + p] = 0.0f;
        }
    }
    __syncthreads();

    // conv1: thread t -> px = t&63 (8x8), oc group = t>>6 (4 oc each)
    int px = t & 63, ocg = t >> 6;
    int lpy = px >> 3, lpx = px & 7;
    float a1[4];
#pragma unroll
    for (int o = 0; o < 4; ++o) a1[o] = sb1[ocg * 4 + o];
#pragma unroll
    for (int ic = 0; ic < 8; ++ic) {
        const float* sp = s0 + ic * 289 + (2 * lpy) * 17 + 2 * lpx;
        float x[9];
#pragma unroll
        for (int ky = 0; ky < 3; ++ky)
#pragma unroll
            for (int kx = 0; kx < 3; ++kx) x[ky * 3 + kx] = sp[ky * 17 + kx];
#pragma unroll
        for (int o = 0; o < 4; ++o) {
            const float* wp = sw1 + ((ocg * 4 + o) * 8 + ic) * 9;
#pragma unroll
            for (int k = 0; k < 9; ++k) a1[o] = fmaf(wp[k], x[k], a1[o]);
        }
    }
    int oy = oy0 + lpy, ox = ox0 + lpx;
#pragma unroll
    for (int o = 0; o < 4; ++o)
        o1[((size_t)(b * 16 + ocg * 4 + o) << 12) + (oy << 6) + ox] = fmaxf(a1[o], 0.0f);
}

// ---------------------------------------------------------------------------
// conv23_k: fused conv2 (16->32 @64 s2) + conv3 (32->64 @32 s2) -> o3
// [8,64,16,16].  512 blocks = b(8) x ty(8) x tx(8); o3 tile 2x2 per block.
// o2 region (32ch x 5x5, incl. halo + zero-pad) in LDS.
// ---------------------------------------------------------------------------
__global__ __launch_bounds__(256) void conv23_k(const float* __restrict__ o1,
                                                const float* __restrict__ sw2,
                                                const float* __restrict__ sb2,
                                                const float* __restrict__ sw3,
                                                const float* __restrict__ sb3,
                                                float* __restrict__ o3) {
    __shared__ float s2[32 * 25];  // [ic][yy*5+xx]
    int t = threadIdx.x;
    int blk = blockIdx.x;
    int tx = blk & 7, ty = (blk >> 3) & 7, b = blk >> 6;
    int oy0 = ty << 1, ox0 = tx << 1;            // o3 tile origin (16x16 grid)
    int iy0s = 2 * oy0 - 1, ix0s = 2 * ox0 - 1;  // o2 region origin (5x5)

    // o2 region: 25 px x 4 oc-groups (8 oc each) = 100 items
    if (t < 100) {
        int ocg = t / 25, p = t - ocg * 25;
        int yy = p / 5, xx = p - yy * 5;
        int iy = iy0s + yy, ix = ix0s + xx;      // o2 coords in [0,32)
        if ((unsigned)iy < 32u && (unsigned)ix < 32u) {
            float acc[8];
#pragma unroll
            for (int o = 0; o < 8; ++o) acc[o] = sb2[ocg * 8 + o];
            const float* ip = o1 + ((size_t)b << 16);
            int ry0 = 2 * iy - 1, rx0 = 2 * ix - 1;
            for (int ic = 0; ic < 16; ++ic) {
                const float* ipc = ip + (ic << 12);
                float x[9];
#pragma unroll
                for (int ky = 0; ky < 3; ++ky) {
                    int r = ry0 + ky;
#pragma unroll
                    for (int kx = 0; kx < 3; ++kx) {
                        int c = rx0 + kx;
                        bool ok = ((unsigned)r < 64u) && ((unsigned)c < 64u);
                        x[ky * 3 + kx] = ok ? ipc[(r << 6) + c] : 0.0f;
                    }
                }
#pragma unroll
                for (int o = 0; o < 8; ++o) {
                    const float* wp = sw2 + ((ocg * 8 + o) * 16 + ic) * 9;
#pragma unroll
                    for (int k = 0; k < 9; ++k) acc[o] = fmaf(wp[k], x[k], acc[o]);
                }
            }
#pragma unroll
            for (int o = 0; o < 8; ++o) s2[(ocg * 8 + o) * 25 + p] = fmaxf(acc[o], 0.0f);
        } else {
#pragma unroll
            for (int o = 0; o < 8; ++o) s2[(ocg * 8 + o) * 25 + p] = 0.0f;
        }
    }
    __syncthreads();

    // conv3: thread t -> oc = t>>2, p2 = t&3 (2x2), 1 output each
    int oc = t >> 2, p2 = t & 3;
    int py = p2 >> 1, pxx = p2 & 1;
    float a3 = sb3[oc];
    for (int ic = 0; ic < 32; ++ic) {
        const float* wp = sw3 + (oc * 32 + ic) * 9;
        const float* sp = s2 + ic * 25 + (2 * py) * 5 + 2 * pxx;
#pragma unroll
        for (int ky = 0; ky < 3; ++ky)
#pragma unroll
            for (int kx = 0; kx < 3; ++kx)
                a3 = fmaf(wp[ky * 3 + kx], sp[ky * 5 + kx], a3);
    }
    o3[((size_t)(b * 64 + oc) << 8) + ((oy0 + py) << 4) + (ox0 + pxx)] = fmaxf(a3, 0.0f);
}

// ---------------------------------------------------------------------------
// lw1cw0_k: lw1 (64->64 @16 s1, relu) on blocks 0..511; cw0 (64->64 @16 s2,
// relu) on blocks 512..639. Both read o3.
// ---------------------------------------------------------------------------
__global__ __launch_bounds__(256) void lw1cw0_k(const float* __restrict__ o3,
                                                const float* __restrict__ lw1,
                                                const float* __restrict__ lb1,
                                                const float* __restrict__ cw0,
                                                const float* __restrict__ cb0,
                                                float* __restrict__ xl1,
                                                float* __restrict__ xg0) {
    int blk = blockIdx.x;
    if (blk < 512) {
        conv_item<64, 64, 16, 16, 1, true, true>(blk * 256 + threadIdx.x, o3, lw1, lb1, xl1);
    } else {
        conv_item<64, 64, 16, 16, 2, true, true>((blk - 512) * 256 + threadIdx.x, o3, cw0, cb0, xg0);
    }
}

// ---------------------------------------------------------------------------
// lw2cw1fc1_k: lw2 (64->64 @16 s1, no bias/relu) on blocks 0..511 -> xl2;
// blocks 512..575 (8 per batch): LDS-stage xg0[b], redundantly compute cw1
// (+cb1+relu) -> sX, then fc1 for this block's 32 rows -> h1[b,256].
// fc1 math identical to the round-0-verified fc1_k (same chunking+butterfly).
// ---------------------------------------------------------------------------
__global__ __launch_bounds__(256) void lw2cw1fc1_k(const float* __restrict__ xl1,
                                                   const float* __restrict__ lw2,
                                                   const float* __restrict__ xg0,
                                                   const float* __restrict__ cw1,
                                                   const float* __restrict__ cb1,
                                                   const float* __restrict__ fw1,
                                                   const float* __restrict__ fb1,
                                                   float* __restrict__ xl2,
                                                   float* __restrict__ h1) {
    int blk = blockIdx.x, t = threadIdx.x;
    if (blk < 512) {
        conv_item<64, 64, 16, 16, 1, false, false>(blk * 256 + t, xl1, lw2, nullptr, xl2);
        return;
    }
    int rg2 = blk - 512;           // 0..63
    int b = rg2 >> 3, rg = rg2 & 7;
    __shared__ __align__(16) float sG[4096];   // xg0[b] : [64][8][8]
    __shared__ __align__(16) float sX[1024];   // cw1 out (flat oc*16+px)

#pragma unroll
    for (int j = 0; j < 16; ++j) sG[t + (j << 8)] = xg0[((size_t)b << 12) + t + (j << 8)];
    __syncthreads();

    // cw1: 4 items/thread, item = oc*16 + px (matches xg1 flatten order)
#pragma unroll
    for (int j = 0; j < 4; ++j) {
        int item = t + (j << 8);
        int oc = item >> 4, px = item & 15;
        int oy = px >> 2, ox = px & 3;
        int iy0 = 2 * oy - 1, ix0 = 2 * ox - 1;
        float acc = cb1[oc];
        for (int ic = 0; ic < 64; ++ic) {
            const float* ipc = sG + (ic << 6);
            const float* wp = cw1 + (oc * 64 + ic) * 9;
#pragma unroll
            for (int ky = 0; ky < 3; ++ky) {
                int r = iy0 + ky;
#pragma unroll
                for (int kx = 0; kx < 3; ++kx) {
                    int c = ix0 + kx;
                    bool ok = ((unsigned)r < 8u) && ((unsigned)c < 8u);
                    float x = ok ? ipc[(r << 3) + c] : 0.0f;
                    acc = fmaf(wp[ky * 3 + kx], x, acc);
                }
            }
        }
        sX[item] = fmaxf(acc, 0.0f);
    }
    __syncthreads();

    // fc1: this block's rows = rg*32 .. rg*32+31; wave-per-row, 8 rows/wave
    int wave = t >> 6, lane = t & 63;
    const float4* x4 = (const float4*)sX;
#pragma unroll
    for (int k = 0; k < 8; ++k) {
        int r = (rg << 5) + (wave << 3) + k;
        const float4* w4 = (const float4*)(fw1 + (size_t)r * 1024);
        float acc = 0.0f;
#pragma unroll
        for (int jj = 0; jj < 4; ++jj) {
            float4 wv = w4[lane + 64 * jj];
            float4 xv = x4[lane + 64 * jj];
            acc = fmaf(wv.x, xv.x, acc);
            acc = fmaf(wv.y, xv.y, acc);
            acc = fmaf(wv.z, xv.z, acc);
            acc = fmaf(wv.w, xv.w, acc);
        }
#pragma unroll
        for (int m = 32; m; m >>= 1) acc += __shfl_xor(acc, m, 64);
        if (lane == 0) h1[b * 256 + r] = fmaxf(acc + fb1[r], 0.0f);
    }
}

// ---------------------------------------------------------------------------
// bgfuse_k: 8 blocks (one per batch). fc2 -> fc3 -> fuse -> bg[8,8,16,16].
// Exactly the round-3-verified fc2/fc3/fuse arithmetic, done once per batch
// instead of redundantly in all 4096 guide blocks.
// ---------------------------------------------------------------------------
__global__ __launch_bounds__(256) void bgfuse_k(const float* __restrict__ h1g,
                                                const float* __restrict__ fw2,
                                                const float* __restrict__ fb2,
                                                const float* __restrict__ fw3,
                                                const float* __restrict__ fb3,
                                                const float* __restrict__ xl2,
                                                const float* __restrict__ fuw,
                                                const float* __restrict__ fub,
                                                float* __restrict__ bg) {
    __shared__ __align__(16) float sH1[256];
    __shared__ __align__(16) float sH2[128];
    __shared__ float sXG[64];
    int b = blockIdx.x, t = threadIdx.x;

    sH1[t] = h1g[b * 256 + t];
    __syncthreads();

    // fc2: h2[r] = relu(fw2[r,:].h1 + fb2[r])
    if (t < 128) {
        const float4* w4 = (const float4*)(fw2 + (size_t)t * 256);
        const float4* x4 = (const float4*)sH1;
        float a[4] = {0.f, 0.f, 0.f, 0.f};
#pragma unroll 4
        for (int j = 0; j < 64; ++j) {
            float4 wv = w4[j], xv = x4[j];
            a[j & 3] = fmaf(wv.x, xv.x, fmaf(wv.y, xv.y,
                       fmaf(wv.z, xv.z, fmaf(wv.w, xv.w, a[j & 3]))));
        }
        sH2[t] = fmaxf(a[0] + a[1] + a[2] + a[3] + fb2[t], 0.0f);
    }
    __syncthreads();
    // fc3: xg[r] = fw3[r,:].h2 + fb3[r]
    if (t < 64) {
        const float4* w4 = (const float4*)(fw3 + (size_t)t * 128);
        const float4* x4 = (const float4*)sH2;
        float a[4] = {0.f, 0.f, 0.f, 0.f};
#pragma unroll 4
        for (int j = 0; j < 32; ++j) {
            float4 wv = w4[j], xv = x4[j];
            a[j & 3] = fmaf(wv.x, xv.x, fmaf(wv.y, xv.y,
                       fmaf(wv.z, xv.z, fmaf(wv.w, xv.w, a[j & 3]))));
        }
        sXG[t] = a[0] + a[1] + a[2] + a[3] + fb3[t];
    }
    __syncthreads();

    // fuse: bg[b,d,px] = fub[d] + sum_c fuw[d,c]*relu(xg[c]+xl2[b,c,px])
    float accd[8];
#pragma unroll
    for (int d = 0; d < 8; ++d) accd[d] = fub[d];
    const float* xp = xl2 + ((size_t)b << 14) + t;
    for (int c = 0; c < 64; ++c) {
        float f = fmaxf(sXG[c] + xp[c << 8], 0.0f);
#pragma unroll
        for (int d = 0; d < 8; ++d) accd[d] = fmaf(fuw[(d << 6) + c], f, accd[d]);
    }
#pragma unroll
    for (int d = 0; d < 8; ++d) bg[((b << 3) + d) * 256 + t] = accd[d];
}

// ---------------------------------------------------------------------------
// guide+slice (exact round-0 verified version, 74 µs): vertical-first
// separable blur, sliding register windows, per-px guide MLP + trilinear
// grid slice.
// ---------------------------------------------------------------------------
__global__ __launch_bounds__(256) void guide_slice_k(const float* __restrict__ lqs,
                                                     const float* __restrict__ bgp,
                                                     const float* __restrict__ gw1,
                                                     const float* __restrict__ gb1,
                                                     const float* __restrict__ gw2,
                                                     const float* __restrict__ gb2,
                                                     float* __restrict__ out) {
    constexpr int TW = 64, TH = 32;
    __shared__ float sBH[3][TH][81];
    __shared__ float sBG[2048];
    __shared__ float sW1[48], sB1[16], sW2[16], sB2v[1];

    int t = threadIdx.x;
    int bx = blockIdx.x & 15;
    int by = (blockIdx.x >> 4) & 31;
    int b = blockIdx.x >> 9;
    int x0 = bx * TW, y0 = by * TH;

    float gv[17];
    {
        float gs = 0.0f;
#pragma unroll
        for (int i = 0; i < 17; ++i) {
            float d = (float)i - 8.0f;
            gv[i] = expf(-(d * d) * 0.125f);
            gs += gv[i];
        }
        float inv = 1.0f / gs;
#pragma unroll
        for (int i = 0; i < 17; ++i) gv[i] *= inv;
    }

    for (int i = t; i < 2048; i += 256) sBG[i] = bgp[b * 2048 + i];
    if (t < 48) sW1[t] = gw1[t];
    if (t < 16) { sB1[t] = gb1[t]; sW2[t] = gw2[t]; }
    if (t == 0) sB2v[0] = gb2[0];

    if (t < 240) {
        int c = t / 80, xo = t % 80;
        int gx = reflect1024(x0 + xo - 8);
        const float* colp = lqs + (size_t)(b * 3 + c) * HH * WW + gx;
        float win[17];
#pragma unroll
        for (int i = 0; i < 16; ++i)
            win[i] = colp[(size_t)reflect1024(y0 - 8 + i) * WW];
#pragma unroll
        for (int j = 0; j < TH; ++j) {
            win[(16 + j) % 17] = colp[(size_t)reflect1024(y0 + 8 + j) * WW];
            float acc = 0.0f;
#pragma unroll
            for (int i = 0; i < 17; ++i) acc = fmaf(gv[i], win[(j + i) % 17], acc);
            sBH[c][j][xo] = acc;
        }
    }
    __syncthreads();

    int yy = t >> 3, xs = (t & 7) * 8;
    int Y = y0 + yy;
    float fy = fminf(fmaxf((Y + 0.5f) * (1.0f / 64.0f) + 3.5f, 0.0f), 15.0f);
    float yf = floorf(fy);
    int yi = (int)yf;
    float ay = fy - yf;
    int yi1 = min(yi + 1, 15);

    float bcv[3][8];
#pragma unroll
    for (int c = 0; c < 3; ++c) {
        float win[17];
#pragma unroll
        for (int i = 0; i < 16; ++i) win[i] = sBH[c][yy][xs + i];
#pragma unroll
        for (int j = 0; j < 8; ++j) {
            win[(16 + j) % 17] = sBH[c][yy][xs + 16 + j];
            float acc = 0.0f;
#pragma unroll
            for (int i = 0; i < 17; ++i) acc = fmaf(gv[i], win[(j + i) % 17], acc);
            bcv[c][j] = acc;
        }
    }

    float val[8];
#pragma unroll
    for (int j = 0; j < 8; ++j) {
        float b0 = bcv[0][j], b1 = bcv[1][j], b2 = bcv[2][j];
        float s = sB2v[0];
#pragma unroll
        for (int c = 0; c < 16; ++c) {
            float g1 = fmaf(sW1[c * 3 + 0], b0,
                       fmaf(sW1[c * 3 + 1], b1,
                       fmaf(sW1[c * 3 + 2], b2, sB1[c])));
            s = fmaf(sW2[c], fmaxf(g1, 0.0f), s);
        }
        float sig = 1.0f / (1.0f + expf(-s));
        float guide = sig * 2.0f - 0.5f;

        int X = x0 + xs + j;
        float fx = fminf(fmaxf((X + 0.5f) * (1.0f / 64.0f) + 3.5f, 0.0f), 15.0f);
        float fz = fminf(fmaxf(fmaf(guide, 4.0f, 3.5f), 0.0f), 7.0f);
        float xf = floorf(fx), zf = floorf(fz);
        int xi = (int)xf, zi = (int)zf;
        float ax = fx - xf, az = fz - zf;
        int xi1 = min(xi + 1, 15), zi1 = min(zi + 1, 7);

        const float* g0 = sBG + zi * 256;
        const float* g1p = sBG + zi1 * 256;
        int i00 = yi * 16 + xi, i01 = yi * 16 + xi1;
        int i10 = yi1 * 16 + xi, i11 = yi1 * 16 + xi1;
        float c00 = g0[i00] + az * (g1p[i00] - g0[i00]);
        float c01 = g0[i01] + az * (g1p[i01] - g0[i01]);
        float c10 = g0[i10] + az * (g1p[i10] - g0[i10]);
        float c11 = g0[i11] + az * (g1p[i11] - g0[i11]);
        float c0 = c00 + ay * (c10 - c00);
        float c1 = c01 + ay * (c11 - c01);
        val[j] = c0 + ax * (c1 - c0);
    }
    float4* op = (float4*)(out + (size_t)b * HH * WW + (size_t)Y * WW + x0 + xs);
    op[0] = make_float4(val[0], val[1], val[2], val[3]);
    op[1] = make_float4(val[4], val[5], val[6], val[7]);
}

// ---------------------------------------------------------------------------
extern "C" void kernel_launch(void* const* d_in, const int* in_sizes, int n_in,
                              void* d_out, int out_size, void* d_ws, size_t ws_size,
                              hipStream_t stream) {
    const float* lqs = (const float*)d_in[0];
    const float* evs = (const float*)d_in[1];
    const float* gw1 = (const float*)d_in[2];
    const float* gb1 = (const float*)d_in[3];
    const float* gw2 = (const float*)d_in[4];
    const float* gb2 = (const float*)d_in[5];
    const float* sw0 = (const float*)d_in[6];
    const float* sb0 = (const float*)d_in[7];
    const float* sw1 = (const float*)d_in[8];
    const float* sb1 = (const float*)d_in[9];
    const float* sw2 = (const float*)d_in[10];
    const float* sb2 = (const float*)d_in[11];
    const float* sw3 = (const float*)d_in[12];
    const float* sb3 = (const float*)d_in[13];
    const float* cw0 = (const float*)d_in[14];
    const float* cb0 = (const float*)d_in[15];
    const float* cw1 = (const float*)d_in[16];
    const float* cb1 = (const float*)d_in[17];
    const float* fw1 = (const float*)d_in[18];
    const float* fb1 = (const float*)d_in[19];
    const float* fw2 = (const float*)d_in[20];
    const float* fb2 = (const float*)d_in[21];
    const float* fw3 = (const float*)d_in[22];
    const float* fb3 = (const float*)d_in[23];
    const float* lw1 = (const float*)d_in[24];
    const float* lb1 = (const float*)d_in[25];
    const float* lw2 = (const float*)d_in[26];
    const float* fuw = (const float*)d_in[27];
    const float* fub = (const float*)d_in[28];
    float* out = (float*)d_out;

    float* ws = (float*)d_ws;
    float* o1  = ws;               // [8,16,64,64]   524288
    float* o3  = o1 + 524288;      // [8,64,16,16]   131072
    float* xl1 = o3 + 131072;      // [8,64,16,16]   131072
    float* xl2 = xl1 + 131072;     // [8,64,16,16]   131072
    float* xg0 = xl2 + 131072;     // [8,64,8,8]      32768
    float* h1  = xg0 + 32768;      // [8,256]          2048
    float* bg  = h1 + 2048;        // [8,8,16,16]     16384
    // total ~1.0M floats = 4.0 MB

    conv01_k<<<512, 256, 0, stream>>>(lqs, evs, sw0, sb0, sw1, sb1, o1);
    conv23_k<<<512, 256, 0, stream>>>(o1, sw2, sb2, sw3, sb3, o3);
    lw1cw0_k<<<640, 256, 0, stream>>>(o3, lw1, lb1, cw0, cb0, xl1, xg0);
    lw2cw1fc1_k<<<576, 256, 0, stream>>>(xl1, lw2, xg0, cw1, cb1, fw1, fb1, xl2, h1);
    bgfuse_k<<<8, 256, 0, stream>>>(h1, fw2, fb2, fw3, fb3, xl2, fuw, fub, bg);
    guide_slice_k<<<BATCH * 32 * 16, 256, 0, stream>>>(lqs, bg, gw1, gb1, gw2, gb2, out);
}

// Round 8
// 473.526 us; speedup vs baseline: 1.8755x; 1.0497x over previous
//
#include <hip/hip_runtime.h>
#include <hip/hip_bf16.h>
#include <math.h>

#define BATCH 8
#define HH 1024
#define WW 1024

__device__ __forceinline__ int reflect1024(int i) {
    i = i < 0 ? -i : i;
    return i > 1023 ? 2046 - i : i;
}

// ---------------------------------------------------------------------------
// conv01_k: fused conv0 (18->8 @256 s2) + conv1 (8->16 @128 s2) -> o1
// [8,16,64,64].  2048 blocks = b(8) x ty(16) x tx(16); o1 tile 4x4 per block
// (8 blocks/CU for latency hiding — round-6 512-block version sat at 19%
// occupancy, 2 blocks/CU, latency-bound).  o0 region 9x9 x 8ch in LDS.
// ---------------------------------------------------------------------------
__global__ __launch_bounds__(256) void conv01_k(const float* __restrict__ lqs,
                                                const float* __restrict__ evs,
                                                const float* __restrict__ sw0,
                                                const float* __restrict__ sb0,
                                                const float* __restrict__ sw1,
                                                const float* __restrict__ sb1,
                                                float* __restrict__ o1) {
    __shared__ float s0[8 * 81];  // [ic][yy*9+xx]
    int t = threadIdx.x;
    int blk = blockIdx.x;
    int tx = blk & 15, ty = (blk >> 4) & 15, b = blk >> 8;
    int oy0 = ty << 2, ox0 = tx << 2;            // o1 tile origin (64x64 grid)
    int iy0s = 2 * oy0 - 1, ix0s = 2 * ox0 - 1;  // o0 region origin (9x9)

    if (t < 81) {
        int p = t;
        int yy = p / 9, xx = p - yy * 9;
        int iy = iy0s + yy, ix = ix0s + xx;      // o0 coords in [0,128)
        if ((unsigned)iy < 128u && (unsigned)ix < 128u) {
            float acc[8];
#pragma unroll
            for (int o = 0; o < 8; ++o) acc[o] = sb0[o];
#pragma unroll
            for (int ic = 0; ic < 3; ++ic) {
                const float* ipc = lqs + ((size_t)(b * 3 + ic) << 20);
#pragma unroll
                for (int ky = 0; ky < 3; ++ky) {
                    int r = 2 * iy - 1 + ky;
                    if ((unsigned)r >= 256u) continue;
                    const float* row = ipc + ((size_t)r << 12);  // nearest: row 4*r
#pragma unroll
                    for (int kx = 0; kx < 3; ++kx) {
                        int c = 2 * ix - 1 + kx;
                        if ((unsigned)c >= 256u) continue;
                        float v = row[c << 2];                    // nearest: col 4*c
                        const float* wp = sw0 + ic * 9 + ky * 3 + kx;
#pragma unroll
                        for (int o = 0; o < 8; ++o) acc[o] = fmaf(wp[o * 162], v, acc[o]);
                    }
                }
            }
            for (int ic = 0; ic < 15; ++ic) {
                const float* ipc = evs + ((size_t)(b * 15 + ic) << 16);
#pragma unroll
                for (int ky = 0; ky < 3; ++ky) {
                    int r = 2 * iy - 1 + ky;
                    if ((unsigned)r >= 256u) continue;
                    const float* row = ipc + (r << 8);
#pragma unroll
                    for (int kx = 0; kx < 3; ++kx) {
                        int c = 2 * ix - 1 + kx;
                        if ((unsigned)c >= 256u) continue;
                        float v = row[c];
                        const float* wp = sw0 + (ic + 3) * 9 + ky * 3 + kx;
#pragma unroll
                        for (int o = 0; o < 8; ++o) acc[o] = fmaf(wp[o * 162], v, acc[o]);
                    }
                }
            }
#pragma unroll
            for (int o = 0; o < 8; ++o) s0[o * 81 + p] = fmaxf(acc[o], 0.0f);
        } else {
#pragma unroll
            for (int o = 0; o < 8; ++o) s0[o * 81 + p] = 0.0f;
        }
    }
    __syncthreads();

    // conv1: thread t -> px = t&15 (4x4), oc = t>>4 (1 oc each)
    int px = t & 15, oc = t >> 4;
    int lpy = px >> 2, lpx = px & 3;
    float a1 = sb1[oc];
#pragma unroll
    for (int ic = 0; ic < 8; ++ic) {
        const float* sp = s0 + ic * 81 + (2 * lpy) * 9 + 2 * lpx;
        float x[9];
#pragma unroll
        for (int ky = 0; ky < 3; ++ky)
#pragma unroll
            for (int kx = 0; kx < 3; ++kx) x[ky * 3 + kx] = sp[ky * 9 + kx];
        const float* wp = sw1 + (oc * 8 + ic) * 9;
#pragma unroll
        for (int k = 0; k < 9; ++k) a1 = fmaf(wp[k], x[k], a1);
    }
    int oy = oy0 + lpy, ox = ox0 + lpx;
    o1[((size_t)(b * 16 + oc) << 12) + (oy << 6) + ox] = fmaxf(a1, 0.0f);
}

// ---------------------------------------------------------------------------
// conv23_k: fused conv2 (16->32 @64 s2) + conv3 (32->64 @32 s2) -> o3
// [8,64,16,16].  512 blocks = b(8) x ty(8) x tx(8); o3 tile 2x2 per block.
// o2 region (32ch x 5x5, incl. halo + zero-pad) in LDS.  (unchanged)
// ---------------------------------------------------------------------------
__global__ __launch_bounds__(256) void conv23_k(const float* __restrict__ o1,
                                                const float* __restrict__ sw2,
                                                const float* __restrict__ sb2,
                                                const float* __restrict__ sw3,
                                                const float* __restrict__ sb3,
                                                float* __restrict__ o3) {
    __shared__ float s2[32 * 25];  // [ic][yy*5+xx]
    int t = threadIdx.x;
    int blk = blockIdx.x;
    int tx = blk & 7, ty = (blk >> 3) & 7, b = blk >> 6;
    int oy0 = ty << 1, ox0 = tx << 1;            // o3 tile origin (16x16 grid)
    int iy0s = 2 * oy0 - 1, ix0s = 2 * ox0 - 1;  // o2 region origin (5x5)

    // o2 region: 25 px x 4 oc-groups (8 oc each) = 100 items
    if (t < 100) {
        int ocg = t / 25, p = t - ocg * 25;
        int yy = p / 5, xx = p - yy * 5;
        int iy = iy0s + yy, ix = ix0s + xx;      // o2 coords in [0,32)
        if ((unsigned)iy < 32u && (unsigned)ix < 32u) {
            float acc[8];
#pragma unroll
            for (int o = 0; o < 8; ++o) acc[o] = sb2[ocg * 8 + o];
            const float* ip = o1 + ((size_t)b << 16);
            int ry0 = 2 * iy - 1, rx0 = 2 * ix - 1;
            for (int ic = 0; ic < 16; ++ic) {
                const float* ipc = ip + (ic << 12);
                float x[9];
#pragma unroll
                for (int ky = 0; ky < 3; ++ky) {
                    int r = ry0 + ky;
#pragma unroll
                    for (int kx = 0; kx < 3; ++kx) {
                        int c = rx0 + kx;
                        bool ok = ((unsigned)r < 64u) && ((unsigned)c < 64u);
                        x[ky * 3 + kx] = ok ? ipc[(r << 6) + c] : 0.0f;
                    }
                }
#pragma unroll
                for (int o = 0; o < 8; ++o) {
                    const float* wp = sw2 + ((ocg * 8 + o) * 16 + ic) * 9;
#pragma unroll
                    for (int k = 0; k < 9; ++k) acc[o] = fmaf(wp[k], x[k], acc[o]);
                }
            }
#pragma unroll
            for (int o = 0; o < 8; ++o) s2[(ocg * 8 + o) * 25 + p] = fmaxf(acc[o], 0.0f);
        } else {
#pragma unroll
            for (int o = 0; o < 8; ++o) s2[(ocg * 8 + o) * 25 + p] = 0.0f;
        }
    }
    __syncthreads();

    // conv3: thread t -> oc = t>>2, p2 = t&3 (2x2), 1 output each
    int oc = t >> 2, p2 = t & 3;
    int py = p2 >> 1, pxx = p2 & 1;
    float a3 = sb3[oc];
    for (int ic = 0; ic < 32; ++ic) {
        const float* wp = sw3 + (oc * 32 + ic) * 9;
        const float* sp = s2 + ic * 25 + (2 * py) * 5 + 2 * pxx;
#pragma unroll
        for (int ky = 0; ky < 3; ++ky)
#pragma unroll
            for (int kx = 0; kx < 3; ++kx)
                a3 = fmaf(wp[ky * 3 + kx], sp[ky * 5 + kx], a3);
    }
    o3[((size_t)(b * 64 + oc) << 8) + ((oy0 + py) << 4) + (ox0 + pxx)] = fmaxf(a3, 0.0f);
}

// ---------------------------------------------------------------------------
// lw1cw0_k with LDS-staged weights.  Block=(b,oc) [lw1] shares one 576-float
// weight row; block covers 4 ocs [cw0] -> 2304 floats.  Stage coalesced once,
// read via LDS broadcast (uniform address = free) instead of 576+ scalar L2
// loads per thread.  FMA order identical to conv_item.
// ---------------------------------------------------------------------------
__global__ __launch_bounds__(256) void lw1cw0_k(const float* __restrict__ o3,
                                                const float* __restrict__ lw1,
                                                const float* __restrict__ lb1,
                                                const float* __restrict__ cw0,
                                                const float* __restrict__ cb0,
                                                float* __restrict__ xl1,
                                                float* __restrict__ xg0) {
    __shared__ float sW[2304];
    int blk = blockIdx.x, t = threadIdx.x;
    if (blk < 512) {
        // lw1: 64->64 @16 s1, relu.  b = blk>>6, oc = blk&63, px = t.
        int b = blk >> 6, oc = blk & 63;
        for (int i = t; i < 576; i += 256) sW[i] = lw1[oc * 576 + i];
        __syncthreads();
        int oy = t >> 4, ox = t & 15;
        int iy0 = oy - 1, ix0 = ox - 1;
        float acc = lb1[oc];
        const float* ip = o3 + ((size_t)b << 14);
        for (int ic = 0; ic < 64; ++ic) {
            const float* ipc = ip + (ic << 8);
            float x[9];
#pragma unroll
            for (int ky = 0; ky < 3; ++ky) {
                int iy = iy0 + ky;
#pragma unroll
                for (int kx = 0; kx < 3; ++kx) {
                    int ix = ix0 + kx;
                    bool ok = ((unsigned)iy < 16u) && ((unsigned)ix < 16u);
                    x[ky * 3 + kx] = ok ? ipc[(iy << 4) + ix] : 0.0f;
                }
            }
            const float* wp = sW + ic * 9;
#pragma unroll
            for (int k = 0; k < 9; ++k) acc = fmaf(wp[k], x[k], acc);
        }
        xl1[((size_t)(b * 64 + oc) << 8) + t] = fmaxf(acc, 0.0f);
    } else {
        // cw0: 64->64 @16 s2, relu.  q = blk-512: b = q>>4, oc_base = (q&15)*4,
        // oc = oc_base + t>>6, px = t&63.
        int q = blk - 512;
        int b = q >> 4, oc_base = (q & 15) << 2;
        for (int i = t; i < 2304; i += 256) sW[i] = cw0[oc_base * 576 + i];
        __syncthreads();
        int px = t & 63, ol = t >> 6;
        int oy = px >> 3, ox = px & 7;
        int iy0 = 2 * oy - 1, ix0 = 2 * ox - 1;
        float acc = cb0[oc_base + ol];
        const float* ip = o3 + ((size_t)b << 14);
        for (int ic = 0; ic < 64; ++ic) {
            const float* ipc = ip + (ic << 8);
            float x[9];
#pragma unroll
            for (int ky = 0; ky < 3; ++ky) {
                int iy = iy0 + ky;
#pragma unroll
                for (int kx = 0; kx < 3; ++kx) {
                    int ix = ix0 + kx;
                    bool ok = ((unsigned)iy < 16u) && ((unsigned)ix < 16u);
                    x[ky * 3 + kx] = ok ? ipc[(iy << 4) + ix] : 0.0f;
                }
            }
            const float* wp = sW + ol * 576 + ic * 9;
#pragma unroll
            for (int k = 0; k < 9; ++k) acc = fmaf(wp[k], x[k], acc);
        }
        xg0[((size_t)(b * 64 + oc_base + ol) << 6) + px] = fmaxf(acc, 0.0f);
    }
}

// ---------------------------------------------------------------------------
// lw2cw1fc1_k: lw2 (blocks 0..511, LDS weights) -> xl2; fc blocks 512..575
// (8 per batch): LDS-stage xg0[b]; cw1 computed with weights LDS-staged in
// 4 chunks of 16 oc (kills the round-6 2304-scalar-load-per-thread storm);
// then fc1 for this block's 32 rows -> h1[b,256].
// ---------------------------------------------------------------------------
__global__ __launch_bounds__(256) void lw2cw1fc1_k(const float* __restrict__ xl1,
                                                   const float* __restrict__ lw2,
                                                   const float* __restrict__ xg0,
                                                   const float* __restrict__ cw1,
                                                   const float* __restrict__ cb1,
                                                   const float* __restrict__ fw1,
                                                   const float* __restrict__ fb1,
                                                   float* __restrict__ xl2,
                                                   float* __restrict__ h1) {
    __shared__ __align__(16) float smem[14336];  // 57.3 KB, shared by branches
    int blk = blockIdx.x, t = threadIdx.x;
    if (blk < 512) {
        // lw2: 64->64 @16 s1, no bias/relu.  b = blk>>6, oc = blk&63, px = t.
        float* sW = smem;
        int b = blk >> 6, oc = blk & 63;
        for (int i = t; i < 576; i += 256) sW[i] = lw2[oc * 576 + i];
        __syncthreads();
        int oy = t >> 4, ox = t & 15;
        int iy0 = oy - 1, ix0 = ox - 1;
        float acc = 0.0f;
        const float* ip = xl1 + ((size_t)b << 14);
        for (int ic = 0; ic < 64; ++ic) {
            const float* ipc = ip + (ic << 8);
            float x[9];
#pragma unroll
            for (int ky = 0; ky < 3; ++ky) {
                int iy = iy0 + ky;
#pragma unroll
                for (int kx = 0; kx < 3; ++kx) {
                    int ix = ix0 + kx;
                    bool ok = ((unsigned)iy < 16u) && ((unsigned)ix < 16u);
                    x[ky * 3 + kx] = ok ? ipc[(iy << 4) + ix] : 0.0f;
                }
            }
            const float* wp = sW + ic * 9;
#pragma unroll
            for (int k = 0; k < 9; ++k) acc = fmaf(wp[k], x[k], acc);
        }
        xl2[((size_t)(b * 64 + oc) << 8) + t] = acc;
        return;
    }
    int q = blk - 512;             // 0..63
    int b = q >> 3, rg = q & 7;
    float* sG  = smem;             // xg0[b] : [64][8][8]   (4096)
    float* sX  = smem + 4096;      // cw1 out (oc*16+px)    (1024)
    float* sWc = smem + 5120;      // weight chunk 16x576   (9216)

#pragma unroll
    for (int j = 0; j < 16; ++j) sG[t + (j << 8)] = xg0[((size_t)b << 12) + t + (j << 8)];
    __syncthreads();

    // cw1 in 4 chunks of 16 oc; item = oc*16+px, thread -> (ol = t>>4, px = t&15)
    for (int c = 0; c < 4; ++c) {
        for (int i = t; i < 9216; i += 256) sWc[i] = cw1[c * 9216 + i];
        __syncthreads();
        int ol = t >> 4, px = t & 15;
        int oc = (c << 4) + ol;
        int oy = px >> 2, ox = px & 3;
        int iy0 = 2 * oy - 1, ix0 = 2 * ox - 1;
        float acc = cb1[oc];
        for (int ic = 0; ic < 64; ++ic) {
            const float* ipc = sG + (ic << 6);
            const float* wp = sWc + ol * 576 + ic * 9;
#pragma unroll
            for (int ky = 0; ky < 3; ++ky) {
                int r = iy0 + ky;
#pragma unroll
                for (int kx = 0; kx < 3; ++kx) {
                    int cc = ix0 + kx;
                    bool ok = ((unsigned)r < 8u) && ((unsigned)cc < 8u);
                    float x = ok ? ipc[(r << 3) + cc] : 0.0f;
                    acc = fmaf(wp[ky * 3 + kx], x, acc);
                }
            }
        }
        sX[(oc << 4) + px] = fmaxf(acc, 0.0f);
        __syncthreads();
    }

    // fc1: this block's rows = rg*32 .. rg*32+31; wave-per-row, 8 rows/wave
    int wave = t >> 6, lane = t & 63;
    const float4* x4 = (const float4*)sX;
#pragma unroll
    for (int k = 0; k < 8; ++k) {
        int r = (rg << 5) + (wave << 3) + k;
        const float4* w4 = (const float4*)(fw1 + (size_t)r * 1024);
        float acc = 0.0f;
#pragma unroll
        for (int jj = 0; jj < 4; ++jj) {
            float4 wv = w4[lane + 64 * jj];
            float4 xv = x4[lane + 64 * jj];
            acc = fmaf(wv.x, xv.x, acc);
            acc = fmaf(wv.y, xv.y, acc);
            acc = fmaf(wv.z, xv.z, acc);
            acc = fmaf(wv.w, xv.w, acc);
        }
#pragma unroll
        for (int m = 32; m; m >>= 1) acc += __shfl_xor(acc, m, 64);
        if (lane == 0) h1[b * 256 + r] = fmaxf(acc + fb1[r], 0.0f);
    }
}

// ---------------------------------------------------------------------------
// bgfuse_k: 8 blocks (one per batch). fc2 -> fc3 -> fuse -> bg[8,8,16,16].
// (unchanged)
// ---------------------------------------------------------------------------
__global__ __launch_bounds__(256) void bgfuse_k(const float* __restrict__ h1g,
                                                const float* __restrict__ fw2,
                                                const float* __restrict__ fb2,
                                                const float* __restrict__ fw3,
                                                const float* __restrict__ fb3,
                                                const float* __restrict__ xl2,
                                                const float* __restrict__ fuw,
                                                const float* __restrict__ fub,
                                                float* __restrict__ bg) {
    __shared__ __align__(16) float sH1[256];
    __shared__ __align__(16) float sH2[128];
    __shared__ float sXG[64];
    int b = blockIdx.x, t = threadIdx.x;

    sH1[t] = h1g[b * 256 + t];
    __syncthreads();

    if (t < 128) {
        const float4* w4 = (const float4*)(fw2 + (size_t)t * 256);
        const float4* x4 = (const float4*)sH1;
        float a[4] = {0.f, 0.f, 0.f, 0.f};
#pragma unroll 4
        for (int j = 0; j < 64; ++j) {
            float4 wv = w4[j], xv = x4[j];
            a[j & 3] = fmaf(wv.x, xv.x, fmaf(wv.y, xv.y,
                       fmaf(wv.z, xv.z, fmaf(wv.w, xv.w, a[j & 3]))));
        }
        sH2[t] = fmaxf(a[0] + a[1] + a[2] + a[3] + fb2[t], 0.0f);
    }
    __syncthreads();
    if (t < 64) {
        const float4* w4 = (const float4*)(fw3 + (size_t)t * 128);
        const float4* x4 = (const float4*)sH2;
        float a[4] = {0.f, 0.f, 0.f, 0.f};
#pragma unroll 4
        for (int j = 0; j < 32; ++j) {
            float4 wv = w4[j], xv = x4[j];
            a[j & 3] = fmaf(wv.x, xv.x, fmaf(wv.y, xv.y,
                       fmaf(wv.z, xv.z, fmaf(wv.w, xv.w, a[j & 3]))));
        }
        sXG[t] = a[0] + a[1] + a[2] + a[3] + fb3[t];
    }
    __syncthreads();

    float accd[8];
#pragma unroll
    for (int d = 0; d < 8; ++d) accd[d] = fub[d];
    const float* xp = xl2 + ((size_t)b << 14) + t;
    for (int c = 0; c < 64; ++c) {
        float f = fmaxf(sXG[c] + xp[c << 8], 0.0f);
#pragma unroll
        for (int d = 0; d < 8; ++d) accd[d] = fmaf(fuw[(d << 6) + c], f, accd[d]);
    }
#pragma unroll
    for (int d = 0; d < 8; ++d) bg[((b << 3) + d) * 256 + t] = accd[d];
}

// ---------------------------------------------------------------------------
// guide+slice (exact round-0 verified version): vertical-first separable
// blur, sliding register windows, per-px guide MLP + trilinear grid slice.
// (unchanged)
// ---------------------------------------------------------------------------
__global__ __launch_bounds__(256) void guide_slice_k(const float* __restrict__ lqs,
                                                     const float* __restrict__ bgp,
                                                     const float* __restrict__ gw1,
                                                     const float* __restrict__ gb1,
                                                     const float* __restrict__ gw2,
                                                     const float* __restrict__ gb2,
                                                     float* __restrict__ out) {
    constexpr int TW = 64, TH = 32;
    __shared__ float sBH[3][TH][81];
    __shared__ float sBG[2048];
    __shared__ float sW1[48], sB1[16], sW2[16], sB2v[1];

    int t = threadIdx.x;
    int bx = blockIdx.x & 15;
    int by = (blockIdx.x >> 4) & 31;
    int b = blockIdx.x >> 9;
    int x0 = bx * TW, y0 = by * TH;

    float gv[17];
    {
        float gs = 0.0f;
#pragma unroll
        for (int i = 0; i < 17; ++i) {
            float d = (float)i - 8.0f;
            gv[i] = expf(-(d * d) * 0.125f);
            gs += gv[i];
        }
        float inv = 1.0f / gs;
#pragma unroll
        for (int i = 0; i < 17; ++i) gv[i] *= inv;
    }

    for (int i = t; i < 2048; i += 256) sBG[i] = bgp[b * 2048 + i];
    if (t < 48) sW1[t] = gw1[t];
    if (t < 16) { sB1[t] = gb1[t]; sW2[t] = gw2[t]; }
    if (t == 0) sB2v[0] = gb2[0];

    if (t < 240) {
        int c = t / 80, xo = t % 80;
        int gx = reflect1024(x0 + xo - 8);
        const float* colp = lqs + (size_t)(b * 3 + c) * HH * WW + gx;
        float win[17];
#pragma unroll
        for (int i = 0; i < 16; ++i)
            win[i] = colp[(size_t)reflect1024(y0 - 8 + i) * WW];
#pragma unroll
        for (int j = 0; j < TH; ++j) {
            win[(16 + j) % 17] = colp[(size_t)reflect1024(y0 + 8 + j) * WW];
            float acc = 0.0f;
#pragma unroll
            for (int i = 0; i < 17; ++i) acc = fmaf(gv[i], win[(j + i) % 17], acc);
            sBH[c][j][xo] = acc;
        }
    }
    __syncthreads();

    int yy = t >> 3, xs = (t & 7) * 8;
    int Y = y0 + yy;
    float fy = fminf(fmaxf((Y + 0.5f) * (1.0f / 64.0f) + 3.5f, 0.0f), 15.0f);
    float yf = floorf(fy);
    int yi = (int)yf;
    float ay = fy - yf;
    int yi1 = min(yi + 1, 15);

    float bcv[3][8];
#pragma unroll
    for (int c = 0; c < 3; ++c) {
        float win[17];
#pragma unroll
        for (int i = 0; i < 16; ++i) win[i] = sBH[c][yy][xs + i];
#pragma unroll
        for (int j = 0; j < 8; ++j) {
            win[(16 + j) % 17] = sBH[c][yy][xs + 16 + j];
            float acc = 0.0f;
#pragma unroll
            for (int i = 0; i < 17; ++i) acc = fmaf(gv[i], win[(j + i) % 17], acc);
            bcv[c][j] = acc;
        }
    }

    float val[8];
#pragma unroll
    for (int j = 0; j < 8; ++j) {
        float b0 = bcv[0][j], b1 = bcv[1][j], b2 = bcv[2][j];
        float s = sB2v[0];
#pragma unroll
        for (int c = 0; c < 16; ++c) {
            float g1 = fmaf(sW1[c * 3 + 0], b0,
                       fmaf(sW1[c * 3 + 1], b1,
                       fmaf(sW1[c * 3 + 2], b2, sB1[c])));
            s = fmaf(sW2[c], fmaxf(g1, 0.0f), s);
        }
        float sig = 1.0f / (1.0f + expf(-s));
        float guide = sig * 2.0f - 0.5f;

        int X = x0 + xs + j;
        float fx = fminf(fmaxf((X + 0.5f) * (1.0f / 64.0f) + 3.5f, 0.0f), 15.0f);
        float fz = fminf(fmaxf(fmaf(guide, 4.0f, 3.5f), 0.0f), 7.0f);
        float xf = floorf(fx), zf = floorf(fz);
        int xi = (int)xf, zi = (int)zf;
        float ax = fx - xf, az = fz - zf;
        int xi1 = min(xi + 1, 15), zi1 = min(zi + 1, 7);

        const float* g0 = sBG + zi * 256;
        const float* g1p = sBG + zi1 * 256;
        int i00 = yi * 16 + xi, i01 = yi * 16 + xi1;
        int i10 = yi1 * 16 + xi, i11 = yi1 * 16 + xi1;
        float c00 = g0[i00] + az * (g1p[i00] - g0[i00]);
        float c01 = g0[i01] + az * (g1p[i01] - g0[i01]);
        float c10 = g0[i10] + az * (g1p[i10] - g0[i10]);
        float c11 = g0[i11] + az * (g1p[i11] - g0[i11]);
        float c0 = c00 + ay * (c10 - c00);
        float c1 = c01 + ay * (c11 - c01);
        val[j] = c0 + ax * (c1 - c0);
    }
    float4* op = (float4*)(out + (size_t)b * HH * WW + (size_t)Y * WW + x0 + xs);
    op[0] = make_float4(val[0], val[1], val[2], val[3]);
    op[1] = make_float4(val[4], val[5], val[6], val[7]);
}

// ---------------------------------------------------------------------------
extern "C" void kernel_launch(void* const* d_in, const int* in_sizes, int n_in,
                              void* d_out, int out_size, void* d_ws, size_t ws_size,
                              hipStream_t stream) {
    const float* lqs = (const float*)d_in[0];
    const float* evs = (const float*)d_in[1];
    const float* gw1 = (const float*)d_in[2];
    const float* gb1 = (const float*)d_in[3];
    const float* gw2 = (const float*)d_in[4];
    const float* gb2 = (const float*)d_in[5];
    const float* sw0 = (const float*)d_in[6];
    const float* sb0 = (const float*)d_in[7];
    const float* sw1 = (const float*)d_in[8];
    const float* sb1 = (const float*)d_in[9];
    const float* sw2 = (const float*)d_in[10];
    const float* sb2 = (const float*)d_in[11];
    const float* sw3 = (const float*)d_in[12];
    const float* sb3 = (const float*)d_in[13];
    const float* cw0 = (const float*)d_in[14];
    const float* cb0 = (const float*)d_in[15];
    const float* cw1 = (const float*)d_in[16];
    const float* cb1 = (const float*)d_in[17];
    const float* fw1 = (const float*)d_in[18];
    const float* fb1 = (const float*)d_in[19];
    const float* fw2 = (const float*)d_in[20];
    const float* fb2 = (const float*)d_in[21];
    const float* fw3 = (const float*)d_in[22];
    const float* fb3 = (const float*)d_in[23];
    const float* lw1 = (const float*)d_in[24];
    const float* lb1 = (const float*)d_in[25];
    const float* lw2 = (const float*)d_in[26];
    const float* fuw = (const float*)d_in[27];
    const float* fub = (const float*)d_in[28];
    float* out = (float*)d_out;

    float* ws = (float*)d_ws;
    float* o1  = ws;               // [8,16,64,64]   524288
    float* o3  = o1 + 524288;      // [8,64,16,16]   131072
    float* xl1 = o3 + 131072;      // [8,64,16,16]   131072
    float* xl2 = xl1 + 131072;     // [8,64,16,16]   131072
    float* xg0 = xl2 + 131072;     // [8,64,8,8]      32768
    float* h1  = xg0 + 32768;      // [8,256]          2048
    float* bg  = h1 + 2048;        // [8,8,16,16]     16384
    // total ~1.0M floats = 4.0 MB

    conv01_k<<<2048, 256, 0, stream>>>(lqs, evs, sw0, sb0, sw1, sb1, o1);
    conv23_k<<<512, 256, 0, stream>>>(o1, sw2, sb2, sw3, sb3, o3);
    lw1cw0_k<<<640, 256, 0, stream>>>(o3, lw1, lb1, cw0, cb0, xl1, xg0);
    lw2cw1fc1_k<<<576, 256, 0, stream>>>(xl1, lw2, xg0, cw1, cb1, fw1, fb1, xl2, h1);
    bgfuse_k<<<8, 256, 0, stream>>>(h1, fw2, fb2, fw3, fb3, xl2, fuw, fub, bg);
    guide_slice_k<<<BATCH * 32 * 16, 256, 0, stream>>>(lqs, bg, gw1, gb1, gw2, gb2, out);
}

// Round 10
// 468.148 us; speedup vs baseline: 1.8970x; 1.0115x over previous
//
#include <hip/hip_runtime.h>
#include <hip/hip_bf16.h>
#include <math.h>

#define BATCH 8
#define HH 1024
#define WW 1024

__device__ __forceinline__ int reflect1024(int i) {
    i = i < 0 ? -i : i;
    return i > 1023 ? 2046 - i : i;
}

// ---------------------------------------------------------------------------
// conv01_k: fused conv0 (18->8 @256 s2) + conv1 (8->16 @128 s2) -> o1
// [8,16,64,64].  2048 blocks = b(8) x ty(16) x tx(16); o1 tile 4x4 per block.
// (unchanged from round 8)
// ---------------------------------------------------------------------------
__global__ __launch_bounds__(256) void conv01_k(const float* __restrict__ lqs,
                                                const float* __restrict__ evs,
                                                const float* __restrict__ sw0,
                                                const float* __restrict__ sb0,
                                                const float* __restrict__ sw1,
                                                const float* __restrict__ sb1,
                                                float* __restrict__ o1) {
    __shared__ float s0[8 * 81];  // [ic][yy*9+xx]
    int t = threadIdx.x;
    int blk = blockIdx.x;
    int tx = blk & 15, ty = (blk >> 4) & 15, b = blk >> 8;
    int oy0 = ty << 2, ox0 = tx << 2;            // o1 tile origin (64x64 grid)
    int iy0s = 2 * oy0 - 1, ix0s = 2 * ox0 - 1;  // o0 region origin (9x9)

    if (t < 81) {
        int p = t;
        int yy = p / 9, xx = p - yy * 9;
        int iy = iy0s + yy, ix = ix0s + xx;      // o0 coords in [0,128)
        if ((unsigned)iy < 128u && (unsigned)ix < 128u) {
            float acc[8];
#pragma unroll
            for (int o = 0; o < 8; ++o) acc[o] = sb0[o];
#pragma unroll
            for (int ic = 0; ic < 3; ++ic) {
                const float* ipc = lqs + ((size_t)(b * 3 + ic) << 20);
#pragma unroll
                for (int ky = 0; ky < 3; ++ky) {
                    int r = 2 * iy - 1 + ky;
                    if ((unsigned)r >= 256u) continue;
                    const float* row = ipc + ((size_t)r << 12);  // nearest: row 4*r
#pragma unroll
                    for (int kx = 0; kx < 3; ++kx) {
                        int c = 2 * ix - 1 + kx;
                        if ((unsigned)c >= 256u) continue;
                        float v = row[c << 2];                    // nearest: col 4*c
                        const float* wp = sw0 + ic * 9 + ky * 3 + kx;
#pragma unroll
                        for (int o = 0; o < 8; ++o) acc[o] = fmaf(wp[o * 162], v, acc[o]);
                    }
                }
            }
            for (int ic = 0; ic < 15; ++ic) {
                const float* ipc = evs + ((size_t)(b * 15 + ic) << 16);
#pragma unroll
                for (int ky = 0; ky < 3; ++ky) {
                    int r = 2 * iy - 1 + ky;
                    if ((unsigned)r >= 256u) continue;
                    const float* row = ipc + (r << 8);
#pragma unroll
                    for (int kx = 0; kx < 3; ++kx) {
                        int c = 2 * ix - 1 + kx;
                        if ((unsigned)c >= 256u) continue;
                        float v = row[c];
                        const float* wp = sw0 + (ic + 3) * 9 + ky * 3 + kx;
#pragma unroll
                        for (int o = 0; o < 8; ++o) acc[o] = fmaf(wp[o * 162], v, acc[o]);
                    }
                }
            }
#pragma unroll
            for (int o = 0; o < 8; ++o) s0[o * 81 + p] = fmaxf(acc[o], 0.0f);
        } else {
#pragma unroll
            for (int o = 0; o < 8; ++o) s0[o * 81 + p] = 0.0f;
        }
    }
    __syncthreads();

    // conv1: thread t -> px = t&15 (4x4), oc = t>>4 (1 oc each)
    int px = t & 15, oc = t >> 4;
    int lpy = px >> 2, lpx = px & 3;
    float a1 = sb1[oc];
#pragma unroll
    for (int ic = 0; ic < 8; ++ic) {
        const float* sp = s0 + ic * 81 + (2 * lpy) * 9 + 2 * lpx;
        float x[9];
#pragma unroll
        for (int ky = 0; ky < 3; ++ky)
#pragma unroll
            for (int kx = 0; kx < 3; ++kx) x[ky * 3 + kx] = sp[ky * 9 + kx];
        const float* wp = sw1 + (oc * 8 + ic) * 9;
#pragma unroll
        for (int k = 0; k < 9; ++k) a1 = fmaf(wp[k], x[k], a1);
    }
    int oy = oy0 + lpy, ox = ox0 + lpx;
    o1[((size_t)(b * 16 + oc) << 12) + (oy << 6) + ox] = fmaxf(a1, 0.0f);
}

// ---------------------------------------------------------------------------
// conv23_k: fused conv2 (16->32 @64 s2) + conv3 (32->64 @32 s2) -> o3
// [8,64,16,16].  512 blocks; o3 tile 2x2; o2 region 32ch x 5x5 in LDS.
// (unchanged)
// ---------------------------------------------------------------------------
__global__ __launch_bounds__(256) void conv23_k(const float* __restrict__ o1,
                                                const float* __restrict__ sw2,
                                                const float* __restrict__ sb2,
                                                const float* __restrict__ sw3,
                                                const float* __restrict__ sb3,
                                                float* __restrict__ o3) {
    __shared__ float s2[32 * 25];  // [ic][yy*5+xx]
    int t = threadIdx.x;
    int blk = blockIdx.x;
    int tx = blk & 7, ty = (blk >> 3) & 7, b = blk >> 6;
    int oy0 = ty << 1, ox0 = tx << 1;            // o3 tile origin (16x16 grid)
    int iy0s = 2 * oy0 - 1, ix0s = 2 * ox0 - 1;  // o2 region origin (5x5)

    // o2 region: 25 px x 4 oc-groups (8 oc each) = 100 items
    if (t < 100) {
        int ocg = t / 25, p = t - ocg * 25;
        int yy = p / 5, xx = p - yy * 5;
        int iy = iy0s + yy, ix = ix0s + xx;      // o2 coords in [0,32)
        if ((unsigned)iy < 32u && (unsigned)ix < 32u) {
            float acc[8];
#pragma unroll
            for (int o = 0; o < 8; ++o) acc[o] = sb2[ocg * 8 + o];
            const float* ip = o1 + ((size_t)b << 16);
            int ry0 = 2 * iy - 1, rx0 = 2 * ix - 1;
            for (int ic = 0; ic < 16; ++ic) {
                const float* ipc = ip + (ic << 12);
                float x[9];
#pragma unroll
                for (int ky = 0; ky < 3; ++ky) {
                    int r = ry0 + ky;
#pragma unroll
                    for (int kx = 0; kx < 3; ++kx) {
                        int c = rx0 + kx;
                        bool ok = ((unsigned)r < 64u) && ((unsigned)c < 64u);
                        x[ky * 3 + kx] = ok ? ipc[(r << 6) + c] : 0.0f;
                    }
                }
#pragma unroll
                for (int o = 0; o < 8; ++o) {
                    const float* wp = sw2 + ((ocg * 8 + o) * 16 + ic) * 9;
#pragma unroll
                    for (int k = 0; k < 9; ++k) acc[o] = fmaf(wp[k], x[k], acc[o]);
                }
            }
#pragma unroll
            for (int o = 0; o < 8; ++o) s2[(ocg * 8 + o) * 25 + p] = fmaxf(acc[o], 0.0f);
        } else {
#pragma unroll
            for (int o = 0; o < 8; ++o) s2[(ocg * 8 + o) * 25 + p] = 0.0f;
        }
    }
    __syncthreads();

    // conv3: thread t -> oc = t>>2, p2 = t&3 (2x2), 1 output each
    int oc = t >> 2, p2 = t & 3;
    int py = p2 >> 1, pxx = p2 & 1;
    float a3 = sb3[oc];
    for (int ic = 0; ic < 32; ++ic) {
        const float* wp = sw3 + (oc * 32 + ic) * 9;
        const float* sp = s2 + ic * 25 + (2 * py) * 5 + 2 * pxx;
#pragma unroll
        for (int ky = 0; ky < 3; ++ky)
#pragma unroll
            for (int kx = 0; kx < 3; ++kx)
                a3 = fmaf(wp[ky * 3 + kx], sp[ky * 5 + kx], a3);
    }
    o3[((size_t)(b * 64 + oc) << 8) + ((oy0 + py) << 4) + (ox0 + pxx)] = fmaxf(a3, 0.0f);
}

// ---------------------------------------------------------------------------
// lw1cw0_k with LDS-staged weights.  (unchanged from round 8)
// ---------------------------------------------------------------------------
__global__ __launch_bounds__(256) void lw1cw0_k(const float* __restrict__ o3,
                                                const float* __restrict__ lw1,
                                                const float* __restrict__ lb1,
                                                const float* __restrict__ cw0,
                                                const float* __restrict__ cb0,
                                                float* __restrict__ xl1,
                                                float* __restrict__ xg0) {
    __shared__ float sW[2304];
    int blk = blockIdx.x, t = threadIdx.x;
    if (blk < 512) {
        // lw1: 64->64 @16 s1, relu.  b = blk>>6, oc = blk&63, px = t.
        int b = blk >> 6, oc = blk & 63;
        for (int i = t; i < 576; i += 256) sW[i] = lw1[oc * 576 + i];
        __syncthreads();
        int oy = t >> 4, ox = t & 15;
        int iy0 = oy - 1, ix0 = ox - 1;
        float acc = lb1[oc];
        const float* ip = o3 + ((size_t)b << 14);
        for (int ic = 0; ic < 64; ++ic) {
            const float* ipc = ip + (ic << 8);
            float x[9];
#pragma unroll
            for (int ky = 0; ky < 3; ++ky) {
                int iy = iy0 + ky;
#pragma unroll
                for (int kx = 0; kx < 3; ++kx) {
                    int ix = ix0 + kx;
                    bool ok = ((unsigned)iy < 16u) && ((unsigned)ix < 16u);
                    x[ky * 3 + kx] = ok ? ipc[(iy << 4) + ix] : 0.0f;
                }
            }
            const float* wp = sW + ic * 9;
#pragma unroll
            for (int k = 0; k < 9; ++k) acc = fmaf(wp[k], x[k], acc);
        }
        xl1[((size_t)(b * 64 + oc) << 8) + t] = fmaxf(acc, 0.0f);
    } else {
        // cw0: 64->64 @16 s2, relu.
        int q = blk - 512;
        int b = q >> 4, oc_base = (q & 15) << 2;
        for (int i = t; i < 2304; i += 256) sW[i] = cw0[oc_base * 576 + i];
        __syncthreads();
        int px = t & 63, ol = t >> 6;
        int oy = px >> 3, ox = px & 7;
        int iy0 = 2 * oy - 1, ix0 = 2 * ox - 1;
        float acc = cb0[oc_base + ol];
        const float* ip = o3 + ((size_t)b << 14);
        for (int ic = 0; ic < 64; ++ic) {
            const float* ipc = ip + (ic << 8);
            float x[9];
#pragma unroll
            for (int ky = 0; ky < 3; ++ky) {
                int iy = iy0 + ky;
#pragma unroll
                for (int kx = 0; kx < 3; ++kx) {
                    int ix = ix0 + kx;
                    bool ok = ((unsigned)iy < 16u) && ((unsigned)ix < 16u);
                    x[ky * 3 + kx] = ok ? ipc[(iy << 4) + ix] : 0.0f;
                }
            }
            const float* wp = sW + ol * 576 + ic * 9;
#pragma unroll
            for (int k = 0; k < 9; ++k) acc = fmaf(wp[k], x[k], acc);
        }
        xg0[((size_t)(b * 64 + oc_base + ol) << 6) + px] = fmaxf(acc, 0.0f);
    }
}

// ---------------------------------------------------------------------------
// lw2cw1fc1_k: lw2 (blocks 0..511, LDS weights) -> xl2; fc blocks 512..575:
// LDS-stage xg0[b]; cw1 with chunked LDS weights; fc1 32 rows -> h1.
// (unchanged from round 8)
// ---------------------------------------------------------------------------
__global__ __launch_bounds__(256) void lw2cw1fc1_k(const float* __restrict__ xl1,
                                                   const float* __restrict__ lw2,
                                                   const float* __restrict__ xg0,
                                                   const float* __restrict__ cw1,
                                                   const float* __restrict__ cb1,
                                                   const float* __restrict__ fw1,
                                                   const float* __restrict__ fb1,
                                                   float* __restrict__ xl2,
                                                   float* __restrict__ h1) {
    __shared__ __align__(16) float smem[14336];  // 57.3 KB, shared by branches
    int blk = blockIdx.x, t = threadIdx.x;
    if (blk < 512) {
        // lw2: 64->64 @16 s1, no bias/relu.
        float* sW = smem;
        int b = blk >> 6, oc = blk & 63;
        for (int i = t; i < 576; i += 256) sW[i] = lw2[oc * 576 + i];
        __syncthreads();
        int oy = t >> 4, ox = t & 15;
        int iy0 = oy - 1, ix0 = ox - 1;
        float acc = 0.0f;
        const float* ip = xl1 + ((size_t)b << 14);
        for (int ic = 0; ic < 64; ++ic) {
            const float* ipc = ip + (ic << 8);
            float x[9];
#pragma unroll
            for (int ky = 0; ky < 3; ++ky) {
                int iy = iy0 + ky;
#pragma unroll
                for (int kx = 0; kx < 3; ++kx) {
                    int ix = ix0 + kx;
                    bool ok = ((unsigned)iy < 16u) && ((unsigned)ix < 16u);
                    x[ky * 3 + kx] = ok ? ipc[(iy << 4) + ix] : 0.0f;
                }
            }
            const float* wp = sW + ic * 9;
#pragma unroll
            for (int k = 0; k < 9; ++k) acc = fmaf(wp[k], x[k], acc);
        }
        xl2[((size_t)(b * 64 + oc) << 8) + t] = acc;
        return;
    }
    int q = blk - 512;             // 0..63
    int b = q >> 3, rg = q & 7;
    float* sG  = smem;             // xg0[b] : [64][8][8]   (4096)
    float* sX  = smem + 4096;      // cw1 out (oc*16+px)    (1024)
    float* sWc = smem + 5120;      // weight chunk 16x576   (9216)

#pragma unroll
    for (int j = 0; j < 16; ++j) sG[t + (j << 8)] = xg0[((size_t)b << 12) + t + (j << 8)];
    __syncthreads();

    // cw1 in 4 chunks of 16 oc
    for (int c = 0; c < 4; ++c) {
        for (int i = t; i < 9216; i += 256) sWc[i] = cw1[c * 9216 + i];
        __syncthreads();
        int ol = t >> 4, px = t & 15;
        int oc = (c << 4) + ol;
        int oy = px >> 2, ox = px & 3;
        int iy0 = 2 * oy - 1, ix0 = 2 * ox - 1;
        float acc = cb1[oc];
        for (int ic = 0; ic < 64; ++ic) {
            const float* ipc = sG + (ic << 6);
            const float* wp = sWc + ol * 576 + ic * 9;
#pragma unroll
            for (int ky = 0; ky < 3; ++ky) {
                int r = iy0 + ky;
#pragma unroll
                for (int kx = 0; kx < 3; ++kx) {
                    int cc = ix0 + kx;
                    bool ok = ((unsigned)r < 8u) && ((unsigned)cc < 8u);
                    float x = ok ? ipc[(r << 3) + cc] : 0.0f;
                    acc = fmaf(wp[ky * 3 + kx], x, acc);
                }
            }
        }
        sX[(oc << 4) + px] = fmaxf(acc, 0.0f);
        __syncthreads();
    }

    // fc1: rows rg*32 .. rg*32+31; wave-per-row, 8 rows/wave
    int wave = t >> 6, lane = t & 63;
    const float4* x4 = (const float4*)sX;
#pragma unroll
    for (int k = 0; k < 8; ++k) {
        int r = (rg << 5) + (wave << 3) + k;
        const float4* w4 = (const float4*)(fw1 + (size_t)r * 1024);
        float acc = 0.0f;
#pragma unroll
        for (int jj = 0; jj < 4; ++jj) {
            float4 wv = w4[lane + 64 * jj];
            float4 xv = x4[lane + 64 * jj];
            acc = fmaf(wv.x, xv.x, acc);
            acc = fmaf(wv.y, xv.y, acc);
            acc = fmaf(wv.z, xv.z, acc);
            acc = fmaf(wv.w, xv.w, acc);
        }
#pragma unroll
        for (int m = 32; m; m >>= 1) acc += __shfl_xor(acc, m, 64);
        if (lane == 0) h1[b * 256 + r] = fmaxf(acc + fb1[r], 0.0f);
    }
}

// ---------------------------------------------------------------------------
// bgfuse_k: 8 blocks (one per batch). fc2 -> fc3 -> fuse -> bg[8,8,16,16].
// (unchanged)
// ---------------------------------------------------------------------------
__global__ __launch_bounds__(256) void bgfuse_k(const float* __restrict__ h1g,
                                                const float* __restrict__ fw2,
                                                const float* __restrict__ fb2,
                                                const float* __restrict__ fw3,
                                                const float* __restrict__ fb3,
                                                const float* __restrict__ xl2,
                                                const float* __restrict__ fuw,
                                                const float* __restrict__ fub,
                                                float* __restrict__ bg) {
    __shared__ __align__(16) float sH1[256];
    __shared__ __align__(16) float sH2[128];
    __shared__ float sXG[64];
    int b = blockIdx.x, t = threadIdx.x;

    sH1[t] = h1g[b * 256 + t];
    __syncthreads();

    if (t < 128) {
        const float4* w4 = (const float4*)(fw2 + (size_t)t * 256);
        const float4* x4 = (const float4*)sH1;
        float a[4] = {0.f, 0.f, 0.f, 0.f};
#pragma unroll 4
        for (int j = 0; j < 64; ++j) {
            float4 wv = w4[j], xv = x4[j];
            a[j & 3] = fmaf(wv.x, xv.x, fmaf(wv.y, xv.y,
                       fmaf(wv.z, xv.z, fmaf(wv.w, xv.w, a[j & 3]))));
        }
        sH2[t] = fmaxf(a[0] + a[1] + a[2] + a[3] + fb2[t], 0.0f);
    }
    __syncthreads();
    if (t < 64) {
        const float4* w4 = (const float4*)(fw3 + (size_t)t * 128);
        const float4* x4 = (const float4*)sH2;
        float a[4] = {0.f, 0.f, 0.f, 0.f};
#pragma unroll 4
        for (int j = 0; j < 32; ++j) {
            float4 wv = w4[j], xv = x4[j];
            a[j & 3] = fmaf(wv.x, xv.x, fmaf(wv.y, xv.y,
                       fmaf(wv.z, xv.z, fmaf(wv.w, xv.w, a[j & 3]))));
        }
        sXG[t] = a[0] + a[1] + a[2] + a[3] + fb3[t];
    }
    __syncthreads();

    float accd[8];
#pragma unroll
    for (int d = 0; d < 8; ++d) accd[d] = fub[d];
    const float* xp = xl2 + ((size_t)b << 14) + t;
    for (int c = 0; c < 64; ++c) {
        float f = fmaxf(sXG[c] + xp[c << 8], 0.0f);
#pragma unroll
        for (int d = 0; d < 8; ++d) accd[d] = fmaf(fuw[(d << 6) + c], f, accd[d]);
    }
#pragma unroll
    for (int d = 0; d < 8; ++d) bg[((b << 3) + d) * 256 + t] = accd[d];
}

// ---------------------------------------------------------------------------
// guide+slice, TH=16 occupancy rework: LDS 39.9 KB -> ~24.2 KB => 6 blocks/CU
// (was 3-4; Occupancy 32%, latency-bound at 55% VALUBusy in round 8).
// 8192 blocks = b(8) x by(64) x bx(16); 4 px per thread (one float4 store).
// Per-output arithmetic identical to the verified TH=32 version: same 17-tap
// windows in the same i order, same MLP/slice FMA chains.
// ---------------------------------------------------------------------------
__global__ __launch_bounds__(256) void guide_slice_k(const float* __restrict__ lqs,
                                                     const float* __restrict__ bgp,
                                                     const float* __restrict__ gw1,
                                                     const float* __restrict__ gb1,
                                                     const float* __restrict__ gw2,
                                                     const float* __restrict__ gb2,
                                                     float* __restrict__ out) {
    constexpr int TW = 64, TH = 16;
    __shared__ float sBH[3][TH][81];
    __shared__ float sBG[2048];
    __shared__ float sW1[48], sB1[16], sW2[16], sB2v[1];

    int t = threadIdx.x;
    int bx = blockIdx.x & 15;
    int by = (blockIdx.x >> 4) & 63;
    int b = blockIdx.x >> 10;
    int x0 = bx * TW, y0 = by * TH;

    float gv[17];
    {
        float gs = 0.0f;
#pragma unroll
        for (int i = 0; i < 17; ++i) {
            float d = (float)i - 8.0f;
            gv[i] = expf(-(d * d) * 0.125f);
            gs += gv[i];
        }
        float inv = 1.0f / gs;
#pragma unroll
        for (int i = 0; i < 17; ++i) gv[i] *= inv;
    }

    for (int i = t; i < 2048; i += 256) sBG[i] = bgp[b * 2048 + i];
    if (t < 48) sW1[t] = gw1[t];
    if (t < 16) { sB1[t] = gb1[t]; sW2[t] = gw2[t]; }
    if (t == 0) sB2v[0] = gb2[0];

    if (t < 240) {
        int c = t / 80, xo = t % 80;
        int gx = reflect1024(x0 + xo - 8);
        const float* colp = lqs + (size_t)(b * 3 + c) * HH * WW + gx;
        float win[17];
#pragma unroll
        for (int i = 0; i < 16; ++i)
            win[i] = colp[(size_t)reflect1024(y0 - 8 + i) * WW];
#pragma unroll
        for (int j = 0; j < TH; ++j) {
            win[(16 + j) % 17] = colp[(size_t)reflect1024(y0 + 8 + j) * WW];
            float acc = 0.0f;
#pragma unroll
            for (int i = 0; i < 17; ++i) acc = fmaf(gv[i], win[(j + i) % 17], acc);
            sBH[c][j][xo] = acc;
        }
    }
    __syncthreads();

    // 4 px per thread: yy = t>>4 (0..15), xs = (t&15)*4 (0..60)
    int yy = t >> 4, xs = (t & 15) * 4;
    int Y = y0 + yy;
    float fy = fminf(fmaxf((Y + 0.5f) * (1.0f / 64.0f) + 3.5f, 0.0f), 15.0f);
    float yf = floorf(fy);
    int yi = (int)yf;
    float ay = fy - yf;
    int yi1 = min(yi + 1, 15);

    float bcv[3][4];
#pragma unroll
    for (int c = 0; c < 3; ++c) {
        float win[17];
#pragma unroll
        for (int i = 0; i < 16; ++i) win[i] = sBH[c][yy][xs + i];
#pragma unroll
        for (int j = 0; j < 4; ++j) {
            win[(16 + j) % 17] = sBH[c][yy][xs + 16 + j];
            float acc = 0.0f;
#pragma unroll
            for (int i = 0; i < 17; ++i) acc = fmaf(gv[i], win[(j + i) % 17], acc);
            bcv[c][j] = acc;
        }
    }

    float val[4];
#pragma unroll
    for (int j = 0; j < 4; ++j) {
        float b0 = bcv[0][j], b1 = bcv[1][j], b2 = bcv[2][j];
        float s = sB2v[0];
#pragma unroll
        for (int c = 0; c < 16; ++c) {
            float g1 = fmaf(sW1[c * 3 + 0], b0,
                       fmaf(sW1[c * 3 + 1], b1,
                       fmaf(sW1[c * 3 + 2], b2, sB1[c])));
            s = fmaf(sW2[c], fmaxf(g1, 0.0f), s);
        }
        float sig = 1.0f / (1.0f + expf(-s));
        float guide = sig * 2.0f - 0.5f;

        int X = x0 + xs + j;
        float fx = fminf(fmaxf((X + 0.5f) * (1.0f / 64.0f) + 3.5f, 0.0f), 15.0f);
        float fz = fminf(fmaxf(fmaf(guide, 4.0f, 3.5f), 0.0f), 7.0f);
        float xf = floorf(fx), zf = floorf(fz);
        int xi = (int)xf, zi = (int)zf;
        float ax = fx - xf, az = fz - zf;
        int xi1 = min(xi + 1, 15), zi1 = min(zi + 1, 7);

        const float* g0 = sBG + zi * 256;
        const float* g1p = sBG + zi1 * 256;
        int i00 = yi * 16 + xi, i01 = yi * 16 + xi1;
        int i10 = yi1 * 16 + xi, i11 = yi1 * 16 + xi1;
        float c00 = g0[i00] + az * (g1p[i00] - g0[i00]);
        float c01 = g0[i01] + az * (g1p[i01] - g0[i01]);
        float c10 = g0[i10] + az * (g1p[i10] - g0[i10]);
        float c11 = g0[i11] + az * (g1p[i11] - g0[i11]);
        float c0 = c00 + ay * (c10 - c00);
        float c1 = c01 + ay * (c11 - c01);
        val[j] = c0 + ax * (c1 - c0);
    }
    float4* op = (float4*)(out + (size_t)b * HH * WW + (size_t)Y * WW + x0 + xs);
    op[0] = make_float4(val[0], val[1], val[2], val[3]);
}

// ---------------------------------------------------------------------------
extern "C" void kernel_launch(void* const* d_in, const int* in_sizes, int n_in,
                              void* d_out, int out_size, void* d_ws, size_t ws_size,
                              hipStream_t stream) {
    const float* lqs = (const float*)d_in[0];
    const float* evs = (const float*)d_in[1];
    const float* gw1 = (const float*)d_in[2];
    const float* gb1 = (const float*)d_in[3];
    const float* gw2 = (const float*)d_in[4];
    const float* gb2 = (const float*)d_in[5];
    const float* sw0 = (const float*)d_in[6];
    const float* sb0 = (const float*)d_in[7];
    const float* sw1 = (const float*)d_in[8];
    const float* sb1 = (const float*)d_in[9];
    const float* sw2 = (const float*)d_in[10];
    const float* sb2 = (const float*)d_in[11];
    const float* sw3 = (const float*)d_in[12];
    const float* sb3 = (const float*)d_in[13];
    const float* cw0 = (const float*)d_in[14];
    const float* cb0 = (const float*)d_in[15];
    const float* cw1 = (const float*)d_in[16];
    const float* cb1 = (const float*)d_in[17];
    const float* fw1 = (const float*)d_in[18];
    const float* fb1 = (const float*)d_in[19];
    const float* fw2 = (const float*)d_in[20];
    const float* fb2 = (const float*)d_in[21];
    const float* fw3 = (const float*)d_in[22];
    const float* fb3 = (const float*)d_in[23];
    const float* lw1 = (const float*)d_in[24];
    const float* lb1 = (const float*)d_in[25];
    const float* lw2 = (const float*)d_in[26];
    const float* fuw = (const float*)d_in[27];
    const float* fub = (const float*)d_in[28];
    float* out = (float*)d_out;

    float* ws = (float*)d_ws;
    float* o1  = ws;               // [8,16,64,64]   524288
    float* o3  = o1 + 524288;      // [8,64,16,16]   131072
    float* xl1 = o3 + 131072;      // [8,64,16,16]   131072
    float* xl2 = xl1 + 131072;     // [8,64,16,16]   131072
    float* xg0 = xl2 + 131072;     // [8,64,8,8]      32768
    float* h1  = xg0 + 32768;      // [8,256]          2048
    float* bg  = h1 + 2048;        // [8,8,16,16]     16384
    // total ~1.0M floats = 4.0 MB

    conv01_k<<<2048, 256, 0, stream>>>(lqs, evs, sw0, sb0, sw1, sb1, o1);
    conv23_k<<<512, 256, 0, stream>>>(o1, sw2, sb2, sw3, sb3, o3);
    lw1cw0_k<<<640, 256, 0, stream>>>(o3, lw1, lb1, cw0, cb0, xl1, xg0);
    lw2cw1fc1_k<<<576, 256, 0, stream>>>(xl1, lw2, xg0, cw1, cb1, fw1, fb1, xl2, h1);
    bgfuse_k<<<8, 256, 0, stream>>>(h1, fw2, fb2, fw3, fb3, xl2, fuw, fub, bg);
    guide_slice_k<<<BATCH * 64 * 16, 256, 0, stream>>>(lqs, bg, gw1, gb1, gw2, gb2, out);
}

// Round 11
// 467.176 us; speedup vs baseline: 1.9010x; 1.0021x over previous
//
#include <hip/hip_runtime.h>
#include <hip/hip_bf16.h>
#include <math.h>

#define BATCH 8
#define HH 1024
#define WW 1024

__device__ __forceinline__ int reflect1024(int i) {
    i = i < 0 ? -i : i;
    return i > 1023 ? 2046 - i : i;
}

// ---------------------------------------------------------------------------
// conv01_k: fused conv0 (18->8 @256 s2) + conv1 (8->16 @128 s2) -> o1
// [8,16,64,64].  2048 blocks; o1 tile 4x4 per block.  (unchanged, verified)
// ---------------------------------------------------------------------------
__global__ __launch_bounds__(256) void conv01_k(const float* __restrict__ lqs,
                                                const float* __restrict__ evs,
                                                const float* __restrict__ sw0,
                                                const float* __restrict__ sb0,
                                                const float* __restrict__ sw1,
                                                const float* __restrict__ sb1,
                                                float* __restrict__ o1) {
    __shared__ float s0[8 * 81];  // [ic][yy*9+xx]
    int t = threadIdx.x;
    int blk = blockIdx.x;
    int tx = blk & 15, ty = (blk >> 4) & 15, b = blk >> 8;
    int oy0 = ty << 2, ox0 = tx << 2;            // o1 tile origin (64x64 grid)
    int iy0s = 2 * oy0 - 1, ix0s = 2 * ox0 - 1;  // o0 region origin (9x9)

    if (t < 81) {
        int p = t;
        int yy = p / 9, xx = p - yy * 9;
        int iy = iy0s + yy, ix = ix0s + xx;      // o0 coords in [0,128)
        if ((unsigned)iy < 128u && (unsigned)ix < 128u) {
            float acc[8];
#pragma unroll
            for (int o = 0; o < 8; ++o) acc[o] = sb0[o];
#pragma unroll
            for (int ic = 0; ic < 3; ++ic) {
                const float* ipc = lqs + ((size_t)(b * 3 + ic) << 20);
#pragma unroll
                for (int ky = 0; ky < 3; ++ky) {
                    int r = 2 * iy - 1 + ky;
                    if ((unsigned)r >= 256u) continue;
                    const float* row = ipc + ((size_t)r << 12);  // nearest: row 4*r
#pragma unroll
                    for (int kx = 0; kx < 3; ++kx) {
                        int c = 2 * ix - 1 + kx;
                        if ((unsigned)c >= 256u) continue;
                        float v = row[c << 2];                    // nearest: col 4*c
                        const float* wp = sw0 + ic * 9 + ky * 3 + kx;
#pragma unroll
                        for (int o = 0; o < 8; ++o) acc[o] = fmaf(wp[o * 162], v, acc[o]);
                    }
                }
            }
            for (int ic = 0; ic < 15; ++ic) {
                const float* ipc = evs + ((size_t)(b * 15 + ic) << 16);
#pragma unroll
                for (int ky = 0; ky < 3; ++ky) {
                    int r = 2 * iy - 1 + ky;
                    if ((unsigned)r >= 256u) continue;
                    const float* row = ipc + (r << 8);
#pragma unroll
                    for (int kx = 0; kx < 3; ++kx) {
                        int c = 2 * ix - 1 + kx;
                        if ((unsigned)c >= 256u) continue;
                        float v = row[c];
                        const float* wp = sw0 + (ic + 3) * 9 + ky * 3 + kx;
#pragma unroll
                        for (int o = 0; o < 8; ++o) acc[o] = fmaf(wp[o * 162], v, acc[o]);
                    }
                }
            }
#pragma unroll
            for (int o = 0; o < 8; ++o) s0[o * 81 + p] = fmaxf(acc[o], 0.0f);
        } else {
#pragma unroll
            for (int o = 0; o < 8; ++o) s0[o * 81 + p] = 0.0f;
        }
    }
    __syncthreads();

    // conv1: thread t -> px = t&15 (4x4), oc = t>>4 (1 oc each)
    int px = t & 15, oc = t >> 4;
    int lpy = px >> 2, lpx = px & 3;
    float a1 = sb1[oc];
#pragma unroll
    for (int ic = 0; ic < 8; ++ic) {
        const float* sp = s0 + ic * 81 + (2 * lpy) * 9 + 2 * lpx;
        float x[9];
#pragma unroll
        for (int ky = 0; ky < 3; ++ky)
#pragma unroll
            for (int kx = 0; kx < 3; ++kx) x[ky * 3 + kx] = sp[ky * 9 + kx];
        const float* wp = sw1 + (oc * 8 + ic) * 9;
#pragma unroll
        for (int k = 0; k < 9; ++k) a1 = fmaf(wp[k], x[k], a1);
    }
    int oy = oy0 + lpy, ox = ox0 + lpx;
    o1[((size_t)(b * 16 + oc) << 12) + (oy << 6) + ox] = fmaxf(a1, 0.0f);
}

// ---------------------------------------------------------------------------
// conv23_k: fused conv2 + conv3 -> o3 [8,64,16,16].  (unchanged, verified)
// ---------------------------------------------------------------------------
__global__ __launch_bounds__(256) void conv23_k(const float* __restrict__ o1,
                                                const float* __restrict__ sw2,
                                                const float* __restrict__ sb2,
                                                const float* __restrict__ sw3,
                                                const float* __restrict__ sb3,
                                                float* __restrict__ o3) {
    __shared__ float s2[32 * 25];  // [ic][yy*5+xx]
    int t = threadIdx.x;
    int blk = blockIdx.x;
    int tx = blk & 7, ty = (blk >> 3) & 7, b = blk >> 6;
    int oy0 = ty << 1, ox0 = tx << 1;
    int iy0s = 2 * oy0 - 1, ix0s = 2 * ox0 - 1;

    if (t < 100) {
        int ocg = t / 25, p = t - ocg * 25;
        int yy = p / 5, xx = p - yy * 5;
        int iy = iy0s + yy, ix = ix0s + xx;
        if ((unsigned)iy < 32u && (unsigned)ix < 32u) {
            float acc[8];
#pragma unroll
            for (int o = 0; o < 8; ++o) acc[o] = sb2[ocg * 8 + o];
            const float* ip = o1 + ((size_t)b << 16);
            int ry0 = 2 * iy - 1, rx0 = 2 * ix - 1;
            for (int ic = 0; ic < 16; ++ic) {
                const float* ipc = ip + (ic << 12);
                float x[9];
#pragma unroll
                for (int ky = 0; ky < 3; ++ky) {
                    int r = ry0 + ky;
#pragma unroll
                    for (int kx = 0; kx < 3; ++kx) {
                        int c = rx0 + kx;
                        bool ok = ((unsigned)r < 64u) && ((unsigned)c < 64u);
                        x[ky * 3 + kx] = ok ? ipc[(r << 6) + c] : 0.0f;
                    }
                }
#pragma unroll
                for (int o = 0; o < 8; ++o) {
                    const float* wp = sw2 + ((ocg * 8 + o) * 16 + ic) * 9;
#pragma unroll
                    for (int k = 0; k < 9; ++k) acc[o] = fmaf(wp[k], x[k], acc[o]);
                }
            }
#pragma unroll
            for (int o = 0; o < 8; ++o) s2[(ocg * 8 + o) * 25 + p] = fmaxf(acc[o], 0.0f);
        } else {
#pragma unroll
            for (int o = 0; o < 8; ++o) s2[(ocg * 8 + o) * 25 + p] = 0.0f;
        }
    }
    __syncthreads();

    int oc = t >> 2, p2 = t & 3;
    int py = p2 >> 1, pxx = p2 & 1;
    float a3 = sb3[oc];
    for (int ic = 0; ic < 32; ++ic) {
        const float* wp = sw3 + (oc * 32 + ic) * 9;
        const float* sp = s2 + ic * 25 + (2 * py) * 5 + 2 * pxx;
#pragma unroll
        for (int ky = 0; ky < 3; ++ky)
#pragma unroll
            for (int kx = 0; kx < 3; ++kx)
                a3 = fmaf(wp[ky * 3 + kx], sp[ky * 5 + kx], a3);
    }
    o3[((size_t)(b * 64 + oc) << 8) + ((oy0 + py) << 4) + (ox0 + pxx)] = fmaxf(a3, 0.0f);
}

// ---------------------------------------------------------------------------
// lw1cw0_k with LDS-staged weights.  (unchanged, verified)
// ---------------------------------------------------------------------------
__global__ __launch_bounds__(256) void lw1cw0_k(const float* __restrict__ o3,
                                                const float* __restrict__ lw1,
                                                const float* __restrict__ lb1,
                                                const float* __restrict__ cw0,
                                                const float* __restrict__ cb0,
                                                float* __restrict__ xl1,
                                                float* __restrict__ xg0) {
    __shared__ float sW[2304];
    int blk = blockIdx.x, t = threadIdx.x;
    if (blk < 512) {
        int b = blk >> 6, oc = blk & 63;
        for (int i = t; i < 576; i += 256) sW[i] = lw1[oc * 576 + i];
        __syncthreads();
        int oy = t >> 4, ox = t & 15;
        int iy0 = oy - 1, ix0 = ox - 1;
        float acc = lb1[oc];
        const float* ip = o3 + ((size_t)b << 14);
        for (int ic = 0; ic < 64; ++ic) {
            const float* ipc = ip + (ic << 8);
            float x[9];
#pragma unroll
            for (int ky = 0; ky < 3; ++ky) {
                int iy = iy0 + ky;
#pragma unroll
                for (int kx = 0; kx < 3; ++kx) {
                    int ix = ix0 + kx;
                    bool ok = ((unsigned)iy < 16u) && ((unsigned)ix < 16u);
                    x[ky * 3 + kx] = ok ? ipc[(iy << 4) + ix] : 0.0f;
                }
            }
            const float* wp = sW + ic * 9;
#pragma unroll
            for (int k = 0; k < 9; ++k) acc = fmaf(wp[k], x[k], acc);
        }
        xl1[((size_t)(b * 64 + oc) << 8) + t] = fmaxf(acc, 0.0f);
    } else {
        int q = blk - 512;
        int b = q >> 4, oc_base = (q & 15) << 2;
        for (int i = t; i < 2304; i += 256) sW[i] = cw0[oc_base * 576 + i];
        __syncthreads();
        int px = t & 63, ol = t >> 6;
        int oy = px >> 3, ox = px & 7;
        int iy0 = 2 * oy - 1, ix0 = 2 * ox - 1;
        float acc = cb0[oc_base + ol];
        const float* ip = o3 + ((size_t)b << 14);
        for (int ic = 0; ic < 64; ++ic) {
            const float* ipc = ip + (ic << 8);
            float x[9];
#pragma unroll
            for (int ky = 0; ky < 3; ++ky) {
                int iy = iy0 + ky;
#pragma unroll
                for (int kx = 0; kx < 3; ++kx) {
                    int ix = ix0 + kx;
                    bool ok = ((unsigned)iy < 16u) && ((unsigned)ix < 16u);
                    x[ky * 3 + kx] = ok ? ipc[(iy << 4) + ix] : 0.0f;
                }
            }
            const float* wp = sW + ol * 576 + ic * 9;
#pragma unroll
            for (int k = 0; k < 9; ++k) acc = fmaf(wp[k], x[k], acc);
        }
        xg0[((size_t)(b * 64 + oc_base + ol) << 6) + px] = fmaxf(acc, 0.0f);
    }
}

// ---------------------------------------------------------------------------
// lw2cw1_k: cw1 on blocks 0..63 (FIRST, so they overlap lw2), lw2 on blocks
// 64..575.  cw1 block = (b, 8 ocs): xg0[b] + its 8 weight rows in LDS
// (row stride 584 — 584%32=8 kills the round-10 4-way bank conflict on the
// 576-stride layout), 128 items, no chunk loop.  Static LDS 35.1 KB (was
// 57.3) -> 4 blocks/CU for the 512 lw2 blocks (was 2, Occupancy 8.4%).
// FMA order per output identical to the verified round-8 bodies.
// ---------------------------------------------------------------------------
__global__ __launch_bounds__(256) void lw2cw1_k(const float* __restrict__ xl1,
                                                const float* __restrict__ lw2,
                                                const float* __restrict__ xg0,
                                                const float* __restrict__ cw1,
                                                const float* __restrict__ cb1,
                                                float* __restrict__ xl2,
                                                float* __restrict__ xg1) {
    __shared__ __align__(16) float smem[8768];  // 35072 B
    int blk = blockIdx.x, t = threadIdx.x;
    if (blk < 64) {
        // cw1: b = blk>>3, ocs og*8 .. og*8+7
        int b = blk >> 3, og = blk & 7;
        float* sG = smem;            // xg0[b] : [64][8][8]  (4096)
        float* sW = smem + 4096;     // 8 x 584 padded rows  (4672)
#pragma unroll
        for (int j = 0; j < 16; ++j) sG[t + (j << 8)] = xg0[((size_t)b << 12) + t + (j << 8)];
        for (int i = t; i < 4608; i += 256) {
            int ol = i / 576, r = i - ol * 576;
            sW[ol * 584 + r] = cw1[(og * 8 + ol) * 576 + r];
        }
        __syncthreads();
        if (t < 128) {
            int ol = t >> 4, px = t & 15;
            int oc = og * 8 + ol;
            int oy = px >> 2, ox = px & 3;
            int iy0 = 2 * oy - 1, ix0 = 2 * ox - 1;
            float acc = cb1[oc];
            for (int ic = 0; ic < 64; ++ic) {
                const float* ipc = sG + (ic << 6);
                const float* wp = sW + ol * 584 + ic * 9;
#pragma unroll
                for (int ky = 0; ky < 3; ++ky) {
                    int r = iy0 + ky;
#pragma unroll
                    for (int kx = 0; kx < 3; ++kx) {
                        int cc = ix0 + kx;
                        bool ok = ((unsigned)r < 8u) && ((unsigned)cc < 8u);
                        float x = ok ? ipc[(r << 3) + cc] : 0.0f;
                        acc = fmaf(wp[ky * 3 + kx], x, acc);
                    }
                }
            }
            xg1[b * 1024 + (oc << 4) + px] = fmaxf(acc, 0.0f);
        }
    } else {
        // lw2: 64->64 @16 s1, no bias/relu.  (verified body)
        int q = blk - 64;
        float* sW = smem;
        int b = q >> 6, oc = q & 63;
        for (int i = t; i < 576; i += 256) sW[i] = lw2[oc * 576 + i];
        __syncthreads();
        int oy = t >> 4, ox = t & 15;
        int iy0 = oy - 1, ix0 = ox - 1;
        float acc = 0.0f;
        const float* ip = xl1 + ((size_t)b << 14);
        for (int ic = 0; ic < 64; ++ic) {
            const float* ipc = ip + (ic << 8);
            float x[9];
#pragma unroll
            for (int ky = 0; ky < 3; ++ky) {
                int iy = iy0 + ky;
#pragma unroll
                for (int kx = 0; kx < 3; ++kx) {
                    int ix = ix0 + kx;
                    bool ok = ((unsigned)iy < 16u) && ((unsigned)ix < 16u);
                    x[ky * 3 + kx] = ok ? ipc[(iy << 4) + ix] : 0.0f;
                }
            }
            const float* wp = sW + ic * 9;
#pragma unroll
            for (int k = 0; k < 9; ++k) acc = fmaf(wp[k], x[k], acc);
        }
        xl2[((size_t)(b * 64 + oc) << 8) + t] = acc;
    }
}

// ---------------------------------------------------------------------------
// fc1bgfuse_k: 8 blocks (one per batch).  fc1 (wave-per-row, the verified
// round-8 inner body: lane-strided float4 dot + butterfly; 4 waves x 64 rows)
// -> sH1, then the verified fc2/fc3/fuse -> bg.
// ---------------------------------------------------------------------------
__global__ __launch_bounds__(256) void fc1bgfuse_k(const float* __restrict__ xg1,
                                                   const float* __restrict__ fw1,
                                                   const float* __restrict__ fb1,
                                                   const float* __restrict__ fw2,
                                                   const float* __restrict__ fb2,
                                                   const float* __restrict__ fw3,
                                                   const float* __restrict__ fb3,
                                                   const float* __restrict__ xl2,
                                                   const float* __restrict__ fuw,
                                                   const float* __restrict__ fub,
                                                   float* __restrict__ bg) {
    __shared__ __align__(16) float sX[1024];
    __shared__ __align__(16) float sH1[256];
    __shared__ __align__(16) float sH2[128];
    __shared__ float sXG[64];
    int b = blockIdx.x, t = threadIdx.x;

#pragma unroll
    for (int j = 0; j < 4; ++j) sX[t + (j << 8)] = xg1[b * 1024 + t + (j << 8)];
    __syncthreads();

    // fc1: wave-per-row, 64 rows per wave (verified per-row FMA order)
    {
        int wave = t >> 6, lane = t & 63;
        const float4* x4 = (const float4*)sX;
        for (int k = 0; k < 64; ++k) {
            int r = (wave << 6) + k;
            const float4* w4 = (const float4*)(fw1 + (size_t)r * 1024);
            float acc = 0.0f;
#pragma unroll
            for (int jj = 0; jj < 4; ++jj) {
                float4 wv = w4[lane + 64 * jj];
                float4 xv = x4[lane + 64 * jj];
                acc = fmaf(wv.x, xv.x, acc);
                acc = fmaf(wv.y, xv.y, acc);
                acc = fmaf(wv.z, xv.z, acc);
                acc = fmaf(wv.w, xv.w, acc);
            }
#pragma unroll
            for (int m = 32; m; m >>= 1) acc += __shfl_xor(acc, m, 64);
            if (lane == 0) sH1[r] = fmaxf(acc + fb1[r], 0.0f);
        }
    }
    __syncthreads();

    // fc2 (verified)
    if (t < 128) {
        const float4* w4 = (const float4*)(fw2 + (size_t)t * 256);
        const float4* x4 = (const float4*)sH1;
        float a[4] = {0.f, 0.f, 0.f, 0.f};
#pragma unroll 4
        for (int j = 0; j < 64; ++j) {
            float4 wv = w4[j], xv = x4[j];
            a[j & 3] = fmaf(wv.x, xv.x, fmaf(wv.y, xv.y,
                       fmaf(wv.z, xv.z, fmaf(wv.w, xv.w, a[j & 3]))));
        }
        sH2[t] = fmaxf(a[0] + a[1] + a[2] + a[3] + fb2[t], 0.0f);
    }
    __syncthreads();
    // fc3 (verified)
    if (t < 64) {
        const float4* w4 = (const float4*)(fw3 + (size_t)t * 128);
        const float4* x4 = (const float4*)sH2;
        float a[4] = {0.f, 0.f, 0.f, 0.f};
#pragma unroll 4
        for (int j = 0; j < 32; ++j) {
            float4 wv = w4[j], xv = x4[j];
            a[j & 3] = fmaf(wv.x, xv.x, fmaf(wv.y, xv.y,
                       fmaf(wv.z, xv.z, fmaf(wv.w, xv.w, a[j & 3]))));
        }
        sXG[t] = a[0] + a[1] + a[2] + a[3] + fb3[t];
    }
    __syncthreads();

    // fuse (verified)
    float accd[8];
#pragma unroll
    for (int d = 0; d < 8; ++d) accd[d] = fub[d];
    const float* xp = xl2 + ((size_t)b << 14) + t;
    for (int c = 0; c < 64; ++c) {
        float f = fmaxf(sXG[c] + xp[c << 8], 0.0f);
#pragma unroll
        for (int d = 0; d < 8; ++d) accd[d] = fmaf(fuw[(d << 6) + c], f, accd[d]);
    }
#pragma unroll
    for (int d = 0; d < 8; ++d) bg[((b << 3) + d) * 256 + t] = accd[d];
}

// ---------------------------------------------------------------------------
// guide+slice, TH=16.  (unchanged from round 10, verified)
// ---------------------------------------------------------------------------
__global__ __launch_bounds__(256) void guide_slice_k(const float* __restrict__ lqs,
                                                     const float* __restrict__ bgp,
                                                     const float* __restrict__ gw1,
                                                     const float* __restrict__ gb1,
                                                     const float* __restrict__ gw2,
                                                     const float* __restrict__ gb2,
                                                     float* __restrict__ out) {
    constexpr int TW = 64, TH = 16;
    __shared__ float sBH[3][TH][81];
    __shared__ float sBG[2048];
    __shared__ float sW1[48], sB1[16], sW2[16], sB2v[1];

    int t = threadIdx.x;
    int bx = blockIdx.x & 15;
    int by = (blockIdx.x >> 4) & 63;
    int b = blockIdx.x >> 10;
    int x0 = bx * TW, y0 = by * TH;

    float gv[17];
    {
        float gs = 0.0f;
#pragma unroll
        for (int i = 0; i < 17; ++i) {
            float d = (float)i - 8.0f;
            gv[i] = expf(-(d * d) * 0.125f);
            gs += gv[i];
        }
        float inv = 1.0f / gs;
#pragma unroll
        for (int i = 0; i < 17; ++i) gv[i] *= inv;
    }

    for (int i = t; i < 2048; i += 256) sBG[i] = bgp[b * 2048 + i];
    if (t < 48) sW1[t] = gw1[t];
    if (t < 16) { sB1[t] = gb1[t]; sW2[t] = gw2[t]; }
    if (t == 0) sB2v[0] = gb2[0];

    if (t < 240) {
        int c = t / 80, xo = t % 80;
        int gx = reflect1024(x0 + xo - 8);
        const float* colp = lqs + (size_t)(b * 3 + c) * HH * WW + gx;
        float win[17];
#pragma unroll
        for (int i = 0; i < 16; ++i)
            win[i] = colp[(size_t)reflect1024(y0 - 8 + i) * WW];
#pragma unroll
        for (int j = 0; j < TH; ++j) {
            win[(16 + j) % 17] = colp[(size_t)reflect1024(y0 + 8 + j) * WW];
            float acc = 0.0f;
#pragma unroll
            for (int i = 0; i < 17; ++i) acc = fmaf(gv[i], win[(j + i) % 17], acc);
            sBH[c][j][xo] = acc;
        }
    }
    __syncthreads();

    int yy = t >> 4, xs = (t & 15) * 4;
    int Y = y0 + yy;
    float fy = fminf(fmaxf((Y + 0.5f) * (1.0f / 64.0f) + 3.5f, 0.0f), 15.0f);
    float yf = floorf(fy);
    int yi = (int)yf;
    float ay = fy - yf;
    int yi1 = min(yi + 1, 15);

    float bcv[3][4];
#pragma unroll
    for (int c = 0; c < 3; ++c) {
        float win[17];
#pragma unroll
        for (int i = 0; i < 16; ++i) win[i] = sBH[c][yy][xs + i];
#pragma unroll
        for (int j = 0; j < 4; ++j) {
            win[(16 + j) % 17] = sBH[c][yy][xs + 16 + j];
            float acc = 0.0f;
#pragma unroll
            for (int i = 0; i < 17; ++i) acc = fmaf(gv[i], win[(j + i) % 17], acc);
            bcv[c][j] = acc;
        }
    }

    float val[4];
#pragma unroll
    for (int j = 0; j < 4; ++j) {
        float b0 = bcv[0][j], b1 = bcv[1][j], b2 = bcv[2][j];
        float s = sB2v[0];
#pragma unroll
        for (int c = 0; c < 16; ++c) {
            float g1 = fmaf(sW1[c * 3 + 0], b0,
                       fmaf(sW1[c * 3 + 1], b1,
                       fmaf(sW1[c * 3 + 2], b2, sB1[c])));
            s = fmaf(sW2[c], fmaxf(g1, 0.0f), s);
        }
        float sig = 1.0f / (1.0f + expf(-s));
        float guide = sig * 2.0f - 0.5f;

        int X = x0 + xs + j;
        float fx = fminf(fmaxf((X + 0.5f) * (1.0f / 64.0f) + 3.5f, 0.0f), 15.0f);
        float fz = fminf(fmaxf(fmaf(guide, 4.0f, 3.5f), 0.0f), 7.0f);
        float xf = floorf(fx), zf = floorf(fz);
        int xi = (int)xf, zi = (int)zf;
        float ax = fx - xf, az = fz - zf;
        int xi1 = min(xi + 1, 15), zi1 = min(zi + 1, 7);

        const float* g0 = sBG + zi * 256;
        const float* g1p = sBG + zi1 * 256;
        int i00 = yi * 16 + xi, i01 = yi * 16 + xi1;
        int i10 = yi1 * 16 + xi, i11 = yi1 * 16 + xi1;
        float c00 = g0[i00] + az * (g1p[i00] - g0[i00]);
        float c01 = g0[i01] + az * (g1p[i01] - g0[i01]);
        float c10 = g0[i10] + az * (g1p[i10] - g0[i10]);
        float c11 = g0[i11] + az * (g1p[i11] - g0[i11]);
        float c0 = c00 + ay * (c10 - c00);
        float c1 = c01 + ay * (c11 - c01);
        val[j] = c0 + ax * (c1 - c0);
    }
    float4* op = (float4*)(out + (size_t)b * HH * WW + (size_t)Y * WW + x0 + xs);
    op[0] = make_float4(val[0], val[1], val[2], val[3]);
}

// ---------------------------------------------------------------------------
extern "C" void kernel_launch(void* const* d_in, const int* in_sizes, int n_in,
                              void* d_out, int out_size, void* d_ws, size_t ws_size,
                              hipStream_t stream) {
    const float* lqs = (const float*)d_in[0];
    const float* evs = (const float*)d_in[1];
    const float* gw1 = (const float*)d_in[2];
    const float* gb1 = (const float*)d_in[3];
    const float* gw2 = (const float*)d_in[4];
    const float* gb2 = (const float*)d_in[5];
    const float* sw0 = (const float*)d_in[6];
    const float* sb0 = (const float*)d_in[7];
    const float* sw1 = (const float*)d_in[8];
    const float* sb1 = (const float*)d_in[9];
    const float* sw2 = (const float*)d_in[10];
    const float* sb2 = (const float*)d_in[11];
    const float* sw3 = (const float*)d_in[12];
    const float* sb3 = (const float*)d_in[13];
    const float* cw0 = (const float*)d_in[14];
    const float* cb0 = (const float*)d_in[15];
    const float* cw1 = (const float*)d_in[16];
    const float* cb1 = (const float*)d_in[17];
    const float* fw1 = (const float*)d_in[18];
    const float* fb1 = (const float*)d_in[19];
    const float* fw2 = (const float*)d_in[20];
    const float* fb2 = (const float*)d_in[21];
    const float* fw3 = (const float*)d_in[22];
    const float* fb3 = (const float*)d_in[23];
    const float* lw1 = (const float*)d_in[24];
    const float* lb1 = (const float*)d_in[25];
    const float* lw2 = (const float*)d_in[26];
    const float* fuw = (const float*)d_in[27];
    const float* fub = (const float*)d_in[28];
    float* out = (float*)d_out;

    float* ws = (float*)d_ws;
    float* o1  = ws;               // [8,16,64,64]   524288
    float* o3  = o1 + 524288;      // [8,64,16,16]   131072
    float* xl1 = o3 + 131072;      // [8,64,16,16]   131072
    float* xl2 = xl1 + 131072;     // [8,64,16,16]   131072
    float* xg0 = xl2 + 131072;     // [8,64,8,8]      32768
    float* xg1 = xg0 + 32768;      // [8,64,4,4]       8192
    float* bg  = xg1 + 8192;       // [8,8,16,16]     16384
    // total ~1.0M floats = 4.0 MB

    conv01_k<<<2048, 256, 0, stream>>>(lqs, evs, sw0, sb0, sw1, sb1, o1);
    conv23_k<<<512, 256, 0, stream>>>(o1, sw2, sb2, sw3, sb3, o3);
    lw1cw0_k<<<640, 256, 0, stream>>>(o3, lw1, lb1, cw0, cb0, xl1, xg0);
    lw2cw1_k<<<576, 256, 0, stream>>>(xl1, lw2, xg0, cw1, cb1, xl2, xg1);
    fc1bgfuse_k<<<8, 256, 0, stream>>>(xg1, fw1, fb1, fw2, fb2, fw3, fb3,
                                       xl2, fuw, fub, bg);
    guide_slice_k<<<BATCH * 64 * 16, 256, 0, stream>>>(lqs, bg, gw1, gb1, gw2, gb2, out);
}

// Round 12
// 445.045 us; speedup vs baseline: 1.9955x; 1.0497x over previous
//
#include <hip/hip_runtime.h>
#include <hip/hip_bf16.h>
#include <math.h>

#define BATCH 8
#define HH 1024
#define WW 1024

__device__ __forceinline__ int reflect1024(int i) {
    i = i < 0 ? -i : i;
    return i > 1023 ? 2046 - i : i;
}

// ---------------------------------------------------------------------------
// conv01_k: fused conv0 (18->8 @256 s2) + conv1 (8->16 @128 s2) -> o1
// [8,16,64,64].  2048 blocks; o1 tile 4x4 per block.  (unchanged, verified)
// ---------------------------------------------------------------------------
__global__ __launch_bounds__(256) void conv01_k(const float* __restrict__ lqs,
                                                const float* __restrict__ evs,
                                                const float* __restrict__ sw0,
                                                const float* __restrict__ sb0,
                                                const float* __restrict__ sw1,
                                                const float* __restrict__ sb1,
                                                float* __restrict__ o1) {
    __shared__ float s0[8 * 81];  // [ic][yy*9+xx]
    int t = threadIdx.x;
    int blk = blockIdx.x;
    int tx = blk & 15, ty = (blk >> 4) & 15, b = blk >> 8;
    int oy0 = ty << 2, ox0 = tx << 2;            // o1 tile origin (64x64 grid)
    int iy0s = 2 * oy0 - 1, ix0s = 2 * ox0 - 1;  // o0 region origin (9x9)

    if (t < 81) {
        int p = t;
        int yy = p / 9, xx = p - yy * 9;
        int iy = iy0s + yy, ix = ix0s + xx;      // o0 coords in [0,128)
        if ((unsigned)iy < 128u && (unsigned)ix < 128u) {
            float acc[8];
#pragma unroll
            for (int o = 0; o < 8; ++o) acc[o] = sb0[o];
#pragma unroll
            for (int ic = 0; ic < 3; ++ic) {
                const float* ipc = lqs + ((size_t)(b * 3 + ic) << 20);
#pragma unroll
                for (int ky = 0; ky < 3; ++ky) {
                    int r = 2 * iy - 1 + ky;
                    if ((unsigned)r >= 256u) continue;
                    const float* row = ipc + ((size_t)r << 12);  // nearest: row 4*r
#pragma unroll
                    for (int kx = 0; kx < 3; ++kx) {
                        int c = 2 * ix - 1 + kx;
                        if ((unsigned)c >= 256u) continue;
                        float v = row[c << 2];                    // nearest: col 4*c
                        const float* wp = sw0 + ic * 9 + ky * 3 + kx;
#pragma unroll
                        for (int o = 0; o < 8; ++o) acc[o] = fmaf(wp[o * 162], v, acc[o]);
                    }
                }
            }
            for (int ic = 0; ic < 15; ++ic) {
                const float* ipc = evs + ((size_t)(b * 15 + ic) << 16);
#pragma unroll
                for (int ky = 0; ky < 3; ++ky) {
                    int r = 2 * iy - 1 + ky;
                    if ((unsigned)r >= 256u) continue;
                    const float* row = ipc + (r << 8);
#pragma unroll
                    for (int kx = 0; kx < 3; ++kx) {
                        int c = 2 * ix - 1 + kx;
                        if ((unsigned)c >= 256u) continue;
                        float v = row[c];
                        const float* wp = sw0 + (ic + 3) * 9 + ky * 3 + kx;
#pragma unroll
                        for (int o = 0; o < 8; ++o) acc[o] = fmaf(wp[o * 162], v, acc[o]);
                    }
                }
            }
#pragma unroll
            for (int o = 0; o < 8; ++o) s0[o * 81 + p] = fmaxf(acc[o], 0.0f);
        } else {
#pragma unroll
            for (int o = 0; o < 8; ++o) s0[o * 81 + p] = 0.0f;
        }
    }
    __syncthreads();

    // conv1: thread t -> px = t&15 (4x4), oc = t>>4 (1 oc each)
    int px = t & 15, oc = t >> 4;
    int lpy = px >> 2, lpx = px & 3;
    float a1 = sb1[oc];
#pragma unroll
    for (int ic = 0; ic < 8; ++ic) {
        const float* sp = s0 + ic * 81 + (2 * lpy) * 9 + 2 * lpx;
        float x[9];
#pragma unroll
        for (int ky = 0; ky < 3; ++ky)
#pragma unroll
            for (int kx = 0; kx < 3; ++kx) x[ky * 3 + kx] = sp[ky * 9 + kx];
        const float* wp = sw1 + (oc * 8 + ic) * 9;
#pragma unroll
        for (int k = 0; k < 9; ++k) a1 = fmaf(wp[k], x[k], a1);
    }
    int oy = oy0 + lpy, ox = ox0 + lpx;
    o1[((size_t)(b * 16 + oc) << 12) + (oy << 6) + ox] = fmaxf(a1, 0.0f);
}

// ---------------------------------------------------------------------------
// conv23_k: fused conv2 + conv3 -> o3 [8,64,16,16].  (unchanged, verified)
// ---------------------------------------------------------------------------
__global__ __launch_bounds__(256) void conv23_k(const float* __restrict__ o1,
                                                const float* __restrict__ sw2,
                                                const float* __restrict__ sb2,
                                                const float* __restrict__ sw3,
                                                const float* __restrict__ sb3,
                                                float* __restrict__ o3) {
    __shared__ float s2[32 * 25];  // [ic][yy*5+xx]
    int t = threadIdx.x;
    int blk = blockIdx.x;
    int tx = blk & 7, ty = (blk >> 3) & 7, b = blk >> 6;
    int oy0 = ty << 1, ox0 = tx << 1;
    int iy0s = 2 * oy0 - 1, ix0s = 2 * ox0 - 1;

    if (t < 100) {
        int ocg = t / 25, p = t - ocg * 25;
        int yy = p / 5, xx = p - yy * 5;
        int iy = iy0s + yy, ix = ix0s + xx;
        if ((unsigned)iy < 32u && (unsigned)ix < 32u) {
            float acc[8];
#pragma unroll
            for (int o = 0; o < 8; ++o) acc[o] = sb2[ocg * 8 + o];
            const float* ip = o1 + ((size_t)b << 16);
            int ry0 = 2 * iy - 1, rx0 = 2 * ix - 1;
            for (int ic = 0; ic < 16; ++ic) {
                const float* ipc = ip + (ic << 12);
                float x[9];
#pragma unroll
                for (int ky = 0; ky < 3; ++ky) {
                    int r = ry0 + ky;
#pragma unroll
                    for (int kx = 0; kx < 3; ++kx) {
                        int c = rx0 + kx;
                        bool ok = ((unsigned)r < 64u) && ((unsigned)c < 64u);
                        x[ky * 3 + kx] = ok ? ipc[(r << 6) + c] : 0.0f;
                    }
                }
#pragma unroll
                for (int o = 0; o < 8; ++o) {
                    const float* wp = sw2 + ((ocg * 8 + o) * 16 + ic) * 9;
#pragma unroll
                    for (int k = 0; k < 9; ++k) acc[o] = fmaf(wp[k], x[k], acc[o]);
                }
            }
#pragma unroll
            for (int o = 0; o < 8; ++o) s2[(ocg * 8 + o) * 25 + p] = fmaxf(acc[o], 0.0f);
        } else {
#pragma unroll
            for (int o = 0; o < 8; ++o) s2[(ocg * 8 + o) * 25 + p] = 0.0f;
        }
    }
    __syncthreads();

    int oc = t >> 2, p2 = t & 3;
    int py = p2 >> 1, pxx = p2 & 1;
    float a3 = sb3[oc];
    for (int ic = 0; ic < 32; ++ic) {
        const float* wp = sw3 + (oc * 32 + ic) * 9;
        const float* sp = s2 + ic * 25 + (2 * py) * 5 + 2 * pxx;
#pragma unroll
        for (int ky = 0; ky < 3; ++ky)
#pragma unroll
            for (int kx = 0; kx < 3; ++kx)
                a3 = fmaf(wp[ky * 3 + kx], sp[ky * 5 + kx], a3);
    }
    o3[((size_t)(b * 64 + oc) << 8) + ((oy0 + py) << 4) + (ox0 + pxx)] = fmaxf(a3, 0.0f);
}

// ---------------------------------------------------------------------------
// lw1cw0_k with LDS-staged weights.  (unchanged, verified)
// ---------------------------------------------------------------------------
__global__ __launch_bounds__(256) void lw1cw0_k(const float* __restrict__ o3,
                                                const float* __restrict__ lw1,
                                                const float* __restrict__ lb1,
                                                const float* __restrict__ cw0,
                                                const float* __restrict__ cb0,
                                                float* __restrict__ xl1,
                                                float* __restrict__ xg0) {
    __shared__ float sW[2304];
    int blk = blockIdx.x, t = threadIdx.x;
    if (blk < 512) {
        int b = blk >> 6, oc = blk & 63;
        for (int i = t; i < 576; i += 256) sW[i] = lw1[oc * 576 + i];
        __syncthreads();
        int oy = t >> 4, ox = t & 15;
        int iy0 = oy - 1, ix0 = ox - 1;
        float acc = lb1[oc];
        const float* ip = o3 + ((size_t)b << 14);
        for (int ic = 0; ic < 64; ++ic) {
            const float* ipc = ip + (ic << 8);
            float x[9];
#pragma unroll
            for (int ky = 0; ky < 3; ++ky) {
                int iy = iy0 + ky;
#pragma unroll
                for (int kx = 0; kx < 3; ++kx) {
                    int ix = ix0 + kx;
                    bool ok = ((unsigned)iy < 16u) && ((unsigned)ix < 16u);
                    x[ky * 3 + kx] = ok ? ipc[(iy << 4) + ix] : 0.0f;
                }
            }
            const float* wp = sW + ic * 9;
#pragma unroll
            for (int k = 0; k < 9; ++k) acc = fmaf(wp[k], x[k], acc);
        }
        xl1[((size_t)(b * 64 + oc) << 8) + t] = fmaxf(acc, 0.0f);
    } else {
        int q = blk - 512;
        int b = q >> 4, oc_base = (q & 15) << 2;
        for (int i = t; i < 2304; i += 256) sW[i] = cw0[oc_base * 576 + i];
        __syncthreads();
        int px = t & 63, ol = t >> 6;
        int oy = px >> 3, ox = px & 7;
        int iy0 = 2 * oy - 1, ix0 = 2 * ox - 1;
        float acc = cb0[oc_base + ol];
        const float* ip = o3 + ((size_t)b << 14);
        for (int ic = 0; ic < 64; ++ic) {
            const float* ipc = ip + (ic << 8);
            float x[9];
#pragma unroll
            for (int ky = 0; ky < 3; ++ky) {
                int iy = iy0 + ky;
#pragma unroll
                for (int kx = 0; kx < 3; ++kx) {
                    int ix = ix0 + kx;
                    bool ok = ((unsigned)iy < 16u) && ((unsigned)ix < 16u);
                    x[ky * 3 + kx] = ok ? ipc[(iy << 4) + ix] : 0.0f;
                }
            }
            const float* wp = sW + ol * 576 + ic * 9;
#pragma unroll
            for (int k = 0; k < 9; ++k) acc = fmaf(wp[k], x[k], acc);
        }
        xg0[((size_t)(b * 64 + oc_base + ol) << 6) + px] = fmaxf(acc, 0.0f);
    }
}

// ---------------------------------------------------------------------------
// lw2cw1_k: cw1 on blocks 0..63 (first, overlaps lw2), lw2 on blocks 64..575.
// (unchanged from round 11, verified: off the top-5)
// ---------------------------------------------------------------------------
__global__ __launch_bounds__(256) void lw2cw1_k(const float* __restrict__ xl1,
                                                const float* __restrict__ lw2,
                                                const float* __restrict__ xg0,
                                                const float* __restrict__ cw1,
                                                const float* __restrict__ cb1,
                                                float* __restrict__ xl2,
                                                float* __restrict__ xg1) {
    __shared__ __align__(16) float smem[8768];  // 35072 B
    int blk = blockIdx.x, t = threadIdx.x;
    if (blk < 64) {
        // cw1: b = blk>>3, ocs og*8 .. og*8+7
        int b = blk >> 3, og = blk & 7;
        float* sG = smem;            // xg0[b] : [64][8][8]  (4096)
        float* sW = smem + 4096;     // 8 x 584 padded rows  (4672)
#pragma unroll
        for (int j = 0; j < 16; ++j) sG[t + (j << 8)] = xg0[((size_t)b << 12) + t + (j << 8)];
        for (int i = t; i < 4608; i += 256) {
            int ol = i / 576, r = i - ol * 576;
            sW[ol * 584 + r] = cw1[(og * 8 + ol) * 576 + r];
        }
        __syncthreads();
        if (t < 128) {
            int ol = t >> 4, px = t & 15;
            int oc = og * 8 + ol;
            int oy = px >> 2, ox = px & 3;
            int iy0 = 2 * oy - 1, ix0 = 2 * ox - 1;
            float acc = cb1[oc];
            for (int ic = 0; ic < 64; ++ic) {
                const float* ipc = sG + (ic << 6);
                const float* wp = sW + ol * 584 + ic * 9;
#pragma unroll
                for (int ky = 0; ky < 3; ++ky) {
                    int r = iy0 + ky;
#pragma unroll
                    for (int kx = 0; kx < 3; ++kx) {
                        int cc = ix0 + kx;
                        bool ok = ((unsigned)r < 8u) && ((unsigned)cc < 8u);
                        float x = ok ? ipc[(r << 3) + cc] : 0.0f;
                        acc = fmaf(wp[ky * 3 + kx], x, acc);
                    }
                }
            }
            xg1[b * 1024 + (oc << 4) + px] = fmaxf(acc, 0.0f);
        }
    } else {
        // lw2: 64->64 @16 s1, no bias/relu.  (verified body)
        int q = blk - 64;
        float* sW = smem;
        int b = q >> 6, oc = q & 63;
        for (int i = t; i < 576; i += 256) sW[i] = lw2[oc * 576 + i];
        __syncthreads();
        int oy = t >> 4, ox = t & 15;
        int iy0 = oy - 1, ix0 = ox - 1;
        float acc = 0.0f;
        const float* ip = xl1 + ((size_t)b << 14);
        for (int ic = 0; ic < 64; ++ic) {
            const float* ipc = ip + (ic << 8);
            float x[9];
#pragma unroll
            for (int ky = 0; ky < 3; ++ky) {
                int iy = iy0 + ky;
#pragma unroll
                for (int kx = 0; kx < 3; ++kx) {
                    int ix = ix0 + kx;
                    bool ok = ((unsigned)iy < 16u) && ((unsigned)ix < 16u);
                    x[ky * 3 + kx] = ok ? ipc[(iy << 4) + ix] : 0.0f;
                }
            }
            const float* wp = sW + ic * 9;
#pragma unroll
            for (int k = 0; k < 9; ++k) acc = fmaf(wp[k], x[k], acc);
        }
        xl2[((size_t)(b * 64 + oc) << 8) + t] = acc;
    }
}

// ---------------------------------------------------------------------------
// fc1bgfuse_k: 8 blocks (one per batch).  fc1 with 4-ROW INTERLEAVE: 16
// independent float4 loads in flight per wave (was 4) -> 16 latency-gated
// iterations instead of 64 (round-11 counters: 82 µs, VALUBusy 0.14% —
// pure serial latency).  Per-row FMA order (jj sequence + butterfly) is
// bit-identical to the verified round-8 fc1; rows merely interleaved.
// Then the verified fc2/fc3/fuse -> bg.
// ---------------------------------------------------------------------------
__global__ __launch_bounds__(256) void fc1bgfuse_k(const float* __restrict__ xg1,
                                                   const float* __restrict__ fw1,
                                                   const float* __restrict__ fb1,
                                                   const float* __restrict__ fw2,
                                                   const float* __restrict__ fb2,
                                                   const float* __restrict__ fw3,
                                                   const float* __restrict__ fb3,
                                                   const float* __restrict__ xl2,
                                                   const float* __restrict__ fuw,
                                                   const float* __restrict__ fub,
                                                   float* __restrict__ bg) {
    __shared__ __align__(16) float sX[1024];
    __shared__ __align__(16) float sH1[256];
    __shared__ __align__(16) float sH2[128];
    __shared__ float sXG[64];
    int b = blockIdx.x, t = threadIdx.x;

#pragma unroll
    for (int j = 0; j < 4; ++j) sX[t + (j << 8)] = xg1[b * 1024 + t + (j << 8)];
    __syncthreads();

    // fc1: wave-per-row, 4 rows per iteration (16 loads in flight)
    {
        int wave = t >> 6, lane = t & 63;
        const float4* x4 = (const float4*)sX;
        float4 xv[4];
#pragma unroll
        for (int jj = 0; jj < 4; ++jj) xv[jj] = x4[lane + 64 * jj];
        for (int k0 = 0; k0 < 64; k0 += 4) {
            float acc[4] = {0.f, 0.f, 0.f, 0.f};
#pragma unroll
            for (int rr = 0; rr < 4; ++rr) {
                int r = (wave << 6) + k0 + rr;
                const float4* w4 = (const float4*)(fw1 + (size_t)r * 1024);
#pragma unroll
                for (int jj = 0; jj < 4; ++jj) {
                    float4 wv = w4[lane + 64 * jj];
                    acc[rr] = fmaf(wv.x, xv[jj].x, acc[rr]);
                    acc[rr] = fmaf(wv.y, xv[jj].y, acc[rr]);
                    acc[rr] = fmaf(wv.z, xv[jj].z, acc[rr]);
                    acc[rr] = fmaf(wv.w, xv[jj].w, acc[rr]);
                }
            }
#pragma unroll
            for (int rr = 0; rr < 4; ++rr) {
#pragma unroll
                for (int m = 32; m; m >>= 1) acc[rr] += __shfl_xor(acc[rr], m, 64);
                int r = (wave << 6) + k0 + rr;
                if (lane == 0) sH1[r] = fmaxf(acc[rr] + fb1[r], 0.0f);
            }
        }
    }
    __syncthreads();

    // fc2 (verified)
    if (t < 128) {
        const float4* w4 = (const float4*)(fw2 + (size_t)t * 256);
        const float4* x4 = (const float4*)sH1;
        float a[4] = {0.f, 0.f, 0.f, 0.f};
#pragma unroll 4
        for (int j = 0; j < 64; ++j) {
            float4 wv = w4[j], xv = x4[j];
            a[j & 3] = fmaf(wv.x, xv.x, fmaf(wv.y, xv.y,
                       fmaf(wv.z, xv.z, fmaf(wv.w, xv.w, a[j & 3]))));
        }
        sH2[t] = fmaxf(a[0] + a[1] + a[2] + a[3] + fb2[t], 0.0f);
    }
    __syncthreads();
    // fc3 (verified)
    if (t < 64) {
        const float4* w4 = (const float4*)(fw3 + (size_t)t * 128);
        const float4* x4 = (const float4*)sH2;
        float a[4] = {0.f, 0.f, 0.f, 0.f};
#pragma unroll 4
        for (int j = 0; j < 32; ++j) {
            float4 wv = w4[j], xv = x4[j];
            a[j & 3] = fmaf(wv.x, xv.x, fmaf(wv.y, xv.y,
                       fmaf(wv.z, xv.z, fmaf(wv.w, xv.w, a[j & 3]))));
        }
        sXG[t] = a[0] + a[1] + a[2] + a[3] + fb3[t];
    }
    __syncthreads();

    // fuse (verified)
    float accd[8];
#pragma unroll
    for (int d = 0; d < 8; ++d) accd[d] = fub[d];
    const float* xp = xl2 + ((size_t)b << 14) + t;
    for (int c = 0; c < 64; ++c) {
        float f = fmaxf(sXG[c] + xp[c << 8], 0.0f);
#pragma unroll
        for (int d = 0; d < 8; ++d) accd[d] = fmaf(fuw[(d << 6) + c], f, accd[d]);
    }
#pragma unroll
    for (int d = 0; d < 8; ++d) bg[((b << 3) + d) * 256 + t] = accd[d];
}

// ---------------------------------------------------------------------------
// guide+slice, TH=16.  (unchanged from round 10, verified)
// ---------------------------------------------------------------------------
__global__ __launch_bounds__(256) void guide_slice_k(const float* __restrict__ lqs,
                                                     const float* __restrict__ bgp,
                                                     const float* __restrict__ gw1,
                                                     const float* __restrict__ gb1,
                                                     const float* __restrict__ gw2,
                                                     const float* __restrict__ gb2,
                                                     float* __restrict__ out) {
    constexpr int TW = 64, TH = 16;
    __shared__ float sBH[3][TH][81];
    __shared__ float sBG[2048];
    __shared__ float sW1[48], sB1[16], sW2[16], sB2v[1];

    int t = threadIdx.x;
    int bx = blockIdx.x & 15;
    int by = (blockIdx.x >> 4) & 63;
    int b = blockIdx.x >> 10;
    int x0 = bx * TW, y0 = by * TH;

    float gv[17];
    {
        float gs = 0.0f;
#pragma unroll
        for (int i = 0; i < 17; ++i) {
            float d = (float)i - 8.0f;
            gv[i] = expf(-(d * d) * 0.125f);
            gs += gv[i];
        }
        float inv = 1.0f / gs;
#pragma unroll
        for (int i = 0; i < 17; ++i) gv[i] *= inv;
    }

    for (int i = t; i < 2048; i += 256) sBG[i] = bgp[b * 2048 + i];
    if (t < 48) sW1[t] = gw1[t];
    if (t < 16) { sB1[t] = gb1[t]; sW2[t] = gw2[t]; }
    if (t == 0) sB2v[0] = gb2[0];

    if (t < 240) {
        int c = t / 80, xo = t % 80;
        int gx = reflect1024(x0 + xo - 8);
        const float* colp = lqs + (size_t)(b * 3 + c) * HH * WW + gx;
        float win[17];
#pragma unroll
        for (int i = 0; i < 16; ++i)
            win[i] = colp[(size_t)reflect1024(y0 - 8 + i) * WW];
#pragma unroll
        for (int j = 0; j < TH; ++j) {
            win[(16 + j) % 17] = colp[(size_t)reflect1024(y0 + 8 + j) * WW];
            float acc = 0.0f;
#pragma unroll
            for (int i = 0; i < 17; ++i) acc = fmaf(gv[i], win[(j + i) % 17], acc);
            sBH[c][j][xo] = acc;
        }
    }
    __syncthreads();

    int yy = t >> 4, xs = (t & 15) * 4;
    int Y = y0 + yy;
    float fy = fminf(fmaxf((Y + 0.5f) * (1.0f / 64.0f) + 3.5f, 0.0f), 15.0f);
    float yf = floorf(fy);
    int yi = (int)yf;
    float ay = fy - yf;
    int yi1 = min(yi + 1, 15);

    float bcv[3][4];
#pragma unroll
    for (int c = 0; c < 3; ++c) {
        float win[17];
#pragma unroll
        for (int i = 0; i < 16; ++i) win[i] = sBH[c][yy][xs + i];
#pragma unroll
        for (int j = 0; j < 4; ++j) {
            win[(16 + j) % 17] = sBH[c][yy][xs + 16 + j];
            float acc = 0.0f;
#pragma unroll
            for (int i = 0; i < 17; ++i) acc = fmaf(gv[i], win[(j + i) % 17], acc);
            bcv[c][j] = acc;
        }
    }

    float val[4];
#pragma unroll
    for (int j = 0; j < 4; ++j) {
        float b0 = bcv[0][j], b1 = bcv[1][j], b2 = bcv[2][j];
        float s = sB2v[0];
#pragma unroll
        for (int c = 0; c < 16; ++c) {
            float g1 = fmaf(sW1[c * 3 + 0], b0,
                       fmaf(sW1[c * 3 + 1], b1,
                       fmaf(sW1[c * 3 + 2], b2, sB1[c])));
            s = fmaf(sW2[c], fmaxf(g1, 0.0f), s);
        }
        float sig = 1.0f / (1.0f + expf(-s));
        float guide = sig * 2.0f - 0.5f;

        int X = x0 + xs + j;
        float fx = fminf(fmaxf((X + 0.5f) * (1.0f / 64.0f) + 3.5f, 0.0f), 15.0f);
        float fz = fminf(fmaxf(fmaf(guide, 4.0f, 3.5f), 0.0f), 7.0f);
        float xf = floorf(fx), zf = floorf(fz);
        int xi = (int)xf, zi = (int)zf;
        float ax = fx - xf, az = fz - zf;
        int xi1 = min(xi + 1, 15), zi1 = min(zi + 1, 7);

        const float* g0 = sBG + zi * 256;
        const float* g1p = sBG + zi1 * 256;
        int i00 = yi * 16 + xi, i01 = yi * 16 + xi1;
        int i10 = yi1 * 16 + xi, i11 = yi1 * 16 + xi1;
        float c00 = g0[i00] + az * (g1p[i00] - g0[i00]);
        float c01 = g0[i01] + az * (g1p[i01] - g0[i01]);
        float c10 = g0[i10] + az * (g1p[i10] - g0[i10]);
        float c11 = g0[i11] + az * (g1p[i11] - g0[i11]);
        float c0 = c00 + ay * (c10 - c00);
        float c1 = c01 + ay * (c11 - c01);
        val[j] = c0 + ax * (c1 - c0);
    }
    float4* op = (float4*)(out + (size_t)b * HH * WW + (size_t)Y * WW + x0 + xs);
    op[0] = make_float4(val[0], val[1], val[2], val[3]);
}

// ---------------------------------------------------------------------------
extern "C" void kernel_launch(void* const* d_in, const int* in_sizes, int n_in,
                              void* d_out, int out_size, void* d_ws, size_t ws_size,
                              hipStream_t stream) {
    const float* lqs = (const float*)d_in[0];
    const float* evs = (const float*)d_in[1];
    const float* gw1 = (const float*)d_in[2];
    const float* gb1 = (const float*)d_in[3];
    const float* gw2 = (const float*)d_in[4];
    const float* gb2 = (const float*)d_in[5];
    const float* sw0 = (const float*)d_in[6];
    const float* sb0 = (const float*)d_in[7];
    const float* sw1 = (const float*)d_in[8];
    const float* sb1 = (const float*)d_in[9];
    const float* sw2 = (const float*)d_in[10];
    const float* sb2 = (const float*)d_in[11];
    const float* sw3 = (const float*)d_in[12];
    const float* sb3 = (const float*)d_in[13];
    const float* cw0 = (const float*)d_in[14];
    const float* cb0 = (const float*)d_in[15];
    const float* cw1 = (const float*)d_in[16];
    const float* cb1 = (const float*)d_in[17];
    const float* fw1 = (const float*)d_in[18];
    const float* fb1 = (const float*)d_in[19];
    const float* fw2 = (const float*)d_in[20];
    const float* fb2 = (const float*)d_in[21];
    const float* fw3 = (const float*)d_in[22];
    const float* fb3 = (const float*)d_in[23];
    const float* lw1 = (const float*)d_in[24];
    const float* lb1 = (const float*)d_in[25];
    const float* lw2 = (const float*)d_in[26];
    const float* fuw = (const float*)d_in[27];
    const float* fub = (const float*)d_in[28];
    float* out = (float*)d_out;

    float* ws = (float*)d_ws;
    float* o1  = ws;               // [8,16,64,64]   524288
    float* o3  = o1 + 524288;      // [8,64,16,16]   131072
    float* xl1 = o3 + 131072;      // [8,64,16,16]   131072
    float* xl2 = xl1 + 131072;     // [8,64,16,16]   131072
    float* xg0 = xl2 + 131072;     // [8,64,8,8]      32768
    float* xg1 = xg0 + 32768;      // [8,64,4,4]       8192
    float* bg  = xg1 + 8192;       // [8,8,16,16]     16384
    // total ~1.0M floats = 4.0 MB

    conv01_k<<<2048, 256, 0, stream>>>(lqs, evs, sw0, sb0, sw1, sb1, o1);
    conv23_k<<<512, 256, 0, stream>>>(o1, sw2, sb2, sw3, sb3, o3);
    lw1cw0_k<<<640, 256, 0, stream>>>(o3, lw1, lb1, cw0, cb0, xl1, xg0);
    lw2cw1_k<<<576, 256, 0, stream>>>(xl1, lw2, xg0, cw1, cb1, xl2, xg1);
    fc1bgfuse_k<<<8, 256, 0, stream>>>(xg1, fw1, fb1, fw2, fb2, fw3, fb3,
                                       xl2, fuw, fub, bg);
    guide_slice_k<<<BATCH * 64 * 16, 256, 0, stream>>>(lqs, bg, gw1, gb1, gw2, gb2, out);
}